// Round 1
// baseline (587.355 us; speedup 1.0000x reference)
//
#include <hip/hip_runtime.h>
#include <math.h>

#define NN 50000     // nodes
#define NE 650000    // edges (without self loops)
#define NET 700000   // NE + NN self loops
#define FD 256       // H*C = 4*64
#define NEG 0.2f

static __device__ __forceinline__ float lrelu(float v){ return v > 0.f ? v : NEG*v; }

// ---------------- CSR build (graph identical for all 3 layers) ----------------
__global__ void count_deg(const int* __restrict__ ei, int* __restrict__ deg){
  int e = blockIdx.x*blockDim.x + threadIdx.x;
  if (e >= NET) return;
  int d = (e < NE) ? ei[NE + e] : (e - NE);
  atomicAdd(&deg[d], 1);
}

__global__ void scan_block(const int* __restrict__ deg, int* __restrict__ excl, int* __restrict__ bsums){
  __shared__ int sh[256];
  int t = threadIdx.x;
  int i0 = blockIdx.x*1024 + t*4;
  int v0 = (i0+0 < NN) ? deg[i0+0] : 0;
  int v1 = (i0+1 < NN) ? deg[i0+1] : 0;
  int v2 = (i0+2 < NN) ? deg[i0+2] : 0;
  int v3 = (i0+3 < NN) ? deg[i0+3] : 0;
  int tot = v0+v1+v2+v3;
  sh[t] = tot;
  __syncthreads();
  for (int off=1; off<256; off<<=1){
    int x = (t>=off) ? sh[t-off] : 0;
    __syncthreads();
    sh[t] += x;
    __syncthreads();
  }
  int base = sh[t] - tot;   // exclusive within block
  if (i0+0 < NN) excl[i0+0] = base;
  if (i0+1 < NN) excl[i0+1] = base + v0;
  if (i0+2 < NN) excl[i0+2] = base + v0+v1;
  if (i0+3 < NN) excl[i0+3] = base + v0+v1+v2;
  if (t == 255) bsums[blockIdx.x] = sh[255];
}

__global__ void scan_tops(int* bsums, int nb){
  if (threadIdx.x==0 && blockIdx.x==0){
    int run=0;
    for (int i=0;i<nb;i++){ int x=bsums[i]; bsums[i]=run; run+=x; }
  }
}

__global__ void scan_add(int* __restrict__ indptr, const int* __restrict__ bsums, int* __restrict__ cursor){
  int i = blockIdx.x*blockDim.x + threadIdx.x;
  if (i < NN){
    int v = indptr[i] + bsums[i>>10];
    indptr[i] = v;
    cursor[i] = v;
  }
  if (i == 0) indptr[NN] = NET;
}

__global__ void scatter_csr(const int* __restrict__ ei, int* __restrict__ cursor, int* __restrict__ csr){
  int e = blockIdx.x*blockDim.x + threadIdx.x;
  if (e >= NET) return;
  int s, d;
  if (e < NE){ s = ei[e]; d = ei[NE+e]; } else { s = e-NE; d = e-NE; }
  int pos = atomicAdd(&cursor[d], 1);
  csr[pos] = s;
}

// ---------------- fp32 tiled GEMM: C[M,Nc] = A[M,K] @ B[K,Nc] ----------------
__global__ __launch_bounds__(256) void gemm_f32(const float* __restrict__ A, const float* __restrict__ B,
                                                float* __restrict__ C, int M, int K, int Nc){
  __shared__ float As[16][64];
  __shared__ float Bs[16][64];
  int t = threadIdx.x;
  int tx = t & 15, ty = t >> 4;
  int bm0 = blockIdx.y * 64, bn0 = blockIdx.x * 64;
  float acc[4][4] = {};
  int arow = t >> 2, acol = (t & 3) * 4;
  int brow = t >> 4, bcol = (t & 15) * 4;
  for (int k0 = 0; k0 < K; k0 += 16){
    float4 a4 = make_float4(0.f,0.f,0.f,0.f);
    int gr = bm0 + arow;
    if (gr < M) a4 = *(const float4*)(A + (size_t)gr*K + k0 + acol);
    As[acol+0][arow] = a4.x;
    As[acol+1][arow] = a4.y;
    As[acol+2][arow] = a4.z;
    As[acol+3][arow] = a4.w;
    float4 b4 = *(const float4*)(B + (size_t)(k0+brow)*Nc + bn0 + bcol);
    *(float4*)&Bs[brow][bcol] = b4;
    __syncthreads();
    #pragma unroll
    for (int kk=0; kk<16; ++kk){
      float4 av = *(float4*)&As[kk][ty*4];
      float4 bv = *(float4*)&Bs[kk][tx*4];
      acc[0][0] += av.x*bv.x; acc[0][1] += av.x*bv.y; acc[0][2] += av.x*bv.z; acc[0][3] += av.x*bv.w;
      acc[1][0] += av.y*bv.x; acc[1][1] += av.y*bv.y; acc[1][2] += av.y*bv.z; acc[1][3] += av.y*bv.w;
      acc[2][0] += av.z*bv.x; acc[2][1] += av.z*bv.y; acc[2][2] += av.z*bv.z; acc[2][3] += av.z*bv.w;
      acc[3][0] += av.w*bv.x; acc[3][1] += av.w*bv.y; acc[3][2] += av.w*bv.z; acc[3][3] += av.w*bv.w;
    }
    __syncthreads();
  }
  #pragma unroll
  for (int i=0;i<4;i++){
    int r = bm0 + ty*4 + i;
    if (r < M){
      float4 o = make_float4(acc[i][0],acc[i][1],acc[i][2],acc[i][3]);
      *(float4*)(C + (size_t)r*Nc + bn0 + tx*4) = o;
    }
  }
}

// ---------------- per-node attention coefficients al_src/al_dst [N,4]+[N,4] ----------------
__global__ __launch_bounds__(256) void al_kernel(const float* __restrict__ h, const float* __restrict__ a_src,
                                                 const float* __restrict__ a_dst, float* __restrict__ al){
  int n = (blockIdx.x*blockDim.x + threadIdx.x) >> 6;
  int lane = threadIdx.x & 63;
  if (n >= NN) return;
  int head = lane >> 4;
  // lane*4 == head*64 + (lane&15)*4, so a_src/a_dst index directly with lane*4
  float4 hv = *(const float4*)(h + (size_t)n*FD + lane*4);
  float4 as = *(const float4*)(a_src + lane*4);
  float4 ad = *(const float4*)(a_dst + lane*4);
  float ps = hv.x*as.x + hv.y*as.y + hv.z*as.z + hv.w*as.w;
  float pd = hv.x*ad.x + hv.y*ad.y + hv.z*ad.z + hv.w*ad.w;
  for (int off=1; off<16; off<<=1){
    ps += __shfl_xor(ps, off);
    pd += __shfl_xor(pd, off);
  }
  if ((lane & 15) == 0){
    al[n*8 + head]     = ps;
    al[n*8 + 4 + head] = pd;
  }
}

// ---------------- GAT aggregation: one wave per destination node ----------------
__global__ __launch_bounds__(256) void gat_agg(const float* __restrict__ h, const float* __restrict__ al,
                                               const int* __restrict__ indptr, const int* __restrict__ csr,
                                               const float* __restrict__ bias, float* __restrict__ out, int elu){
  int n = (blockIdx.x*blockDim.x + threadIdx.x) >> 6;
  int lane = threadIdx.x & 63;
  if (n >= NN) return;
  int head = lane >> 4;
  int base = indptr[n], deg = indptr[n+1] - base;
  float4 ald = *(const float4*)(al + n*8 + 4);

  // pass 1: per-head max over incident edges
  float4 mx = make_float4(-1e30f,-1e30f,-1e30f,-1e30f);
  for (int j = lane; j < deg; j += 64){
    int s = csr[base+j];
    float4 als = *(const float4*)(al + s*8);
    mx.x = fmaxf(mx.x, lrelu(als.x + ald.x));
    mx.y = fmaxf(mx.y, lrelu(als.y + ald.y));
    mx.z = fmaxf(mx.z, lrelu(als.z + ald.z));
    mx.w = fmaxf(mx.w, lrelu(als.w + ald.w));
  }
  for (int off=32; off; off>>=1){
    mx.x = fmaxf(mx.x, __shfl_xor(mx.x, off));
    mx.y = fmaxf(mx.y, __shfl_xor(mx.y, off));
    mx.z = fmaxf(mx.z, __shfl_xor(mx.z, off));
    mx.w = fmaxf(mx.w, __shfl_xor(mx.w, off));
  }

  // pass 2: chunked exp + cooperative weighted gather of h[src]
  float4 esum = make_float4(0.f,0.f,0.f,0.f);
  float4 acc  = make_float4(0.f,0.f,0.f,0.f);
  for (int j0 = 0; j0 < deg; j0 += 64){
    int j = j0 + lane;
    float4 e4 = make_float4(0.f,0.f,0.f,0.f);
    int sj = 0;
    if (j < deg){
      sj = csr[base+j];
      float4 als = *(const float4*)(al + sj*8);
      e4.x = expf(lrelu(als.x + ald.x) - mx.x);
      e4.y = expf(lrelu(als.y + ald.y) - mx.y);
      e4.z = expf(lrelu(als.z + ald.z) - mx.z);
      e4.w = expf(lrelu(als.w + ald.w) - mx.w);
      esum.x += e4.x; esum.y += e4.y; esum.z += e4.z; esum.w += e4.w;
    }
    int cnt = min(64, deg - j0);
    for (int k = 0; k < cnt; ++k){
      int sk = __shfl(sj, k);
      float ex = __shfl(e4.x, k);
      float ey = __shfl(e4.y, k);
      float ez = __shfl(e4.z, k);
      float ew = __shfl(e4.w, k);
      float ek = (head==0)?ex:(head==1)?ey:(head==2)?ez:ew;
      float4 hv = *(const float4*)(h + (size_t)sk*FD + lane*4);
      acc.x += ek*hv.x; acc.y += ek*hv.y; acc.z += ek*hv.z; acc.w += ek*hv.w;
    }
  }
  for (int off=32; off; off>>=1){
    esum.x += __shfl_xor(esum.x, off);
    esum.y += __shfl_xor(esum.y, off);
    esum.z += __shfl_xor(esum.z, off);
    esum.w += __shfl_xor(esum.w, off);
  }
  float sH = (head==0)?esum.x:(head==1)?esum.y:(head==2)?esum.z:esum.w;
  float inv = 1.f/(sH + 1e-16f);
  float4 b4 = *(const float4*)(bias + lane*4);
  float4 o;
  o.x = acc.x*inv + b4.x;
  o.y = acc.y*inv + b4.y;
  o.z = acc.z*inv + b4.z;
  o.w = acc.w*inv + b4.w;
  if (elu){
    o.x = o.x>0.f ? o.x : expm1f(o.x);
    o.y = o.y>0.f ? o.y : expm1f(o.y);
    o.z = o.z>0.f ? o.z : expm1f(o.z);
    o.w = o.w>0.f ? o.w : expm1f(o.w);
  }
  *(float4*)(out + (size_t)n*FD + lane*4) = o;
}

// ---------------- layer 3: GEMV [N,256]@[256,1] then scalar GAT ----------------
__global__ __launch_bounds__(256) void gemv3(const float* __restrict__ A, const float* __restrict__ W,
                                             float* __restrict__ h3){
  int n = (blockIdx.x*blockDim.x + threadIdx.x) >> 6;
  int lane = threadIdx.x & 63;
  if (n >= NN) return;
  float4 a = *(const float4*)(A + (size_t)n*FD + lane*4);
  float4 w = *(const float4*)(W + lane*4);
  float p = a.x*w.x + a.y*w.y + a.z*w.z + a.w*w.w;
  for (int off=32; off; off>>=1) p += __shfl_xor(p, off);
  if (lane==0) h3[n] = p;
}

__global__ __launch_bounds__(256) void gat_agg3(const float* __restrict__ h3, const int* __restrict__ indptr,
                                                const int* __restrict__ csr, const float* __restrict__ asrc,
                                                const float* __restrict__ adst, const float* __restrict__ b3,
                                                float* __restrict__ out){
  int n = blockIdx.x*blockDim.x + threadIdx.x;
  if (n >= NN) return;
  float as = asrc[0], ad = adst[0];
  float hd = h3[n]*ad;
  int base = indptr[n], end = indptr[n+1];
  float m = -1e30f;
  for (int e=base; e<end; ++e){
    float l = lrelu(as*h3[csr[e]] + hd);
    m = fmaxf(m, l);
  }
  float s = 0.f, w = 0.f;
  for (int e=base; e<end; ++e){
    float hv = h3[csr[e]];
    float l = lrelu(as*hv + hd);
    float ee = expf(l - m);
    s += ee; w += ee*hv;
  }
  out[n] = w/(s + 1e-16f) + b3[0];
}

extern "C" void kernel_launch(void* const* d_in, const int* in_sizes, int n_in,
                              void* d_out, int out_size, void* d_ws, size_t ws_size,
                              hipStream_t stream){
  const float* x   = (const float*)d_in[0];
  const int*   ei  = (const int*)d_in[1];
  const float* W1  = (const float*)d_in[2];
  const float* as1 = (const float*)d_in[3];
  const float* ad1 = (const float*)d_in[4];
  const float* b1  = (const float*)d_in[5];
  const float* W2  = (const float*)d_in[6];
  const float* as2 = (const float*)d_in[7];
  const float* ad2 = (const float*)d_in[8];
  const float* b2  = (const float*)d_in[9];
  const float* W3  = (const float*)d_in[10];
  const float* as3 = (const float*)d_in[11];
  const float* ad3 = (const float*)d_in[12];
  const float* b3  = (const float*)d_in[13];
  float* outp = (float*)d_out;

  char* w = (char*)d_ws;
  size_t off = 0;
  auto alloc = [&](size_t bytes)->void*{
    void* p = w + off; off += (bytes + 255) & ~(size_t)255; return p;
  };
  float* hbuf  = (float*)alloc((size_t)NN*FD*4);   // 51.2 MB
  float* obuf  = (float*)alloc((size_t)NN*FD*4);   // 51.2 MB
  float* al    = (float*)alloc((size_t)NN*8*4);    // 1.6 MB
  int*   indptr= (int*)alloc((size_t)(NN+1)*4);
  int*   cursor= (int*)alloc((size_t)NN*4);
  int*   csr   = (int*)alloc((size_t)NET*4);       // 2.8 MB
  int*   bsums = (int*)alloc(64*4);
  float* h3    = (float*)alloc((size_t)NN*4);

  // ---- CSR build (once; same graph for all layers) ----
  hipMemsetAsync(cursor, 0, (size_t)NN*4, stream);
  count_deg<<<(NET+255)/256, 256, 0, stream>>>(ei, cursor);
  int nb = (NN+1023)/1024;
  scan_block<<<nb, 256, 0, stream>>>(cursor, indptr, bsums);
  scan_tops<<<1, 64, 0, stream>>>(bsums, nb);
  scan_add<<<(NN+255)/256, 256, 0, stream>>>(indptr, bsums, cursor);
  scatter_csr<<<(NET+255)/256, 256, 0, stream>>>(ei, cursor, csr);

  dim3 gemm_grid(FD/64, (NN+63)/64);
  int node_wave_blocks = (NN*64+255)/256;

  // ---- layer 1 ----
  gemm_f32<<<gemm_grid, 256, 0, stream>>>(x, W1, hbuf, NN, 128, FD);
  al_kernel<<<node_wave_blocks, 256, 0, stream>>>(hbuf, as1, ad1, al);
  gat_agg<<<node_wave_blocks, 256, 0, stream>>>(hbuf, al, indptr, csr, b1, obuf, 1);
  // ---- layer 2 ----
  gemm_f32<<<gemm_grid, 256, 0, stream>>>(obuf, W2, hbuf, NN, 256, FD);
  al_kernel<<<node_wave_blocks, 256, 0, stream>>>(hbuf, as2, ad2, al);
  gat_agg<<<node_wave_blocks, 256, 0, stream>>>(hbuf, al, indptr, csr, b2, obuf, 1);
  // ---- layer 3 ----
  gemv3<<<node_wave_blocks, 256, 0, stream>>>(obuf, W3, h3);
  gat_agg3<<<(NN+255)/256, 256, 0, stream>>>(h3, indptr, csr, as3, ad3, b3, outp);
}

// Round 2
// 576.950 us; speedup vs baseline: 1.0180x; 1.0180x over previous
//
#include <hip/hip_runtime.h>
#include <math.h>

#define NN 50000     // nodes
#define NE 650000    // edges (without self loops)
#define NET 700000   // NE + NN self loops
#define FD 256       // H*C = 4*64
#define NEG 0.2f

static __device__ __forceinline__ float lrelu(float v){ return v > 0.f ? v : NEG*v; }

// ---------------- CSR build (graph identical for all 3 layers) ----------------
__global__ void count_deg(const int* __restrict__ ei, int* __restrict__ deg){
  int e = blockIdx.x*blockDim.x + threadIdx.x;
  if (e >= NET) return;
  int d = (e < NE) ? ei[NE + e] : (e - NE);
  atomicAdd(&deg[d], 1);
}

__global__ void scan_block(const int* __restrict__ deg, int* __restrict__ excl, int* __restrict__ bsums){
  __shared__ int sh[256];
  int t = threadIdx.x;
  int i0 = blockIdx.x*1024 + t*4;
  int v0 = (i0+0 < NN) ? deg[i0+0] : 0;
  int v1 = (i0+1 < NN) ? deg[i0+1] : 0;
  int v2 = (i0+2 < NN) ? deg[i0+2] : 0;
  int v3 = (i0+3 < NN) ? deg[i0+3] : 0;
  int tot = v0+v1+v2+v3;
  sh[t] = tot;
  __syncthreads();
  for (int off=1; off<256; off<<=1){
    int x = (t>=off) ? sh[t-off] : 0;
    __syncthreads();
    sh[t] += x;
    __syncthreads();
  }
  int base = sh[t] - tot;   // exclusive within block
  if (i0+0 < NN) excl[i0+0] = base;
  if (i0+1 < NN) excl[i0+1] = base + v0;
  if (i0+2 < NN) excl[i0+2] = base + v0+v1;
  if (i0+3 < NN) excl[i0+3] = base + v0+v1+v2;
  if (t == 255) bsums[blockIdx.x] = sh[255];
}

__global__ void scan_tops(int* bsums, int nb){
  if (threadIdx.x==0 && blockIdx.x==0){
    int run=0;
    for (int i=0;i<nb;i++){ int x=bsums[i]; bsums[i]=run; run+=x; }
  }
}

__global__ void scan_add(int* __restrict__ indptr, const int* __restrict__ bsums, int* __restrict__ cursor){
  int i = blockIdx.x*blockDim.x + threadIdx.x;
  if (i < NN){
    int v = indptr[i] + bsums[i>>10];
    indptr[i] = v;
    cursor[i] = v;
  }
  if (i == 0) indptr[NN] = NET;
}

__global__ void scatter_csr(const int* __restrict__ ei, int* __restrict__ cursor, int* __restrict__ csr){
  int e = blockIdx.x*blockDim.x + threadIdx.x;
  if (e >= NET) return;
  int s, d;
  if (e < NE){ s = ei[e]; d = ei[NE+e]; } else { s = e-NE; d = e-NE; }
  int pos = atomicAdd(&cursor[d], 1);
  csr[pos] = s;
}

// ---------------- fp32 GEMM: 128x128 tile, 8x8 micro-tile ----------------
// C[M,Nc] = A[M,K] @ B[K,Nc].  Nc multiple of 128, K multiple of 16.
// Split-halves register blocking: thread (tx,ty) owns rows {ty*4+i, 64+ty*4+i},
// cols {tx*4+j, 64+tx*4+j} -> every ds_read_b128 spans <=256B per 16-lane
// group => <=2-way bank aliasing (free, m136). As stored k-major [16][132]
// (pad +4 so transpose scalar stores are 2-way max).
__global__ __launch_bounds__(256) void gemm_f32(const float* __restrict__ A, const float* __restrict__ B,
                                                float* __restrict__ C, int M, int K, int Nc){
  __shared__ float As[16][132];
  __shared__ float Bs[16][132];
  int t = threadIdx.x;
  int tx = t & 15, ty = t >> 4;
  int bm0 = blockIdx.y * 128, bn0 = blockIdx.x * 128;
  float acc[8][8] = {};

  int ra = t >> 2, ka = (t & 3) * 4;       // A staging: row ra & 64+ra, k-cols ka..ka+3
  int kb = t >> 5, cb = (t & 31) * 4;      // B staging: k-row kb & kb+8, cols cb..cb+3
  const float* Ap0 = A + (size_t)(bm0 + ra)*K + ka;
  const float* Ap1 = A + (size_t)(bm0 + 64 + ra)*K + ka;
  bool g0 = (bm0 + ra) < M, g1 = (bm0 + 64 + ra) < M;

  for (int k0 = 0; k0 < K; k0 += 16){
    float4 a0 = g0 ? *(const float4*)(Ap0 + k0) : make_float4(0.f,0.f,0.f,0.f);
    float4 a1 = g1 ? *(const float4*)(Ap1 + k0) : make_float4(0.f,0.f,0.f,0.f);
    float4 b0 = *(const float4*)(B + (size_t)(k0+kb  )*Nc + bn0 + cb);
    float4 b1 = *(const float4*)(B + (size_t)(k0+kb+8)*Nc + bn0 + cb);
    __syncthreads();                      // previous iter's reads complete
    As[ka+0][ra] = a0.x; As[ka+1][ra] = a0.y; As[ka+2][ra] = a0.z; As[ka+3][ra] = a0.w;
    As[ka+0][64+ra] = a1.x; As[ka+1][64+ra] = a1.y; As[ka+2][64+ra] = a1.z; As[ka+3][64+ra] = a1.w;
    *(float4*)&Bs[kb  ][cb] = b0;
    *(float4*)&Bs[kb+8][cb] = b1;
    __syncthreads();
    #pragma unroll
    for (int kk = 0; kk < 16; ++kk){
      float4 av0 = *(float4*)&As[kk][ty*4];
      float4 av1 = *(float4*)&As[kk][64+ty*4];
      float4 bv0 = *(float4*)&Bs[kk][tx*4];
      float4 bv1 = *(float4*)&Bs[kk][64+tx*4];
      float ar[8] = {av0.x,av0.y,av0.z,av0.w,av1.x,av1.y,av1.z,av1.w};
      float br[8] = {bv0.x,bv0.y,bv0.z,bv0.w,bv1.x,bv1.y,bv1.z,bv1.w};
      #pragma unroll
      for (int i=0;i<8;i++)
        #pragma unroll
        for (int j=0;j<8;j++)
          acc[i][j] += ar[i]*br[j];
    }
  }

  #pragma unroll
  for (int i=0;i<8;i++){
    int r = bm0 + ((i<4) ? (ty*4+i) : (64+ty*4+i-4));
    if (r < M){
      float4 o0 = make_float4(acc[i][0],acc[i][1],acc[i][2],acc[i][3]);
      float4 o1 = make_float4(acc[i][4],acc[i][5],acc[i][6],acc[i][7]);
      *(float4*)(C + (size_t)r*Nc + bn0 + tx*4) = o0;
      *(float4*)(C + (size_t)r*Nc + bn0 + 64 + tx*4) = o1;
    }
  }
}

// ---------------- per-node attention coefficients al_src/al_dst [N,4]+[N,4] ----------------
__global__ __launch_bounds__(256) void al_kernel(const float* __restrict__ h, const float* __restrict__ a_src,
                                                 const float* __restrict__ a_dst, float* __restrict__ al){
  int n = (blockIdx.x*blockDim.x + threadIdx.x) >> 6;
  int lane = threadIdx.x & 63;
  if (n >= NN) return;
  int head = lane >> 4;
  float4 hv = *(const float4*)(h + (size_t)n*FD + lane*4);
  float4 as = *(const float4*)(a_src + lane*4);
  float4 ad = *(const float4*)(a_dst + lane*4);
  float ps = hv.x*as.x + hv.y*as.y + hv.z*as.z + hv.w*as.w;
  float pd = hv.x*ad.x + hv.y*ad.y + hv.z*ad.z + hv.w*ad.w;
  for (int off=1; off<16; off<<=1){
    ps += __shfl_xor(ps, off);
    pd += __shfl_xor(pd, off);
  }
  if ((lane & 15) == 0){
    al[n*8 + head]     = ps;
    al[n*8 + 4 + head] = pd;
  }
}

// ---------------- GAT aggregation: one wave per destination node ----------------
__global__ __launch_bounds__(256) void gat_agg(const float* __restrict__ h, const float* __restrict__ al,
                                               const int* __restrict__ indptr, const int* __restrict__ csr,
                                               const float* __restrict__ bias, float* __restrict__ out, int elu){
  int n = (blockIdx.x*blockDim.x + threadIdx.x) >> 6;
  int lane = threadIdx.x & 63;
  if (n >= NN) return;
  int head = lane >> 4;
  int base = indptr[n], deg = indptr[n+1] - base;
  float4 ald = *(const float4*)(al + n*8 + 4);

  // pass 1: per-head max over incident edges
  float4 mx = make_float4(-1e30f,-1e30f,-1e30f,-1e30f);
  for (int j = lane; j < deg; j += 64){
    int s = csr[base+j];
    float4 als = *(const float4*)(al + s*8);
    mx.x = fmaxf(mx.x, lrelu(als.x + ald.x));
    mx.y = fmaxf(mx.y, lrelu(als.y + ald.y));
    mx.z = fmaxf(mx.z, lrelu(als.z + ald.z));
    mx.w = fmaxf(mx.w, lrelu(als.w + ald.w));
  }
  for (int off=32; off; off>>=1){
    mx.x = fmaxf(mx.x, __shfl_xor(mx.x, off));
    mx.y = fmaxf(mx.y, __shfl_xor(mx.y, off));
    mx.z = fmaxf(mx.z, __shfl_xor(mx.z, off));
    mx.w = fmaxf(mx.w, __shfl_xor(mx.w, off));
  }

  // pass 2: chunked exp + cooperative weighted gather of h[src]
  float4 esum = make_float4(0.f,0.f,0.f,0.f);
  float4 acc  = make_float4(0.f,0.f,0.f,0.f);
  for (int j0 = 0; j0 < deg; j0 += 64){
    int j = j0 + lane;
    float4 e4 = make_float4(0.f,0.f,0.f,0.f);
    int sj = 0;
    if (j < deg){
      sj = csr[base+j];
      float4 als = *(const float4*)(al + sj*8);
      e4.x = expf(lrelu(als.x + ald.x) - mx.x);
      e4.y = expf(lrelu(als.y + ald.y) - mx.y);
      e4.z = expf(lrelu(als.z + ald.z) - mx.z);
      e4.w = expf(lrelu(als.w + ald.w) - mx.w);
      esum.x += e4.x; esum.y += e4.y; esum.z += e4.z; esum.w += e4.w;
    }
    int cnt = min(64, deg - j0);
    for (int k = 0; k < cnt; ++k){
      int sk = __shfl(sj, k);
      float ex = __shfl(e4.x, k);
      float ey = __shfl(e4.y, k);
      float ez = __shfl(e4.z, k);
      float ew = __shfl(e4.w, k);
      float ek = (head==0)?ex:(head==1)?ey:(head==2)?ez:ew;
      float4 hv = *(const float4*)(h + (size_t)sk*FD + lane*4);
      acc.x += ek*hv.x; acc.y += ek*hv.y; acc.z += ek*hv.z; acc.w += ek*hv.w;
    }
  }
  for (int off=32; off; off>>=1){
    esum.x += __shfl_xor(esum.x, off);
    esum.y += __shfl_xor(esum.y, off);
    esum.z += __shfl_xor(esum.z, off);
    esum.w += __shfl_xor(esum.w, off);
  }
  float sH = (head==0)?esum.x:(head==1)?esum.y:(head==2)?esum.z:esum.w;
  float inv = 1.f/(sH + 1e-16f);
  float4 b4 = *(const float4*)(bias + lane*4);
  float4 o;
  o.x = acc.x*inv + b4.x;
  o.y = acc.y*inv + b4.y;
  o.z = acc.z*inv + b4.z;
  o.w = acc.w*inv + b4.w;
  if (elu){
    o.x = o.x>0.f ? o.x : expm1f(o.x);
    o.y = o.y>0.f ? o.y : expm1f(o.y);
    o.z = o.z>0.f ? o.z : expm1f(o.z);
    o.w = o.w>0.f ? o.w : expm1f(o.w);
  }
  *(float4*)(out + (size_t)n*FD + lane*4) = o;
}

// ---------------- layer 3: GEMV [N,256]@[256,1] then scalar GAT ----------------
__global__ __launch_bounds__(256) void gemv3(const float* __restrict__ A, const float* __restrict__ W,
                                             float* __restrict__ h3){
  int n = (blockIdx.x*blockDim.x + threadIdx.x) >> 6;
  int lane = threadIdx.x & 63;
  if (n >= NN) return;
  float4 a = *(const float4*)(A + (size_t)n*FD + lane*4);
  float4 w = *(const float4*)(W + lane*4);
  float p = a.x*w.x + a.y*w.y + a.z*w.z + a.w*w.w;
  for (int off=32; off; off>>=1) p += __shfl_xor(p, off);
  if (lane==0) h3[n] = p;
}

__global__ __launch_bounds__(256) void gat_agg3(const float* __restrict__ h3, const int* __restrict__ indptr,
                                                const int* __restrict__ csr, const float* __restrict__ asrc,
                                                const float* __restrict__ adst, const float* __restrict__ b3,
                                                float* __restrict__ out){
  int n = blockIdx.x*blockDim.x + threadIdx.x;
  if (n >= NN) return;
  float as = asrc[0], ad = adst[0];
  float hd = h3[n]*ad;
  int base = indptr[n], end = indptr[n+1];
  float m = -1e30f;
  for (int e=base; e<end; ++e){
    float l = lrelu(as*h3[csr[e]] + hd);
    m = fmaxf(m, l);
  }
  float s = 0.f, w = 0.f;
  for (int e=base; e<end; ++e){
    float hv = h3[csr[e]];
    float l = lrelu(as*hv + hd);
    float ee = expf(l - m);
    s += ee; w += ee*hv;
  }
  out[n] = w/(s + 1e-16f) + b3[0];
}

extern "C" void kernel_launch(void* const* d_in, const int* in_sizes, int n_in,
                              void* d_out, int out_size, void* d_ws, size_t ws_size,
                              hipStream_t stream){
  const float* x   = (const float*)d_in[0];
  const int*   ei  = (const int*)d_in[1];
  const float* W1  = (const float*)d_in[2];
  const float* as1 = (const float*)d_in[3];
  const float* ad1 = (const float*)d_in[4];
  const float* b1  = (const float*)d_in[5];
  const float* W2  = (const float*)d_in[6];
  const float* as2 = (const float*)d_in[7];
  const float* ad2 = (const float*)d_in[8];
  const float* b2  = (const float*)d_in[9];
  const float* W3  = (const float*)d_in[10];
  const float* as3 = (const float*)d_in[11];
  const float* ad3 = (const float*)d_in[12];
  const float* b3  = (const float*)d_in[13];
  float* outp = (float*)d_out;

  char* w = (char*)d_ws;
  size_t off = 0;
  auto alloc = [&](size_t bytes)->void*{
    void* p = w + off; off += (bytes + 255) & ~(size_t)255; return p;
  };
  float* hbuf  = (float*)alloc((size_t)NN*FD*4);   // 51.2 MB
  float* obuf  = (float*)alloc((size_t)NN*FD*4);   // 51.2 MB
  float* al    = (float*)alloc((size_t)NN*8*4);    // 1.6 MB
  int*   indptr= (int*)alloc((size_t)(NN+1)*4);
  int*   cursor= (int*)alloc((size_t)NN*4);
  int*   csr   = (int*)alloc((size_t)NET*4);       // 2.8 MB
  int*   bsums = (int*)alloc(64*4);
  float* h3    = (float*)alloc((size_t)NN*4);

  // ---- CSR build (once; same graph for all layers) ----
  hipMemsetAsync(cursor, 0, (size_t)NN*4, stream);
  count_deg<<<(NET+255)/256, 256, 0, stream>>>(ei, cursor);
  int nb = (NN+1023)/1024;
  scan_block<<<nb, 256, 0, stream>>>(cursor, indptr, bsums);
  scan_tops<<<1, 64, 0, stream>>>(bsums, nb);
  scan_add<<<(NN+255)/256, 256, 0, stream>>>(indptr, bsums, cursor);
  scatter_csr<<<(NET+255)/256, 256, 0, stream>>>(ei, cursor, csr);

  dim3 gemm_grid(FD/128, (NN+127)/128);
  int node_wave_blocks = (NN*64+255)/256;

  // ---- layer 1 ----
  gemm_f32<<<gemm_grid, 256, 0, stream>>>(x, W1, hbuf, NN, 128, FD);
  al_kernel<<<node_wave_blocks, 256, 0, stream>>>(hbuf, as1, ad1, al);
  gat_agg<<<node_wave_blocks, 256, 0, stream>>>(hbuf, al, indptr, csr, b1, obuf, 1);
  // ---- layer 2 ----
  gemm_f32<<<gemm_grid, 256, 0, stream>>>(obuf, W2, hbuf, NN, 256, FD);
  al_kernel<<<node_wave_blocks, 256, 0, stream>>>(hbuf, as2, ad2, al);
  gat_agg<<<node_wave_blocks, 256, 0, stream>>>(hbuf, al, indptr, csr, b2, obuf, 1);
  // ---- layer 3 ----
  gemv3<<<node_wave_blocks, 256, 0, stream>>>(obuf, W3, h3);
  gat_agg3<<<(NN+255)/256, 256, 0, stream>>>(h3, indptr, csr, as3, ad3, b3, outp);
}

// Round 3
// 471.005 us; speedup vs baseline: 1.2470x; 1.2249x over previous
//
#include <hip/hip_runtime.h>
#include <math.h>

#define NN 50000     // nodes
#define NE 650000    // edges (without self loops)
#define NET 700000   // NE + NN self loops
#define FD 256       // H*C = 4*64
#define NEG 0.2f

static __device__ __forceinline__ float lrelu(float v){ return v > 0.f ? v : NEG*v; }

// bf16 helpers (round-to-nearest-even)
static __device__ __forceinline__ unsigned short f2bf(float f){
  union { float f; unsigned u; } v; v.f = f;
  unsigned r = v.u + 0x7fff + ((v.u >> 16) & 1);
  return (unsigned short)(r >> 16);
}
static __device__ __forceinline__ float bf2f(unsigned short h){
  union { unsigned u; float f; } v; v.u = ((unsigned)h) << 16;
  return v.f;
}

typedef __attribute__((ext_vector_type(8))) short short8_t;  // 8 bf16 = 4 VGPR
typedef __attribute__((ext_vector_type(4))) float f32x4;

// ---------------- CSR build (graph identical for all 3 layers) ----------------
__global__ void count_deg(const int* __restrict__ ei, int* __restrict__ deg){
  int e = blockIdx.x*blockDim.x + threadIdx.x;
  if (e >= NET) return;
  int d = (e < NE) ? ei[NE + e] : (e - NE);
  atomicAdd(&deg[d], 1);
}

__global__ void scan_block(const int* __restrict__ deg, int* __restrict__ excl, int* __restrict__ bsums){
  __shared__ int sh[256];
  int t = threadIdx.x;
  int i0 = blockIdx.x*1024 + t*4;
  int v0 = (i0+0 < NN) ? deg[i0+0] : 0;
  int v1 = (i0+1 < NN) ? deg[i0+1] : 0;
  int v2 = (i0+2 < NN) ? deg[i0+2] : 0;
  int v3 = (i0+3 < NN) ? deg[i0+3] : 0;
  int tot = v0+v1+v2+v3;
  sh[t] = tot;
  __syncthreads();
  for (int off=1; off<256; off<<=1){
    int x = (t>=off) ? sh[t-off] : 0;
    __syncthreads();
    sh[t] += x;
    __syncthreads();
  }
  int base = sh[t] - tot;
  if (i0+0 < NN) excl[i0+0] = base;
  if (i0+1 < NN) excl[i0+1] = base + v0;
  if (i0+2 < NN) excl[i0+2] = base + v0+v1;
  if (i0+3 < NN) excl[i0+3] = base + v0+v1+v2;
  if (t == 255) bsums[blockIdx.x] = sh[255];
}

__global__ void scan_tops(int* bsums, int nb){
  if (threadIdx.x==0 && blockIdx.x==0){
    int run=0;
    for (int i=0;i<nb;i++){ int x=bsums[i]; bsums[i]=run; run+=x; }
  }
}

__global__ void scan_add(int* __restrict__ indptr, const int* __restrict__ bsums, int* __restrict__ cursor){
  int i = blockIdx.x*blockDim.x + threadIdx.x;
  if (i < NN){
    int v = indptr[i] + bsums[i>>10];
    indptr[i] = v;
    cursor[i] = v;
  }
  if (i == 0) indptr[NN] = NET;
}

__global__ void scatter_csr(const int* __restrict__ ei, int* __restrict__ cursor, int* __restrict__ csr){
  int e = blockIdx.x*blockDim.x + threadIdx.x;
  if (e >= NET) return;
  int s, d;
  if (e < NE){ s = ei[e]; d = ei[NE+e]; } else { s = e-NE; d = e-NE; }
  int pos = atomicAdd(&cursor[d], 1);
  csr[pos] = s;
}

// ---------------- B[K][256] fp32 -> Bt_hi/Bt_lo [256][K] bf16 (split) ----------------
__global__ void castBt(const float* __restrict__ B, unsigned short* __restrict__ bth,
                       unsigned short* __restrict__ btl, int K){
  int idx = blockIdx.x*blockDim.x + threadIdx.x;   // K*256 total
  if (idx >= K*256) return;
  int k = idx >> 8, n = idx & 255;
  float f = B[idx];
  unsigned short h = f2bf(f);
  float lo = f - bf2f(h);
  bth[n*K + k] = h;
  btl[n*K + k] = f2bf(lo);
}

// ---------------- split-bf16 MFMA GEMM ----------------
// C[M,Nc] = A[M,K] @ B[K,Nc], A fp32 (split to hi/lo bf16 during LDS staging),
// B pre-split as Bt_hi/Bt_lo [Nc][K].  Also emits Cb = bf16(C) for the gather.
// Tile 128x128, BK=32; 4 waves, each computes 64x64 via 4x4 grid of 16x16x32 MFMAs.
// acc = Ahi*Bhi + Ahi*Blo + Alo*Bhi  (~fp32-equivalent precision).
#define LDA 40   // padded k-stride (bf16 elems): 80 B rows -> <=2-way LDS bank aliasing
__global__ __launch_bounds__(256, 1) void gemm_mfma(const float* __restrict__ A,
                                                    const unsigned short* __restrict__ Bth,
                                                    const unsigned short* __restrict__ Btl,
                                                    float* __restrict__ C, unsigned short* __restrict__ Cb,
                                                    int M, int K, int Nc){
  __shared__ unsigned short Ah[128*LDA], Al[128*LDA], Bh[128*LDA], Bl[128*LDA]; // 40 KB
  int t = threadIdx.x;
  int wave = t >> 6, lane = t & 63;
  int wm = wave >> 1, wn = wave & 1;
  int quad = lane >> 4, l16 = lane & 15;
  int bm0 = blockIdx.y*128, bn0 = blockIdx.x*128;

  f32x4 acc[4][4];
  #pragma unroll
  for (int i=0;i<4;i++)
    #pragma unroll
    for (int j=0;j<4;j++) acc[i][j] = (f32x4){0.f,0.f,0.f,0.f};

  for (int k0 = 0; k0 < K; k0 += 32){
    // global loads (before barrier so they overlap the previous compute's tail)
    float4 av[4];
    #pragma unroll
    for (int c=0;c<4;c++){
      int q = c*256 + t;
      int row = q >> 3, kg = (q & 7)*4;
      int gr = bm0 + row;
      av[c] = (gr < M) ? *(const float4*)(A + (size_t)gr*K + k0 + kg)
                       : make_float4(0.f,0.f,0.f,0.f);
    }
    uint4 bh4[2], bl4[2];
    #pragma unroll
    for (int c=0;c<2;c++){
      int q = c*256 + t;
      int n = q >> 2, kg = (q & 3)*8;
      size_t off = (size_t)(bn0 + n)*K + k0 + kg;
      bh4[c] = *(const uint4*)(Bth + off);
      bl4[c] = *(const uint4*)(Btl + off);
    }
    __syncthreads();   // previous iter's frag reads done
    #pragma unroll
    for (int c=0;c<4;c++){
      int q = c*256 + t;
      int row = q >> 3, kg = (q & 7)*4;
      ushort4 h4, l4;
      h4.x = f2bf(av[c].x); l4.x = f2bf(av[c].x - bf2f(h4.x));
      h4.y = f2bf(av[c].y); l4.y = f2bf(av[c].y - bf2f(h4.y));
      h4.z = f2bf(av[c].z); l4.z = f2bf(av[c].z - bf2f(h4.z));
      h4.w = f2bf(av[c].w); l4.w = f2bf(av[c].w - bf2f(h4.w));
      *(ushort4*)&Ah[row*LDA + kg] = h4;
      *(ushort4*)&Al[row*LDA + kg] = l4;
    }
    #pragma unroll
    for (int c=0;c<2;c++){
      int q = c*256 + t;
      int n = q >> 2, kg = (q & 3)*8;
      *(uint4*)&Bh[n*LDA + kg] = bh4[c];
      *(uint4*)&Bl[n*LDA + kg] = bl4[c];
    }
    __syncthreads();

    short8_t afh[4], afl[4], bfh[4], bfl[4];
    #pragma unroll
    for (int mt=0; mt<4; ++mt){
      int row = wm*64 + mt*16 + l16;
      afh[mt] = *(short8_t*)&Ah[row*LDA + quad*8];
      afl[mt] = *(short8_t*)&Al[row*LDA + quad*8];
    }
    #pragma unroll
    for (int nt=0; nt<4; ++nt){
      int col = wn*64 + nt*16 + l16;
      bfh[nt] = *(short8_t*)&Bh[col*LDA + quad*8];
      bfl[nt] = *(short8_t*)&Bl[col*LDA + quad*8];
    }
    #pragma unroll
    for (int mt=0; mt<4; ++mt)
      #pragma unroll
      for (int nt=0; nt<4; ++nt){
        acc[mt][nt] = __builtin_amdgcn_mfma_f32_16x16x32_bf16(afh[mt], bfh[nt], acc[mt][nt], 0,0,0);
        acc[mt][nt] = __builtin_amdgcn_mfma_f32_16x16x32_bf16(afh[mt], bfl[nt], acc[mt][nt], 0,0,0);
        acc[mt][nt] = __builtin_amdgcn_mfma_f32_16x16x32_bf16(afl[mt], bfh[nt], acc[mt][nt], 0,0,0);
      }
  }

  // epilogue: C fp32 + Cb bf16.  C/D layout: col=lane&15, row=quad*4+reg (m89-verified)
  #pragma unroll
  for (int mt=0; mt<4; ++mt){
    #pragma unroll
    for (int r=0; r<4; ++r){
      int row = bm0 + wm*64 + mt*16 + quad*4 + r;
      if (row < M){
        #pragma unroll
        for (int nt=0; nt<4; ++nt){
          int col = bn0 + wn*64 + nt*16 + l16;
          float v = acc[mt][nt][r];
          C[(size_t)row*Nc + col] = v;
          Cb[(size_t)row*Nc + col] = f2bf(v);
        }
      }
    }
  }
}

// ---------------- per-node attention coefficients al_src/al_dst [N,4]+[N,4] ----------------
__global__ __launch_bounds__(256) void al_kernel(const float* __restrict__ h, const float* __restrict__ a_src,
                                                 const float* __restrict__ a_dst, float* __restrict__ al){
  int n = (blockIdx.x*blockDim.x + threadIdx.x) >> 6;
  int lane = threadIdx.x & 63;
  if (n >= NN) return;
  int head = lane >> 4;
  float4 hv = *(const float4*)(h + (size_t)n*FD + lane*4);
  float4 as = *(const float4*)(a_src + lane*4);
  float4 ad = *(const float4*)(a_dst + lane*4);
  float ps = hv.x*as.x + hv.y*as.y + hv.z*as.z + hv.w*as.w;
  float pd = hv.x*ad.x + hv.y*ad.y + hv.z*ad.z + hv.w*ad.w;
  for (int off=1; off<16; off<<=1){
    ps += __shfl_xor(ps, off);
    pd += __shfl_xor(pd, off);
  }
  if ((lane & 15) == 0){
    al[n*8 + head]     = ps;
    al[n*8 + 4 + head] = pd;
  }
}

// ---------------- GAT aggregation: one wave per destination node, bf16 gather ----------------
__global__ __launch_bounds__(256) void gat_agg(const unsigned short* __restrict__ hb, const float* __restrict__ al,
                                               const int* __restrict__ indptr, const int* __restrict__ csr,
                                               const float* __restrict__ bias, float* __restrict__ out, int elu){
  int n = (blockIdx.x*blockDim.x + threadIdx.x) >> 6;
  int lane = threadIdx.x & 63;
  if (n >= NN) return;
  int head = lane >> 4;
  int base = indptr[n], deg = indptr[n+1] - base;
  float4 ald = *(const float4*)(al + n*8 + 4);

  // pass 1: per-head max over incident edges
  float4 mx = make_float4(-1e30f,-1e30f,-1e30f,-1e30f);
  for (int j = lane; j < deg; j += 64){
    int s = csr[base+j];
    float4 als = *(const float4*)(al + s*8);
    mx.x = fmaxf(mx.x, lrelu(als.x + ald.x));
    mx.y = fmaxf(mx.y, lrelu(als.y + ald.y));
    mx.z = fmaxf(mx.z, lrelu(als.z + ald.z));
    mx.w = fmaxf(mx.w, lrelu(als.w + ald.w));
  }
  for (int off=32; off; off>>=1){
    mx.x = fmaxf(mx.x, __shfl_xor(mx.x, off));
    mx.y = fmaxf(mx.y, __shfl_xor(mx.y, off));
    mx.z = fmaxf(mx.z, __shfl_xor(mx.z, off));
    mx.w = fmaxf(mx.w, __shfl_xor(mx.w, off));
  }

  // pass 2: chunked exp + cooperative weighted gather of hb[src] (bf16, 8 B/lane/edge)
  float4 esum = make_float4(0.f,0.f,0.f,0.f);
  float4 acc  = make_float4(0.f,0.f,0.f,0.f);
  for (int j0 = 0; j0 < deg; j0 += 64){
    int j = j0 + lane;
    float4 e4 = make_float4(0.f,0.f,0.f,0.f);
    int sj = 0;
    if (j < deg){
      sj = csr[base+j];
      float4 als = *(const float4*)(al + sj*8);
      e4.x = expf(lrelu(als.x + ald.x) - mx.x);
      e4.y = expf(lrelu(als.y + ald.y) - mx.y);
      e4.z = expf(lrelu(als.z + ald.z) - mx.z);
      e4.w = expf(lrelu(als.w + ald.w) - mx.w);
      esum.x += e4.x; esum.y += e4.y; esum.z += e4.z; esum.w += e4.w;
    }
    int cnt = min(64, deg - j0);
    for (int k = 0; k < cnt; ++k){
      int sk = __shfl(sj, k);
      float ex = __shfl(e4.x, k);
      float ey = __shfl(e4.y, k);
      float ez = __shfl(e4.z, k);
      float ew = __shfl(e4.w, k);
      float ek = (head==0)?ex:(head==1)?ey:(head==2)?ez:ew;
      ushort4 u = *(const ushort4*)(hb + (size_t)sk*FD + lane*4);
      acc.x += ek*bf2f(u.x); acc.y += ek*bf2f(u.y);
      acc.z += ek*bf2f(u.z); acc.w += ek*bf2f(u.w);
    }
  }
  for (int off=32; off; off>>=1){
    esum.x += __shfl_xor(esum.x, off);
    esum.y += __shfl_xor(esum.y, off);
    esum.z += __shfl_xor(esum.z, off);
    esum.w += __shfl_xor(esum.w, off);
  }
  float sH = (head==0)?esum.x:(head==1)?esum.y:(head==2)?esum.z:esum.w;
  float inv = 1.f/(sH + 1e-16f);
  float4 b4 = *(const float4*)(bias + lane*4);
  float4 o;
  o.x = acc.x*inv + b4.x;
  o.y = acc.y*inv + b4.y;
  o.z = acc.z*inv + b4.z;
  o.w = acc.w*inv + b4.w;
  if (elu){
    o.x = o.x>0.f ? o.x : expm1f(o.x);
    o.y = o.y>0.f ? o.y : expm1f(o.y);
    o.z = o.z>0.f ? o.z : expm1f(o.z);
    o.w = o.w>0.f ? o.w : expm1f(o.w);
  }
  *(float4*)(out + (size_t)n*FD + lane*4) = o;
}

// ---------------- layer 3: GEMV [N,256]@[256,1] then scalar GAT ----------------
__global__ __launch_bounds__(256) void gemv3(const float* __restrict__ A, const float* __restrict__ W,
                                             float* __restrict__ h3){
  int n = (blockIdx.x*blockDim.x + threadIdx.x) >> 6;
  int lane = threadIdx.x & 63;
  if (n >= NN) return;
  float4 a = *(const float4*)(A + (size_t)n*FD + lane*4);
  float4 w = *(const float4*)(W + lane*4);
  float p = a.x*w.x + a.y*w.y + a.z*w.z + a.w*w.w;
  for (int off=32; off; off>>=1) p += __shfl_xor(p, off);
  if (lane==0) h3[n] = p;
}

__global__ __launch_bounds__(256) void gat_agg3(const float* __restrict__ h3, const int* __restrict__ indptr,
                                                const int* __restrict__ csr, const float* __restrict__ asrc,
                                                const float* __restrict__ adst, const float* __restrict__ b3,
                                                float* __restrict__ out){
  int n = blockIdx.x*blockDim.x + threadIdx.x;
  if (n >= NN) return;
  float as = asrc[0], ad = adst[0];
  float hd = h3[n]*ad;
  int base = indptr[n], end = indptr[n+1];
  float m = -1e30f;
  for (int e=base; e<end; ++e){
    float l = lrelu(as*h3[csr[e]] + hd);
    m = fmaxf(m, l);
  }
  float s = 0.f, w = 0.f;
  for (int e=base; e<end; ++e){
    float hv = h3[csr[e]];
    float l = lrelu(as*hv + hd);
    float ee = expf(l - m);
    s += ee; w += ee*hv;
  }
  out[n] = w/(s + 1e-16f) + b3[0];
}

extern "C" void kernel_launch(void* const* d_in, const int* in_sizes, int n_in,
                              void* d_out, int out_size, void* d_ws, size_t ws_size,
                              hipStream_t stream){
  const float* x   = (const float*)d_in[0];
  const int*   ei  = (const int*)d_in[1];
  const float* W1  = (const float*)d_in[2];
  const float* as1 = (const float*)d_in[3];
  const float* ad1 = (const float*)d_in[4];
  const float* b1  = (const float*)d_in[5];
  const float* W2  = (const float*)d_in[6];
  const float* as2 = (const float*)d_in[7];
  const float* ad2 = (const float*)d_in[8];
  const float* b2  = (const float*)d_in[9];
  const float* W3  = (const float*)d_in[10];
  const float* as3 = (const float*)d_in[11];
  const float* ad3 = (const float*)d_in[12];
  const float* b3  = (const float*)d_in[13];
  float* outp = (float*)d_out;

  char* w = (char*)d_ws;
  size_t off = 0;
  auto alloc = [&](size_t bytes)->void*{
    void* p = w + off; off += (bytes + 255) & ~(size_t)255; return p;
  };
  float*          hbuf  = (float*)alloc((size_t)NN*FD*4);          // 51.2 MB
  float*          obuf  = (float*)alloc((size_t)NN*FD*4);          // 51.2 MB
  unsigned short* hb    = (unsigned short*)alloc((size_t)NN*FD*2); // 25.6 MB
  float*          al    = (float*)alloc((size_t)NN*8*4);           // 1.6 MB
  int*   indptr= (int*)alloc((size_t)(NN+1)*4);
  int*   cursor= (int*)alloc((size_t)NN*4);
  int*   csr   = (int*)alloc((size_t)NET*4);                       // 2.8 MB
  int*   bsums = (int*)alloc(64*4);
  float* h3    = (float*)alloc((size_t)NN*4);
  unsigned short* bt1h = (unsigned short*)alloc((size_t)256*128*2);
  unsigned short* bt1l = (unsigned short*)alloc((size_t)256*128*2);
  unsigned short* bt2h = (unsigned short*)alloc((size_t)256*256*2);
  unsigned short* bt2l = (unsigned short*)alloc((size_t)256*256*2);

  // ---- CSR build (once; same graph for all layers) ----
  hipMemsetAsync(cursor, 0, (size_t)NN*4, stream);
  count_deg<<<(NET+255)/256, 256, 0, stream>>>(ei, cursor);
  int nb = (NN+1023)/1024;
  scan_block<<<nb, 256, 0, stream>>>(cursor, indptr, bsums);
  scan_tops<<<1, 64, 0, stream>>>(bsums, nb);
  scan_add<<<(NN+255)/256, 256, 0, stream>>>(indptr, bsums, cursor);
  scatter_csr<<<(NET+255)/256, 256, 0, stream>>>(ei, cursor, csr);

  // ---- weight split/transpose (tiny) ----
  castBt<<<128, 256, 0, stream>>>(W1, bt1h, bt1l, 128);
  castBt<<<256, 256, 0, stream>>>(W2, bt2h, bt2l, 256);

  dim3 gemm_grid(FD/128, (NN+127)/128);
  int node_wave_blocks = (NN*64+255)/256;

  // ---- layer 1 ----
  gemm_mfma<<<gemm_grid, 256, 0, stream>>>(x, bt1h, bt1l, hbuf, hb, NN, 128, FD);
  al_kernel<<<node_wave_blocks, 256, 0, stream>>>(hbuf, as1, ad1, al);
  gat_agg<<<node_wave_blocks, 256, 0, stream>>>(hb, al, indptr, csr, b1, obuf, 1);
  // ---- layer 2 ----
  gemm_mfma<<<gemm_grid, 256, 0, stream>>>(obuf, bt2h, bt2l, hbuf, hb, NN, 256, FD);
  al_kernel<<<node_wave_blocks, 256, 0, stream>>>(hbuf, as2, ad2, al);
  gat_agg<<<node_wave_blocks, 256, 0, stream>>>(hb, al, indptr, csr, b2, obuf, 1);
  // ---- layer 3 ----
  gemv3<<<node_wave_blocks, 256, 0, stream>>>(obuf, W3, h3);
  gat_agg3<<<(NN+255)/256, 256, 0, stream>>>(h3, indptr, csr, as3, ad3, b3, outp);
}

// Round 4
// 438.022 us; speedup vs baseline: 1.3409x; 1.0753x over previous
//
#include <hip/hip_runtime.h>
#include <math.h>

#define NN 50000     // nodes
#define NE 650000    // edges (without self loops)
#define NET 700000   // NE + NN self loops
#define FD 256       // H*C = 4*64
#define NEG 0.2f

static __device__ __forceinline__ float lrelu(float v){ return v > 0.f ? v : NEG*v; }

// bf16 helpers
static __device__ __forceinline__ unsigned short f2bf(float f){
  union { float f; unsigned u; } v; v.f = f;
  unsigned r = v.u + 0x7fff + ((v.u >> 16) & 1);
  return (unsigned short)(r >> 16);
}
static __device__ __forceinline__ float bf2f(unsigned short h){
  union { unsigned u; float f; } v; v.u = ((unsigned)h) << 16;
  return v.f;
}
static __device__ __forceinline__ float bflo(unsigned u){ return __uint_as_float(u << 16); }
static __device__ __forceinline__ float bfhi(unsigned u){ return __uint_as_float(u & 0xffff0000u); }

typedef __attribute__((ext_vector_type(8))) short short8_t;  // 8 bf16 = 4 VGPR
typedef __attribute__((ext_vector_type(4))) float f32x4;

// ---------------- CSR build (graph identical for all 3 layers) ----------------
__global__ void count_deg(const int* __restrict__ ei, int* __restrict__ deg){
  int e = blockIdx.x*blockDim.x + threadIdx.x;
  if (e >= NET) return;
  int d = (e < NE) ? ei[NE + e] : (e - NE);
  atomicAdd(&deg[d], 1);
}

__global__ void scan_block(const int* __restrict__ deg, int* __restrict__ excl, int* __restrict__ bsums){
  __shared__ int sh[256];
  int t = threadIdx.x;
  int i0 = blockIdx.x*1024 + t*4;
  int v0 = (i0+0 < NN) ? deg[i0+0] : 0;
  int v1 = (i0+1 < NN) ? deg[i0+1] : 0;
  int v2 = (i0+2 < NN) ? deg[i0+2] : 0;
  int v3 = (i0+3 < NN) ? deg[i0+3] : 0;
  int tot = v0+v1+v2+v3;
  sh[t] = tot;
  __syncthreads();
  for (int off=1; off<256; off<<=1){
    int x = (t>=off) ? sh[t-off] : 0;
    __syncthreads();
    sh[t] += x;
    __syncthreads();
  }
  int base = sh[t] - tot;
  if (i0+0 < NN) excl[i0+0] = base;
  if (i0+1 < NN) excl[i0+1] = base + v0;
  if (i0+2 < NN) excl[i0+2] = base + v0+v1;
  if (i0+3 < NN) excl[i0+3] = base + v0+v1+v2;
  if (t == 255) bsums[blockIdx.x] = sh[255];
}

__global__ void scan_tops(int* bsums, int nb){
  if (threadIdx.x==0 && blockIdx.x==0){
    int run=0;
    for (int i=0;i<nb;i++){ int x=bsums[i]; bsums[i]=run; run+=x; }
  }
}

__global__ void scan_add(int* __restrict__ indptr, const int* __restrict__ bsums, int* __restrict__ cursor){
  int i = blockIdx.x*blockDim.x + threadIdx.x;
  if (i < NN){
    int v = indptr[i] + bsums[i>>10];
    indptr[i] = v;
    cursor[i] = v;
  }
  if (i == 0) indptr[NN] = NET;
}

__global__ void scatter_csr(const int* __restrict__ ei, int* __restrict__ cursor, int* __restrict__ csr){
  int e = blockIdx.x*blockDim.x + threadIdx.x;
  if (e >= NET) return;
  int s, d;
  if (e < NE){ s = ei[e]; d = ei[NE+e]; } else { s = e-NE; d = e-NE; }
  int pos = atomicAdd(&cursor[d], 1);
  csr[pos] = s;
}

// ---------------- B[K][256] fp32 -> Bt_hi/Bt_lo [256][K] bf16 (split) ----------------
__global__ void castBt(const float* __restrict__ B, unsigned short* __restrict__ bth,
                       unsigned short* __restrict__ btl, int K){
  int idx = blockIdx.x*blockDim.x + threadIdx.x;
  if (idx >= K*256) return;
  int k = idx >> 8, n = idx & 255;
  float f = B[idx];
  unsigned short h = f2bf(f);
  float lo = f - bf2f(h);
  bth[n*K + k] = h;
  btl[n*K + k] = f2bf(lo);
}

// ---------------- split-bf16 MFMA GEMM, fused al epilogue ----------------
// C = A @ B with A either fp32 (PRESPLIT=false, split in-kernel) or pre-split
// hi/lo bf16 (PRESPLIT=true). Emits only Cb (bf16 C) plus per-(row,head)
// al_src/al_dst dot products reduced from the fp32 accumulator (no fp32 C).
#define LDA 40
template<bool PRESPLIT>
__global__ __launch_bounds__(256, 1) void gemm_mfma(const float* __restrict__ A,
                                                    const unsigned short* __restrict__ Ahg,
                                                    const unsigned short* __restrict__ Alg,
                                                    const unsigned short* __restrict__ Bth,
                                                    const unsigned short* __restrict__ Btl,
                                                    unsigned short* __restrict__ Cb,
                                                    const float* __restrict__ a_src,
                                                    const float* __restrict__ a_dst,
                                                    float* __restrict__ al,
                                                    int M, int K, int Nc){
  __shared__ unsigned short Ah[128*LDA], Al[128*LDA], Bh[128*LDA], Bl[128*LDA]; // 40 KB
  int t = threadIdx.x;
  int wave = t >> 6, lane = t & 63;
  int wm = wave >> 1, wn = wave & 1;
  int quad = lane >> 4, l16 = lane & 15;
  int bm0 = blockIdx.y*128, bn0 = blockIdx.x*128;

  f32x4 acc[4][4];
  #pragma unroll
  for (int i=0;i<4;i++)
    #pragma unroll
    for (int j=0;j<4;j++) acc[i][j] = (f32x4){0.f,0.f,0.f,0.f};

  for (int k0 = 0; k0 < K; k0 += 32){
    float4 av[4];
    uint4 ah4[2], al4[2];
    if (PRESPLIT){
      #pragma unroll
      for (int c=0;c<2;c++){
        int q = c*256 + t;
        int row = q >> 2, kg = (q & 3)*8;
        int gr = bm0 + row;
        size_t off = (size_t)gr*K + k0 + kg;
        if (gr < M){ ah4[c] = *(const uint4*)(Ahg + off); al4[c] = *(const uint4*)(Alg + off); }
        else { ah4[c] = make_uint4(0,0,0,0); al4[c] = make_uint4(0,0,0,0); }
      }
    } else {
      #pragma unroll
      for (int c=0;c<4;c++){
        int q = c*256 + t;
        int row = q >> 3, kg = (q & 7)*4;
        int gr = bm0 + row;
        av[c] = (gr < M) ? *(const float4*)(A + (size_t)gr*K + k0 + kg)
                         : make_float4(0.f,0.f,0.f,0.f);
      }
    }
    uint4 bh4[2], bl4[2];
    #pragma unroll
    for (int c=0;c<2;c++){
      int q = c*256 + t;
      int n = q >> 2, kg = (q & 3)*8;
      size_t off = (size_t)(bn0 + n)*K + k0 + kg;
      bh4[c] = *(const uint4*)(Bth + off);
      bl4[c] = *(const uint4*)(Btl + off);
    }
    __syncthreads();
    if (PRESPLIT){
      #pragma unroll
      for (int c=0;c<2;c++){
        int q = c*256 + t;
        int row = q >> 2, kg = (q & 3)*8;
        *(uint4*)&Ah[row*LDA + kg] = ah4[c];
        *(uint4*)&Al[row*LDA + kg] = al4[c];
      }
    } else {
      #pragma unroll
      for (int c=0;c<4;c++){
        int q = c*256 + t;
        int row = q >> 3, kg = (q & 7)*4;
        ushort4 h4, l4;
        h4.x = f2bf(av[c].x); l4.x = f2bf(av[c].x - bf2f(h4.x));
        h4.y = f2bf(av[c].y); l4.y = f2bf(av[c].y - bf2f(h4.y));
        h4.z = f2bf(av[c].z); l4.z = f2bf(av[c].z - bf2f(h4.z));
        h4.w = f2bf(av[c].w); l4.w = f2bf(av[c].w - bf2f(h4.w));
        *(ushort4*)&Ah[row*LDA + kg] = h4;
        *(ushort4*)&Al[row*LDA + kg] = l4;
      }
    }
    #pragma unroll
    for (int c=0;c<2;c++){
      int q = c*256 + t;
      int n = q >> 2, kg = (q & 3)*8;
      *(uint4*)&Bh[n*LDA + kg] = bh4[c];
      *(uint4*)&Bl[n*LDA + kg] = bl4[c];
    }
    __syncthreads();

    short8_t afh[4], afl[4], bfh[4], bfl[4];
    #pragma unroll
    for (int mt=0; mt<4; ++mt){
      int row = wm*64 + mt*16 + l16;
      afh[mt] = *(short8_t*)&Ah[row*LDA + quad*8];
      afl[mt] = *(short8_t*)&Al[row*LDA + quad*8];
    }
    #pragma unroll
    for (int nt=0; nt<4; ++nt){
      int col = wn*64 + nt*16 + l16;
      bfh[nt] = *(short8_t*)&Bh[col*LDA + quad*8];
      bfl[nt] = *(short8_t*)&Bl[col*LDA + quad*8];
    }
    #pragma unroll
    for (int mt=0; mt<4; ++mt)
      #pragma unroll
      for (int nt=0; nt<4; ++nt){
        acc[mt][nt] = __builtin_amdgcn_mfma_f32_16x16x32_bf16(afh[mt], bfh[nt], acc[mt][nt], 0,0,0);
        acc[mt][nt] = __builtin_amdgcn_mfma_f32_16x16x32_bf16(afh[mt], bfl[nt], acc[mt][nt], 0,0,0);
        acc[mt][nt] = __builtin_amdgcn_mfma_f32_16x16x32_bf16(afl[mt], bfh[nt], acc[mt][nt], 0,0,0);
      }
  }

  // epilogue: Cb bf16 + fused al_src/al_dst.  One head per wave: head_w.
  // C/D layout: col=lane&15, row=quad*4+reg (m89-verified).
  int head_w = (bn0 >> 6) + wn;
  float cs[4], cd[4];
  #pragma unroll
  for (int nt=0; nt<4; ++nt){
    cs[nt] = a_src[head_w*64 + nt*16 + l16];
    cd[nt] = a_dst[head_w*64 + nt*16 + l16];
  }
  #pragma unroll
  for (int mt=0; mt<4; ++mt){
    #pragma unroll
    for (int r=0; r<4; ++r){
      int row = bm0 + wm*64 + mt*16 + quad*4 + r;
      float psrc = 0.f, pdst = 0.f;
      if (row < M){
        #pragma unroll
        for (int nt=0; nt<4; ++nt){
          int col = bn0 + wn*64 + nt*16 + l16;
          float v = acc[mt][nt][r];
          psrc += v*cs[nt];
          pdst += v*cd[nt];
          Cb[(size_t)row*Nc + col] = f2bf(v);
        }
      }
      #pragma unroll
      for (int off=1; off<16; off<<=1){
        psrc += __shfl_xor(psrc, off);
        pdst += __shfl_xor(pdst, off);
      }
      if (l16 == 0 && row < M){
        al[row*8 + head_w]     = psrc;
        al[row*8 + 4 + head_w] = pdst;
      }
    }
  }
}

// ---------------- gather chunk: 2 edges/iter, 16 B/lane, unroll x2 ----------------
static __device__ __forceinline__ void gather_chunk(int cnt, const float* eb, const int* sb,
                                                    const unsigned short* __restrict__ hb,
                                                    int half, int l32, int head8, float acc[8]){
  for (int tt = 0; tt < cnt; tt += 4){
    int eA = tt + half, eB = tt + 2 + half;
    int iA = (eA < cnt) ? eA : 0;
    int iB = (eB < cnt) ? eB : 0;
    int sA = sb[iA];
    int sB = sb[iB];
    float evA = eb[iA*4 + head8]; if (eA >= cnt) evA = 0.f;
    float evB = eb[iB*4 + head8]; if (eB >= cnt) evB = 0.f;
    uint4 a4 = *(const uint4*)(hb + (size_t)sA*FD + l32*8);
    uint4 b4 = *(const uint4*)(hb + (size_t)sB*FD + l32*8);
    acc[0] += evA*bflo(a4.x); acc[1] += evA*bfhi(a4.x);
    acc[2] += evA*bflo(a4.y); acc[3] += evA*bfhi(a4.y);
    acc[4] += evA*bflo(a4.z); acc[5] += evA*bfhi(a4.z);
    acc[6] += evA*bflo(a4.w); acc[7] += evA*bfhi(a4.w);
    acc[0] += evB*bflo(b4.x); acc[1] += evB*bfhi(b4.x);
    acc[2] += evB*bflo(b4.y); acc[3] += evB*bfhi(b4.y);
    acc[4] += evB*bflo(b4.z); acc[5] += evB*bfhi(b4.z);
    acc[6] += evB*bflo(b4.w); acc[7] += evB*bfhi(b4.w);
  }
}

// ---------------- GAT aggregation v2: wave/node, LDS-staged alpha, hi/lo out ----------------
__global__ __launch_bounds__(256) void gat_agg(const unsigned short* __restrict__ hb,
                                               const float* __restrict__ al,
                                               const int* __restrict__ indptr, const int* __restrict__ csr,
                                               const float* __restrict__ bias,
                                               unsigned short* __restrict__ outh,
                                               unsigned short* __restrict__ outl){
  __shared__ float ebuf[4][256];
  __shared__ int   sbuf[4][64];
  int wv = threadIdx.x >> 6, lane = threadIdx.x & 63;
  int n = blockIdx.x*4 + wv;
  if (n >= NN) return;
  int half = lane >> 5, l32 = lane & 31, head8 = l32 >> 3;
  int base = indptr[n], deg = indptr[n+1] - base;
  float4 ald = *(const float4*)(al + n*8 + 4);
  float* eb = &ebuf[wv][0];
  int*   sb = &sbuf[wv][0];

  float acc[8] = {0.f,0.f,0.f,0.f,0.f,0.f,0.f,0.f};
  float4 esum = make_float4(0.f,0.f,0.f,0.f);

  if (deg <= 64){
    int sj = 0;
    float4 lg = make_float4(-1e30f,-1e30f,-1e30f,-1e30f);
    if (lane < deg){
      sj = csr[base + lane];
      float4 als = *(const float4*)(al + sj*8);
      lg.x = lrelu(als.x + ald.x);
      lg.y = lrelu(als.y + ald.y);
      lg.z = lrelu(als.z + ald.z);
      lg.w = lrelu(als.w + ald.w);
    }
    float4 mx = lg;
    for (int off=32; off; off>>=1){
      mx.x = fmaxf(mx.x, __shfl_xor(mx.x, off));
      mx.y = fmaxf(mx.y, __shfl_xor(mx.y, off));
      mx.z = fmaxf(mx.z, __shfl_xor(mx.z, off));
      mx.w = fmaxf(mx.w, __shfl_xor(mx.w, off));
    }
    float4 e4 = make_float4(0.f,0.f,0.f,0.f);
    if (lane < deg){
      e4.x = expf(lg.x - mx.x); e4.y = expf(lg.y - mx.y);
      e4.z = expf(lg.z - mx.z); e4.w = expf(lg.w - mx.w);
    }
    esum = e4;
    *(float4*)&eb[lane*4] = e4;
    sb[lane] = sj;
    gather_chunk(deg, eb, sb, hb, half, l32, head8, acc);
  } else {
    // generic path (deg > 64): pass-1 max, then chunked
    float4 mx = make_float4(-1e30f,-1e30f,-1e30f,-1e30f);
    for (int j = lane; j < deg; j += 64){
      int s = csr[base+j];
      float4 als = *(const float4*)(al + s*8);
      mx.x = fmaxf(mx.x, lrelu(als.x + ald.x));
      mx.y = fmaxf(mx.y, lrelu(als.y + ald.y));
      mx.z = fmaxf(mx.z, lrelu(als.z + ald.z));
      mx.w = fmaxf(mx.w, lrelu(als.w + ald.w));
    }
    for (int off=32; off; off>>=1){
      mx.x = fmaxf(mx.x, __shfl_xor(mx.x, off));
      mx.y = fmaxf(mx.y, __shfl_xor(mx.y, off));
      mx.z = fmaxf(mx.z, __shfl_xor(mx.z, off));
      mx.w = fmaxf(mx.w, __shfl_xor(mx.w, off));
    }
    for (int j0 = 0; j0 < deg; j0 += 64){
      int j = j0 + lane;
      float4 e4 = make_float4(0.f,0.f,0.f,0.f);
      int sj = 0;
      if (j < deg){
        sj = csr[base+j];
        float4 als = *(const float4*)(al + sj*8);
        e4.x = expf(lrelu(als.x + ald.x) - mx.x);
        e4.y = expf(lrelu(als.y + ald.y) - mx.y);
        e4.z = expf(lrelu(als.z + ald.z) - mx.z);
        e4.w = expf(lrelu(als.w + ald.w) - mx.w);
        esum.x += e4.x; esum.y += e4.y; esum.z += e4.z; esum.w += e4.w;
      }
      *(float4*)&eb[lane*4] = e4;
      sb[lane] = sj;
      gather_chunk(min(64, deg - j0), eb, sb, hb, half, l32, head8, acc);
    }
  }

  for (int off=32; off; off>>=1){
    esum.x += __shfl_xor(esum.x, off);
    esum.y += __shfl_xor(esum.y, off);
    esum.z += __shfl_xor(esum.z, off);
    esum.w += __shfl_xor(esum.w, off);
  }
  // combine the two edge-halves: both halves then hold the full sums
  #pragma unroll
  for (int i=0;i<8;i++) acc[i] += __shfl_xor(acc[i], 32);

  float sH = (head8==0)?esum.x:(head8==1)?esum.y:(head8==2)?esum.z:esum.w;
  float inv = 1.f/(sH + 1e-16f);
  if (half == 0){
    int ch0 = l32*8;
    float4 b0 = *(const float4*)(bias + ch0);
    float4 b1 = *(const float4*)(bias + ch0 + 4);
    float o[8];
    o[0]=acc[0]*inv+b0.x; o[1]=acc[1]*inv+b0.y; o[2]=acc[2]*inv+b0.z; o[3]=acc[3]*inv+b0.w;
    o[4]=acc[4]*inv+b1.x; o[5]=acc[5]*inv+b1.y; o[6]=acc[6]*inv+b1.z; o[7]=acc[7]*inv+b1.w;
    #pragma unroll
    for (int i=0;i<8;i++) o[i] = o[i] > 0.f ? o[i] : expm1f(o[i]);   // elu
    unsigned hi[4], lo[4];
    #pragma unroll
    for (int i=0;i<4;i++){
      unsigned short h0 = f2bf(o[2*i]),   h1 = f2bf(o[2*i+1]);
      unsigned short g0 = f2bf(o[2*i]   - bf2f(h0));
      unsigned short g1 = f2bf(o[2*i+1] - bf2f(h1));
      hi[i] = (unsigned)h0 | ((unsigned)h1 << 16);
      lo[i] = (unsigned)g0 | ((unsigned)g1 << 16);
    }
    *(uint4*)(outh + (size_t)n*FD + ch0) = make_uint4(hi[0],hi[1],hi[2],hi[3]);
    *(uint4*)(outl + (size_t)n*FD + ch0) = make_uint4(lo[0],lo[1],lo[2],lo[3]);
  }
}

// ---------------- layer 3: GEMV [N,256]@[256,1] (hi/lo input) then scalar GAT ----------------
__global__ __launch_bounds__(256) void gemv3(const unsigned short* __restrict__ Ah,
                                             const unsigned short* __restrict__ Al,
                                             const float* __restrict__ W, float* __restrict__ h3){
  int n = (blockIdx.x*blockDim.x + threadIdx.x) >> 6;
  int lane = threadIdx.x & 63;
  if (n >= NN) return;
  ushort4 hv = *(const ushort4*)(Ah + (size_t)n*FD + lane*4);
  ushort4 lv = *(const ushort4*)(Al + (size_t)n*FD + lane*4);
  float4 w = *(const float4*)(W + lane*4);
  float p = (bf2f(hv.x)+bf2f(lv.x))*w.x + (bf2f(hv.y)+bf2f(lv.y))*w.y
          + (bf2f(hv.z)+bf2f(lv.z))*w.z + (bf2f(hv.w)+bf2f(lv.w))*w.w;
  for (int off=32; off; off>>=1) p += __shfl_xor(p, off);
  if (lane==0) h3[n] = p;
}

__global__ __launch_bounds__(256) void gat_agg3(const float* __restrict__ h3, const int* __restrict__ indptr,
                                                const int* __restrict__ csr, const float* __restrict__ asrc,
                                                const float* __restrict__ adst, const float* __restrict__ b3,
                                                float* __restrict__ out){
  int n = blockIdx.x*blockDim.x + threadIdx.x;
  if (n >= NN) return;
  float as = asrc[0], ad = adst[0];
  float hd = h3[n]*ad;
  int base = indptr[n], end = indptr[n+1];
  float m = -1e30f;
  for (int e=base; e<end; ++e){
    float l = lrelu(as*h3[csr[e]] + hd);
    m = fmaxf(m, l);
  }
  float s = 0.f, w = 0.f;
  for (int e=base; e<end; ++e){
    float hv = h3[csr[e]];
    float l = lrelu(as*hv + hd);
    float ee = expf(l - m);
    s += ee; w += ee*hv;
  }
  out[n] = w/(s + 1e-16f) + b3[0];
}

extern "C" void kernel_launch(void* const* d_in, const int* in_sizes, int n_in,
                              void* d_out, int out_size, void* d_ws, size_t ws_size,
                              hipStream_t stream){
  const float* x   = (const float*)d_in[0];
  const int*   ei  = (const int*)d_in[1];
  const float* W1  = (const float*)d_in[2];
  const float* as1 = (const float*)d_in[3];
  const float* ad1 = (const float*)d_in[4];
  const float* b1  = (const float*)d_in[5];
  const float* W2  = (const float*)d_in[6];
  const float* as2 = (const float*)d_in[7];
  const float* ad2 = (const float*)d_in[8];
  const float* b2  = (const float*)d_in[9];
  const float* W3  = (const float*)d_in[10];
  const float* as3 = (const float*)d_in[11];
  const float* ad3 = (const float*)d_in[12];
  const float* b3  = (const float*)d_in[13];
  float* outp = (float*)d_out;

  char* w = (char*)d_ws;
  size_t off = 0;
  auto alloc = [&](size_t bytes)->void*{
    void* p = w + off; off += (bytes + 255) & ~(size_t)255; return p;
  };
  unsigned short* hb  = (unsigned short*)alloc((size_t)NN*FD*2);  // 25.6 MB (Cb of current gemm)
  unsigned short* oh  = (unsigned short*)alloc((size_t)NN*FD*2);  // 25.6 MB (agg out hi)
  unsigned short* ol  = (unsigned short*)alloc((size_t)NN*FD*2);  // 25.6 MB (agg out lo)
  float* al    = (float*)alloc((size_t)NN*8*4);                   // 1.6 MB
  int*   indptr= (int*)alloc((size_t)(NN+1)*4);
  int*   cursor= (int*)alloc((size_t)NN*4);
  int*   csr   = (int*)alloc((size_t)NET*4);                      // 2.8 MB
  int*   bsums = (int*)alloc(64*4);
  float* h3    = (float*)alloc((size_t)NN*4);
  unsigned short* bt1h = (unsigned short*)alloc((size_t)256*128*2);
  unsigned short* bt1l = (unsigned short*)alloc((size_t)256*128*2);
  unsigned short* bt2h = (unsigned short*)alloc((size_t)256*256*2);
  unsigned short* bt2l = (unsigned short*)alloc((size_t)256*256*2);

  // ---- CSR build (once; same graph for all layers) ----
  hipMemsetAsync(cursor, 0, (size_t)NN*4, stream);
  count_deg<<<(NET+255)/256, 256, 0, stream>>>(ei, cursor);
  int nb = (NN+1023)/1024;
  scan_block<<<nb, 256, 0, stream>>>(cursor, indptr, bsums);
  scan_tops<<<1, 64, 0, stream>>>(bsums, nb);
  scan_add<<<(NN+255)/256, 256, 0, stream>>>(indptr, bsums, cursor);
  scatter_csr<<<(NET+255)/256, 256, 0, stream>>>(ei, cursor, csr);

  // ---- weight split/transpose (tiny) ----
  castBt<<<128, 256, 0, stream>>>(W1, bt1h, bt1l, 128);
  castBt<<<256, 256, 0, stream>>>(W2, bt2h, bt2l, 256);

  dim3 gemm_grid(FD/128, (NN+127)/128);
  int agg_blocks = (NN+3)/4;
  int node_wave_blocks = (NN*64+255)/256;

  // ---- layer 1 (A = x fp32, split in-kernel) ----
  gemm_mfma<false><<<gemm_grid, 256, 0, stream>>>(x, nullptr, nullptr, bt1h, bt1l, hb, as1, ad1, al, NN, 128, FD);
  gat_agg<<<agg_blocks, 256, 0, stream>>>(hb, al, indptr, csr, b1, oh, ol);
  // ---- layer 2 (A pre-split by gat_agg) ----
  gemm_mfma<true><<<gemm_grid, 256, 0, stream>>>(nullptr, oh, ol, bt2h, bt2l, hb, as2, ad2, al, NN, 256, FD);
  gat_agg<<<agg_blocks, 256, 0, stream>>>(hb, al, indptr, csr, b2, oh, ol);
  // ---- layer 3 ----
  gemv3<<<node_wave_blocks, 256, 0, stream>>>(oh, ol, W3, h3);
  gat_agg3<<<(NN+255)/256, 256, 0, stream>>>(h3, indptr, csr, as3, ad3, b3, outp);
}

// Round 5
// 403.133 us; speedup vs baseline: 1.4570x; 1.0865x over previous
//
#include <hip/hip_runtime.h>
#include <math.h>

#define NN 50000     // nodes
#define NE 650000    // edges (without self loops)
#define NET 700000   // NE + NN self loops
#define FD 256       // H*C = 4*64
#define NEG 0.2f

static __device__ __forceinline__ float lrelu(float v){ return v > 0.f ? v : NEG*v; }

// bf16 helpers
static __device__ __forceinline__ unsigned short f2bf(float f){
  union { float f; unsigned u; } v; v.f = f;
  unsigned r = v.u + 0x7fff + ((v.u >> 16) & 1);
  return (unsigned short)(r >> 16);
}
static __device__ __forceinline__ float bf2f(unsigned short h){
  union { unsigned u; float f; } v; v.u = ((unsigned)h) << 16;
  return v.f;
}
static __device__ __forceinline__ float bflo(unsigned u){ return __uint_as_float(u << 16); }
static __device__ __forceinline__ float bfhi(unsigned u){ return __uint_as_float(u & 0xffff0000u); }

// async global->LDS DMA, 16 B per lane, LDS dest = uniform base + lane*16 (m97/m104)
static __device__ __forceinline__ void gload_lds16(const unsigned short* g, unsigned short* l){
  __builtin_amdgcn_global_load_lds(
      (const __attribute__((address_space(1))) unsigned int*)(g),
      (__attribute__((address_space(3))) unsigned int*)(l), 16, 0, 0);
}

typedef __attribute__((ext_vector_type(8))) short short8_t;  // 8 bf16 = 4 VGPR
typedef __attribute__((ext_vector_type(4))) float f32x4;

// ---------------- CSR build (graph identical for all 3 layers) ----------------
__global__ void count_deg(const int* __restrict__ ei, int* __restrict__ deg){
  int e = blockIdx.x*blockDim.x + threadIdx.x;
  if (e >= NET) return;
  int d = (e < NE) ? ei[NE + e] : (e - NE);
  atomicAdd(&deg[d], 1);
}

__global__ void scan_block(const int* __restrict__ deg, int* __restrict__ excl, int* __restrict__ bsums){
  __shared__ int sh[256];
  int t = threadIdx.x;
  int i0 = blockIdx.x*1024 + t*4;
  int v0 = (i0+0 < NN) ? deg[i0+0] : 0;
  int v1 = (i0+1 < NN) ? deg[i0+1] : 0;
  int v2 = (i0+2 < NN) ? deg[i0+2] : 0;
  int v3 = (i0+3 < NN) ? deg[i0+3] : 0;
  int tot = v0+v1+v2+v3;
  sh[t] = tot;
  __syncthreads();
  for (int off=1; off<256; off<<=1){
    int x = (t>=off) ? sh[t-off] : 0;
    __syncthreads();
    sh[t] += x;
    __syncthreads();
  }
  int base = sh[t] - tot;
  if (i0+0 < NN) excl[i0+0] = base;
  if (i0+1 < NN) excl[i0+1] = base + v0;
  if (i0+2 < NN) excl[i0+2] = base + v0+v1;
  if (i0+3 < NN) excl[i0+3] = base + v0+v1+v2;
  if (t == 255) bsums[blockIdx.x] = sh[255];
}

__global__ void scan_tops(int* bsums, int nb){
  if (threadIdx.x==0 && blockIdx.x==0){
    int run=0;
    for (int i=0;i<nb;i++){ int x=bsums[i]; bsums[i]=run; run+=x; }
  }
}

__global__ void scan_add(int* __restrict__ indptr, const int* __restrict__ bsums, int* __restrict__ cursor){
  int i = blockIdx.x*blockDim.x + threadIdx.x;
  if (i < NN){
    int v = indptr[i] + bsums[i>>10];
    indptr[i] = v;
    cursor[i] = v;
  }
  if (i == 0) indptr[NN] = NET;
}

__global__ void scatter_csr(const int* __restrict__ ei, int* __restrict__ cursor, int* __restrict__ csr){
  int e = blockIdx.x*blockDim.x + threadIdx.x;
  if (e >= NET) return;
  int s, d;
  if (e < NE){ s = ei[e]; d = ei[NE+e]; } else { s = e-NE; d = e-NE; }
  int pos = atomicAdd(&cursor[d], 1);
  csr[pos] = s;
}

// ---------------- B[K][256] fp32 -> Bt_hi/Bt_lo [256][K] bf16 (split) ----------------
__global__ void castBt(const float* __restrict__ B, unsigned short* __restrict__ bth,
                       unsigned short* __restrict__ btl, int K){
  int idx = blockIdx.x*blockDim.x + threadIdx.x;
  if (idx >= K*256) return;
  int k = idx >> 8, n = idx & 255;
  float f = B[idx];
  unsigned short h = f2bf(f);
  float lo = f - bf2f(h);
  bth[n*K + k] = h;
  btl[n*K + k] = f2bf(lo);
}

// ---------------- x fp32 -> hi/lo bf16 (row-major, once) ----------------
__global__ void castA(const float* __restrict__ x, unsigned short* __restrict__ xh,
                      unsigned short* __restrict__ xl, int n){
  int i = (blockIdx.x*blockDim.x + threadIdx.x)*4;
  if (i >= n) return;
  float4 f = *(const float4*)(x + i);
  ushort4 h, l;
  h.x = f2bf(f.x); l.x = f2bf(f.x - bf2f(h.x));
  h.y = f2bf(f.y); l.y = f2bf(f.y - bf2f(h.y));
  h.z = f2bf(f.z); l.z = f2bf(f.z - bf2f(h.z));
  h.w = f2bf(f.w); l.w = f2bf(f.w - bf2f(h.w));
  *(ushort4*)(xh + i) = h;
  *(ushort4*)(xl + i) = l;
}

// ---------------- split-bf16 MFMA GEMM, global_load_lds staging, fused al ----------------
// C = (Ah+Al) @ (Bh+Bl)^T-ish: acc = Ah*Bh + Ah*Bl + Al*Bh (~fp32 precision).
// A hi/lo pre-split [M][K] bf16; B pre-split [256][K] bf16 (k-major).
// Tile 128x128, BK=32, contiguous k-major LDS (64 B/row) as required by
// global_load_lds (wave-uniform base + lane*16; m104). Wave w stages buffer w.
// Epilogue: al (shfl-reduced from fp32 acc) + Cb bf16 via LDS-staged dwordx4.
__global__ __launch_bounds__(256, 2) void gemm_mfma(const unsigned short* __restrict__ Ahg,
                                                    const unsigned short* __restrict__ Alg,
                                                    const unsigned short* __restrict__ Bth,
                                                    const unsigned short* __restrict__ Btl,
                                                    unsigned short* __restrict__ Cb,
                                                    const float* __restrict__ a_src,
                                                    const float* __restrict__ a_dst,
                                                    float* __restrict__ al,
                                                    int M, int K){
  __shared__ unsigned short Ah[128*32], Al[128*32], Bh[128*32], Bl[128*32]; // 8 KB each = 32 KB
  int t = threadIdx.x;
  int wave = t >> 6, lane = t & 63;
  int wm = wave >> 1, wn = wave & 1;
  int quad = lane >> 4, l16 = lane & 15;
  int bm0 = blockIdx.y*128, bn0 = blockIdx.x*128;

  // staging assignment: wave w owns one of {Ahg,Alg,Bth,Btl}
  const unsigned short* gsrc = (wave==0)?Ahg:(wave==1)?Alg:(wave==2)?Bth:Btl;
  unsigned short* lbuf       = (wave==0)?Ah :(wave==1)?Al :(wave==2)?Bh :Bl;
  int sbase = (wave < 2) ? bm0 : bn0;
  int srow = lane >> 2;          // 16 rows per DMA instruction
  int skg  = (lane & 3) * 8;     // 4 lanes x 8 bf16 = 64 B per row-slice

  f32x4 acc[4][4];
  #pragma unroll
  for (int i=0;i<4;i++)
    #pragma unroll
    for (int j=0;j<4;j++) acc[i][j] = (f32x4){0.f,0.f,0.f,0.f};

  for (int k0 = 0; k0 < K; k0 += 32){
    __syncthreads();             // previous iter's frag reads complete
    #pragma unroll
    for (int i=0;i<8;i++){
      int r = sbase + i*16 + srow;
      if (wave < 2) r = min(r, M-1);   // clamp: dup rows, never OOB; rows>=M unused
      gload_lds16(gsrc + (size_t)r*K + k0 + skg, lbuf + i*512);
    }
    __syncthreads();             // DMA drained (vmcnt before barrier)

    short8_t afh[4], afl[4], bfh[4], bfl[4];
    #pragma unroll
    for (int mt=0; mt<4; ++mt){
      int row = wm*64 + mt*16 + l16;
      afh[mt] = *(short8_t*)&Ah[row*32 + quad*8];
      afl[mt] = *(short8_t*)&Al[row*32 + quad*8];
    }
    #pragma unroll
    for (int nt=0; nt<4; ++nt){
      int col = wn*64 + nt*16 + l16;
      bfh[nt] = *(short8_t*)&Bh[col*32 + quad*8];
      bfl[nt] = *(short8_t*)&Bl[col*32 + quad*8];
    }
    #pragma unroll
    for (int mt=0; mt<4; ++mt)
      #pragma unroll
      for (int nt=0; nt<4; ++nt){
        acc[mt][nt] = __builtin_amdgcn_mfma_f32_16x16x32_bf16(afh[mt], bfh[nt], acc[mt][nt], 0,0,0);
        acc[mt][nt] = __builtin_amdgcn_mfma_f32_16x16x32_bf16(afh[mt], bfl[nt], acc[mt][nt], 0,0,0);
        acc[mt][nt] = __builtin_amdgcn_mfma_f32_16x16x32_bf16(afl[mt], bfh[nt], acc[mt][nt], 0,0,0);
      }
  }

  // ---- epilogue part 1: fused al_src/al_dst from fp32 acc (C/D layout m89) ----
  int head_w = (bn0 >> 6) + wn;
  float cs[4], cd[4];
  #pragma unroll
  for (int nt=0; nt<4; ++nt){
    cs[nt] = a_src[head_w*64 + nt*16 + l16];
    cd[nt] = a_dst[head_w*64 + nt*16 + l16];
  }
  #pragma unroll
  for (int mt=0; mt<4; ++mt){
    #pragma unroll
    for (int r=0; r<4; ++r){
      int row = bm0 + wm*64 + mt*16 + quad*4 + r;
      float psrc = 0.f, pdst = 0.f;
      #pragma unroll
      for (int nt=0; nt<4; ++nt){
        float v = acc[mt][nt][r];
        psrc += v*cs[nt];
        pdst += v*cd[nt];
      }
      #pragma unroll
      for (int off=1; off<16; off<<=1){
        psrc += __shfl_xor(psrc, off);
        pdst += __shfl_xor(pdst, off);
      }
      if (l16 == 0 && row < M){
        al[row*8 + head_w]     = psrc;
        al[row*8 + 4 + head_w] = pdst;
      }
    }
  }

  // ---- epilogue part 2: Cb bf16 via per-wave LDS tile + coalesced dwordx4 ----
  __syncthreads();               // all frag reads done; LDS reusable as scratch
  unsigned short* tile = lbuf;   // this wave's private 8 KB (64x64 bf16)
  #pragma unroll
  for (int mt=0; mt<4; ++mt)
    #pragma unroll
    for (int r=0; r<4; ++r){
      int rl = mt*16 + quad*4 + r;
      #pragma unroll
      for (int nt=0; nt<4; ++nt)
        tile[rl*64 + nt*16 + l16] = f2bf(acc[mt][nt][r]);
    }
  // no barrier needed: wave-private region
  int orow = lane >> 3, ocol = (lane & 7) * 8;   // 8 rows x 128 B per instruction
  #pragma unroll
  for (int it=0; it<8; ++it){
    int rl = it*8 + orow;
    int row = bm0 + wm*64 + rl;
    if (row < M){
      uint4 v = *(uint4*)&tile[rl*64 + ocol];
      *(uint4*)(Cb + (size_t)row*FD + bn0 + wn*64 + ocol) = v;
    }
  }
}

// ---------------- gather chunk: 2 edges/iter, 16 B/lane ----------------
static __device__ __forceinline__ void gather_chunk(int cnt, const float* eb, const int* sb,
                                                    const unsigned short* __restrict__ hb,
                                                    int half, int l32, int head8, float acc[8]){
  for (int tt = 0; tt < cnt; tt += 4){
    int eA = tt + half, eB = tt + 2 + half;
    int iA = (eA < cnt) ? eA : 0;
    int iB = (eB < cnt) ? eB : 0;
    int sA = sb[iA];
    int sB = sb[iB];
    float evA = eb[iA*4 + head8]; if (eA >= cnt) evA = 0.f;
    float evB = eb[iB*4 + head8]; if (eB >= cnt) evB = 0.f;
    uint4 a4 = *(const uint4*)(hb + (size_t)sA*FD + l32*8);
    uint4 b4 = *(const uint4*)(hb + (size_t)sB*FD + l32*8);
    acc[0] += evA*bflo(a4.x); acc[1] += evA*bfhi(a4.x);
    acc[2] += evA*bflo(a4.y); acc[3] += evA*bfhi(a4.y);
    acc[4] += evA*bflo(a4.z); acc[5] += evA*bfhi(a4.z);
    acc[6] += evA*bflo(a4.w); acc[7] += evA*bfhi(a4.w);
    acc[0] += evB*bflo(b4.x); acc[1] += evB*bfhi(b4.x);
    acc[2] += evB*bflo(b4.y); acc[3] += evB*bfhi(b4.y);
    acc[4] += evB*bflo(b4.z); acc[5] += evB*bfhi(b4.z);
    acc[6] += evB*bflo(b4.w); acc[7] += evB*bfhi(b4.w);
  }
}

// ---------------- GAT aggregation: wave/node, LDS-staged alpha, hi/lo out ----------------
__global__ __launch_bounds__(256) void gat_agg(const unsigned short* __restrict__ hb,
                                               const float* __restrict__ al,
                                               const int* __restrict__ indptr, const int* __restrict__ csr,
                                               const float* __restrict__ bias,
                                               unsigned short* __restrict__ outh,
                                               unsigned short* __restrict__ outl){
  __shared__ float ebuf[4][256];
  __shared__ int   sbuf[4][64];
  int wv = threadIdx.x >> 6, lane = threadIdx.x & 63;
  int n = blockIdx.x*4 + wv;
  if (n >= NN) return;
  int half = lane >> 5, l32 = lane & 31, head8 = l32 >> 3;
  int base = indptr[n], deg = indptr[n+1] - base;
  float4 ald = *(const float4*)(al + n*8 + 4);
  float* eb = &ebuf[wv][0];
  int*   sb = &sbuf[wv][0];

  float acc[8] = {0.f,0.f,0.f,0.f,0.f,0.f,0.f,0.f};
  float4 esum = make_float4(0.f,0.f,0.f,0.f);

  if (deg <= 64){
    int sj = 0;
    float4 lg = make_float4(-1e30f,-1e30f,-1e30f,-1e30f);
    if (lane < deg){
      sj = csr[base + lane];
      float4 als = *(const float4*)(al + sj*8);
      lg.x = lrelu(als.x + ald.x);
      lg.y = lrelu(als.y + ald.y);
      lg.z = lrelu(als.z + ald.z);
      lg.w = lrelu(als.w + ald.w);
    }
    float4 mx = lg;
    for (int off=32; off; off>>=1){
      mx.x = fmaxf(mx.x, __shfl_xor(mx.x, off));
      mx.y = fmaxf(mx.y, __shfl_xor(mx.y, off));
      mx.z = fmaxf(mx.z, __shfl_xor(mx.z, off));
      mx.w = fmaxf(mx.w, __shfl_xor(mx.w, off));
    }
    float4 e4 = make_float4(0.f,0.f,0.f,0.f);
    if (lane < deg){
      e4.x = expf(lg.x - mx.x); e4.y = expf(lg.y - mx.y);
      e4.z = expf(lg.z - mx.z); e4.w = expf(lg.w - mx.w);
    }
    esum = e4;
    *(float4*)&eb[lane*4] = e4;
    sb[lane] = sj;
    gather_chunk(deg, eb, sb, hb, half, l32, head8, acc);
  } else {
    float4 mx = make_float4(-1e30f,-1e30f,-1e30f,-1e30f);
    for (int j = lane; j < deg; j += 64){
      int s = csr[base+j];
      float4 als = *(const float4*)(al + s*8);
      mx.x = fmaxf(mx.x, lrelu(als.x + ald.x));
      mx.y = fmaxf(mx.y, lrelu(als.y + ald.y));
      mx.z = fmaxf(mx.z, lrelu(als.z + ald.z));
      mx.w = fmaxf(mx.w, lrelu(als.w + ald.w));
    }
    for (int off=32; off; off>>=1){
      mx.x = fmaxf(mx.x, __shfl_xor(mx.x, off));
      mx.y = fmaxf(mx.y, __shfl_xor(mx.y, off));
      mx.z = fmaxf(mx.z, __shfl_xor(mx.z, off));
      mx.w = fmaxf(mx.w, __shfl_xor(mx.w, off));
    }
    for (int j0 = 0; j0 < deg; j0 += 64){
      int j = j0 + lane;
      float4 e4 = make_float4(0.f,0.f,0.f,0.f);
      int sj = 0;
      if (j < deg){
        sj = csr[base+j];
        float4 als = *(const float4*)(al + sj*8);
        e4.x = expf(lrelu(als.x + ald.x) - mx.x);
        e4.y = expf(lrelu(als.y + ald.y) - mx.y);
        e4.z = expf(lrelu(als.z + ald.z) - mx.z);
        e4.w = expf(lrelu(als.w + ald.w) - mx.w);
        esum.x += e4.x; esum.y += e4.y; esum.z += e4.z; esum.w += e4.w;
      }
      *(float4*)&eb[lane*4] = e4;
      sb[lane] = sj;
      gather_chunk(min(64, deg - j0), eb, sb, hb, half, l32, head8, acc);
    }
  }

  for (int off=32; off; off>>=1){
    esum.x += __shfl_xor(esum.x, off);
    esum.y += __shfl_xor(esum.y, off);
    esum.z += __shfl_xor(esum.z, off);
    esum.w += __shfl_xor(esum.w, off);
  }
  #pragma unroll
  for (int i=0;i<8;i++) acc[i] += __shfl_xor(acc[i], 32);

  float sH = (head8==0)?esum.x:(head8==1)?esum.y:(head8==2)?esum.z:esum.w;
  float inv = 1.f/(sH + 1e-16f);
  if (half == 0){
    int ch0 = l32*8;
    float4 b0 = *(const float4*)(bias + ch0);
    float4 b1 = *(const float4*)(bias + ch0 + 4);
    float o[8];
    o[0]=acc[0]*inv+b0.x; o[1]=acc[1]*inv+b0.y; o[2]=acc[2]*inv+b0.z; o[3]=acc[3]*inv+b0.w;
    o[4]=acc[4]*inv+b1.x; o[5]=acc[5]*inv+b1.y; o[6]=acc[6]*inv+b1.z; o[7]=acc[7]*inv+b1.w;
    #pragma unroll
    for (int i=0;i<8;i++) o[i] = o[i] > 0.f ? o[i] : expm1f(o[i]);   // elu
    unsigned hi[4], lo[4];
    #pragma unroll
    for (int i=0;i<4;i++){
      unsigned short h0 = f2bf(o[2*i]),   h1 = f2bf(o[2*i+1]);
      unsigned short g0 = f2bf(o[2*i]   - bf2f(h0));
      unsigned short g1 = f2bf(o[2*i+1] - bf2f(h1));
      hi[i] = (unsigned)h0 | ((unsigned)h1 << 16);
      lo[i] = (unsigned)g0 | ((unsigned)g1 << 16);
    }
    *(uint4*)(outh + (size_t)n*FD + ch0) = make_uint4(hi[0],hi[1],hi[2],hi[3]);
    *(uint4*)(outl + (size_t)n*FD + ch0) = make_uint4(lo[0],lo[1],lo[2],lo[3]);
  }
}

// ---------------- layer 3: GEMV [N,256]@[256,1] (hi/lo input) then scalar GAT ----------------
__global__ __launch_bounds__(256) void gemv3(const unsigned short* __restrict__ Ah,
                                             const unsigned short* __restrict__ Al,
                                             const float* __restrict__ W, float* __restrict__ h3){
  int n = (blockIdx.x*blockDim.x + threadIdx.x) >> 6;
  int lane = threadIdx.x & 63;
  if (n >= NN) return;
  ushort4 hv = *(const ushort4*)(Ah + (size_t)n*FD + lane*4);
  ushort4 lv = *(const ushort4*)(Al + (size_t)n*FD + lane*4);
  float4 w = *(const float4*)(W + lane*4);
  float p = (bf2f(hv.x)+bf2f(lv.x))*w.x + (bf2f(hv.y)+bf2f(lv.y))*w.y
          + (bf2f(hv.z)+bf2f(lv.z))*w.z + (bf2f(hv.w)+bf2f(lv.w))*w.w;
  for (int off=32; off; off>>=1) p += __shfl_xor(p, off);
  if (lane==0) h3[n] = p;
}

__global__ __launch_bounds__(256) void gat_agg3(const float* __restrict__ h3, const int* __restrict__ indptr,
                                                const int* __restrict__ csr, const float* __restrict__ asrc,
                                                const float* __restrict__ adst, const float* __restrict__ b3,
                                                float* __restrict__ out){
  int n = blockIdx.x*blockDim.x + threadIdx.x;
  if (n >= NN) return;
  float as = asrc[0], ad = adst[0];
  float hd = h3[n]*ad;
  int base = indptr[n], end = indptr[n+1];
  float m = -1e30f;
  for (int e=base; e<end; ++e){
    float l = lrelu(as*h3[csr[e]] + hd);
    m = fmaxf(m, l);
  }
  float s = 0.f, w = 0.f;
  for (int e=base; e<end; ++e){
    float hv = h3[csr[e]];
    float l = lrelu(as*hv + hd);
    float ee = expf(l - m);
    s += ee; w += ee*hv;
  }
  out[n] = w/(s + 1e-16f) + b3[0];
}

extern "C" void kernel_launch(void* const* d_in, const int* in_sizes, int n_in,
                              void* d_out, int out_size, void* d_ws, size_t ws_size,
                              hipStream_t stream){
  const float* x   = (const float*)d_in[0];
  const int*   ei  = (const int*)d_in[1];
  const float* W1  = (const float*)d_in[2];
  const float* as1 = (const float*)d_in[3];
  const float* ad1 = (const float*)d_in[4];
  const float* b1  = (const float*)d_in[5];
  const float* W2  = (const float*)d_in[6];
  const float* as2 = (const float*)d_in[7];
  const float* ad2 = (const float*)d_in[8];
  const float* b2  = (const float*)d_in[9];
  const float* W3  = (const float*)d_in[10];
  const float* as3 = (const float*)d_in[11];
  const float* ad3 = (const float*)d_in[12];
  const float* b3  = (const float*)d_in[13];
  float* outp = (float*)d_out;

  char* w = (char*)d_ws;
  size_t off = 0;
  auto alloc = [&](size_t bytes)->void*{
    void* p = w + off; off += (bytes + 255) & ~(size_t)255; return p;
  };
  unsigned short* hb  = (unsigned short*)alloc((size_t)NN*FD*2);  // 25.6 MB (Cb)
  unsigned short* oh  = (unsigned short*)alloc((size_t)NN*FD*2);  // 25.6 MB
  unsigned short* ol  = (unsigned short*)alloc((size_t)NN*FD*2);  // 25.6 MB
  unsigned short* xh  = (unsigned short*)alloc((size_t)NN*128*2); // 12.8 MB
  unsigned short* xl  = (unsigned short*)alloc((size_t)NN*128*2); // 12.8 MB
  float* al    = (float*)alloc((size_t)NN*8*4);                   // 1.6 MB
  int*   indptr= (int*)alloc((size_t)(NN+1)*4);
  int*   cursor= (int*)alloc((size_t)NN*4);
  int*   csr   = (int*)alloc((size_t)NET*4);                      // 2.8 MB
  int*   bsums = (int*)alloc(64*4);
  float* h3    = (float*)alloc((size_t)NN*4);
  unsigned short* bt1h = (unsigned short*)alloc((size_t)256*128*2);
  unsigned short* bt1l = (unsigned short*)alloc((size_t)256*128*2);
  unsigned short* bt2h = (unsigned short*)alloc((size_t)256*256*2);
  unsigned short* bt2l = (unsigned short*)alloc((size_t)256*256*2);

  // ---- CSR build (once; same graph for all layers) ----
  hipMemsetAsync(cursor, 0, (size_t)NN*4, stream);
  count_deg<<<(NET+255)/256, 256, 0, stream>>>(ei, cursor);
  int nb = (NN+1023)/1024;
  scan_block<<<nb, 256, 0, stream>>>(cursor, indptr, bsums);
  scan_tops<<<1, 64, 0, stream>>>(bsums, nb);
  scan_add<<<(NN+255)/256, 256, 0, stream>>>(indptr, bsums, cursor);
  scatter_csr<<<(NET+255)/256, 256, 0, stream>>>(ei, cursor, csr);

  // ---- input/weight split (tiny) ----
  castBt<<<128, 256, 0, stream>>>(W1, bt1h, bt1l, 128);
  castBt<<<256, 256, 0, stream>>>(W2, bt2h, bt2l, 256);
  castA<<<(NN*128/4+255)/256, 256, 0, stream>>>(x, xh, xl, NN*128);

  dim3 gemm_grid(FD/128, (NN+127)/128);
  int agg_blocks = (NN+3)/4;
  int node_wave_blocks = (NN*64+255)/256;

  // ---- layer 1 ----
  gemm_mfma<<<gemm_grid, 256, 0, stream>>>(xh, xl, bt1h, bt1l, hb, as1, ad1, al, NN, 128);
  gat_agg<<<agg_blocks, 256, 0, stream>>>(hb, al, indptr, csr, b1, oh, ol);
  // ---- layer 2 ----
  gemm_mfma<<<gemm_grid, 256, 0, stream>>>(oh, ol, bt2h, bt2l, hb, as2, ad2, al, NN, 256);
  gat_agg<<<agg_blocks, 256, 0, stream>>>(hb, al, indptr, csr, b2, oh, ol);
  // ---- layer 3 ----
  gemv3<<<node_wave_blocks, 256, 0, stream>>>(oh, ol, W3, h3);
  gat_agg3<<<(NN+255)/256, 256, 0, stream>>>(h3, indptr, csr, as3, ad3, b3, outp);
}

// Round 6
// 379.076 us; speedup vs baseline: 1.5494x; 1.0635x over previous
//
#include <hip/hip_runtime.h>
#include <math.h>

#define NN 50000     // nodes
#define NE 650000    // edges (without self loops)
#define NET 700000   // NE + NN self loops
#define FD 256       // H*C = 4*64
#define NEG 0.2f

static __device__ __forceinline__ float lrelu(float v){ return v > 0.f ? v : NEG*v; }

// bf16 helpers
static __device__ __forceinline__ unsigned short f2bf(float f){
  union { float f; unsigned u; } v; v.f = f;
  unsigned r = v.u + 0x7fff + ((v.u >> 16) & 1);
  return (unsigned short)(r >> 16);
}
static __device__ __forceinline__ float bf2f(unsigned short h){
  union { unsigned u; float f; } v; v.u = ((unsigned)h) << 16;
  return v.f;
}
static __device__ __forceinline__ float bflo(unsigned u){ return __uint_as_float(u << 16); }
static __device__ __forceinline__ float bfhi(unsigned u){ return __uint_as_float(u & 0xffff0000u); }

// async global->LDS DMA, 16 B per lane, LDS dest = uniform base + lane*16 (m97/m104)
static __device__ __forceinline__ void gload_lds16(const unsigned short* g, unsigned short* l){
  __builtin_amdgcn_global_load_lds(
      (const __attribute__((address_space(1))) unsigned int*)(g),
      (__attribute__((address_space(3))) unsigned int*)(l), 16, 0, 0);
}

typedef __attribute__((ext_vector_type(8))) short short8_t;  // 8 bf16 = 4 VGPR
typedef __attribute__((ext_vector_type(4))) float f32x4;

// ---------------- CSR build (graph identical for all 3 layers) ----------------
__global__ void count_deg(const int* __restrict__ ei, int* __restrict__ deg){
  int e = blockIdx.x*blockDim.x + threadIdx.x;
  if (e >= NET) return;
  int d = (e < NE) ? ei[NE + e] : (e - NE);
  atomicAdd(&deg[d], 1);
}

__global__ void scan_block(const int* __restrict__ deg, int* __restrict__ excl, int* __restrict__ bsums){
  __shared__ int sh[256];
  int t = threadIdx.x;
  int i0 = blockIdx.x*1024 + t*4;
  int v0 = (i0+0 < NN) ? deg[i0+0] : 0;
  int v1 = (i0+1 < NN) ? deg[i0+1] : 0;
  int v2 = (i0+2 < NN) ? deg[i0+2] : 0;
  int v3 = (i0+3 < NN) ? deg[i0+3] : 0;
  int tot = v0+v1+v2+v3;
  sh[t] = tot;
  __syncthreads();
  for (int off=1; off<256; off<<=1){
    int x = (t>=off) ? sh[t-off] : 0;
    __syncthreads();
    sh[t] += x;
    __syncthreads();
  }
  int base = sh[t] - tot;
  if (i0+0 < NN) excl[i0+0] = base;
  if (i0+1 < NN) excl[i0+1] = base + v0;
  if (i0+2 < NN) excl[i0+2] = base + v0+v1;
  if (i0+3 < NN) excl[i0+3] = base + v0+v1+v2;
  if (t == 255) bsums[blockIdx.x] = sh[255];
}

__global__ void scan_tops(int* bsums, int nb){
  if (threadIdx.x==0 && blockIdx.x==0){
    int run=0;
    for (int i=0;i<nb;i++){ int x=bsums[i]; bsums[i]=run; run+=x; }
  }
}

__global__ void scan_add(int* __restrict__ indptr, const int* __restrict__ bsums, int* __restrict__ cursor){
  int i = blockIdx.x*blockDim.x + threadIdx.x;
  if (i < NN){
    int v = indptr[i] + bsums[i>>10];
    indptr[i] = v;
    cursor[i] = v;
  }
  if (i == 0) indptr[NN] = NET;
}

__global__ void scatter_csr(const int* __restrict__ ei, int* __restrict__ cursor, int* __restrict__ csr){
  int e = blockIdx.x*blockDim.x + threadIdx.x;
  if (e >= NET) return;
  int s, d;
  if (e < NE){ s = ei[e]; d = ei[NE+e]; } else { s = e-NE; d = e-NE; }
  int pos = atomicAdd(&cursor[d], 1);
  csr[pos] = s;
}

// ---------------- B[K][256] fp32 -> Bt_hi/Bt_lo [256][K] bf16 (split) ----------------
__global__ void castBt(const float* __restrict__ B, unsigned short* __restrict__ bth,
                       unsigned short* __restrict__ btl, int K){
  int idx = blockIdx.x*blockDim.x + threadIdx.x;
  if (idx >= K*256) return;
  int k = idx >> 8, n = idx & 255;
  float f = B[idx];
  unsigned short h = f2bf(f);
  float lo = f - bf2f(h);
  bth[n*K + k] = h;
  btl[n*K + k] = f2bf(lo);
}

// ---------------- x fp32 -> hi/lo bf16 (row-major, once) ----------------
__global__ void castA(const float* __restrict__ x, unsigned short* __restrict__ xh,
                      unsigned short* __restrict__ xl, int n){
  int i = (blockIdx.x*blockDim.x + threadIdx.x)*4;
  if (i >= n) return;
  float4 f = *(const float4*)(x + i);
  ushort4 h, l;
  h.x = f2bf(f.x); l.x = f2bf(f.x - bf2f(h.x));
  h.y = f2bf(f.y); l.y = f2bf(f.y - bf2f(h.y));
  h.z = f2bf(f.z); l.z = f2bf(f.z - bf2f(h.z));
  h.w = f2bf(f.w); l.w = f2bf(f.w - bf2f(h.w));
  *(ushort4*)(xh + i) = h;
  *(ushort4*)(xl + i) = l;
}

// ---------------- split-bf16 MFMA GEMM, global_load_lds staging, fused al ----------------
// acc = Ah*Bh + Ah*Bl + Al*Bh (~fp32 precision). Tile 128x128, BK=32,
// contiguous k-major LDS (64 B/row) per global_load_lds constraint (m104).
// Epilogue: al via wave-private LDS transpose (not shfl), Cb bf16 via LDS +
// coalesced dwordx4.
__global__ __launch_bounds__(256, 2) void gemm_mfma(const unsigned short* __restrict__ Ahg,
                                                    const unsigned short* __restrict__ Alg,
                                                    const unsigned short* __restrict__ Bth,
                                                    const unsigned short* __restrict__ Btl,
                                                    unsigned short* __restrict__ Cb,
                                                    const float* __restrict__ a_src,
                                                    const float* __restrict__ a_dst,
                                                    float* __restrict__ al,
                                                    int M, int K){
  __shared__ unsigned short Ah[128*32], Al[128*32], Bh[128*32], Bl[128*32]; // 8 KB each
  int t = threadIdx.x;
  int wave = t >> 6, lane = t & 63;
  int wm = wave >> 1, wn = wave & 1;
  int quad = lane >> 4, l16 = lane & 15;
  int bm0 = blockIdx.y*128, bn0 = blockIdx.x*128;

  const unsigned short* gsrc = (wave==0)?Ahg:(wave==1)?Alg:(wave==2)?Bth:Btl;
  unsigned short* lbuf       = (wave==0)?Ah :(wave==1)?Al :(wave==2)?Bh :Bl;
  int sbase = (wave < 2) ? bm0 : bn0;
  int srow = lane >> 2;
  int skg  = (lane & 3) * 8;

  f32x4 acc[4][4];
  #pragma unroll
  for (int i=0;i<4;i++)
    #pragma unroll
    for (int j=0;j<4;j++) acc[i][j] = (f32x4){0.f,0.f,0.f,0.f};

  for (int k0 = 0; k0 < K; k0 += 32){
    __syncthreads();
    #pragma unroll
    for (int i=0;i<8;i++){
      int r = sbase + i*16 + srow;
      if (wave < 2) r = min(r, M-1);   // clamp: dup rows, never OOB
      gload_lds16(gsrc + (size_t)r*K + k0 + skg, lbuf + i*512);
    }
    __syncthreads();

    short8_t afh[4], afl[4], bfh[4], bfl[4];
    #pragma unroll
    for (int mt=0; mt<4; ++mt){
      int row = wm*64 + mt*16 + l16;
      afh[mt] = *(short8_t*)&Ah[row*32 + quad*8];
      afl[mt] = *(short8_t*)&Al[row*32 + quad*8];
    }
    #pragma unroll
    for (int nt=0; nt<4; ++nt){
      int col = wn*64 + nt*16 + l16;
      bfh[nt] = *(short8_t*)&Bh[col*32 + quad*8];
      bfl[nt] = *(short8_t*)&Bl[col*32 + quad*8];
    }
    #pragma unroll
    for (int mt=0; mt<4; ++mt)
      #pragma unroll
      for (int nt=0; nt<4; ++nt){
        acc[mt][nt] = __builtin_amdgcn_mfma_f32_16x16x32_bf16(afh[mt], bfh[nt], acc[mt][nt], 0,0,0);
        acc[mt][nt] = __builtin_amdgcn_mfma_f32_16x16x32_bf16(afh[mt], bfl[nt], acc[mt][nt], 0,0,0);
        acc[mt][nt] = __builtin_amdgcn_mfma_f32_16x16x32_bf16(afl[mt], bfh[nt], acc[mt][nt], 0,0,0);
      }
  }

  __syncthreads();   // all waves done reading LDS; lbuf becomes wave-private scratch

  // ---- epilogue 1: fused al via LDS transpose (stride 17 floats, ~2-way banks)
  int head_w = (bn0 >> 6) + wn;
  float cs[4], cd[4];
  #pragma unroll
  for (int nt=0; nt<4; ++nt){
    cs[nt] = a_src[head_w*64 + nt*16 + l16];
    cd[nt] = a_dst[head_w*64 + nt*16 + l16];
  }
  {
    float* fsc = (float*)lbuf;   // 64 rows x 17 floats = 4352 B < 8 KB
    int grow = bm0 + wm*64 + lane;
    #pragma unroll
    for (int pass=0; pass<2; ++pass){
      #pragma unroll
      for (int mt=0; mt<4; ++mt)
        #pragma unroll
        for (int r=0; r<4; ++r){
          float p = 0.f;
          #pragma unroll
          for (int nt=0; nt<4; ++nt)
            p += acc[mt][nt][r] * (pass ? cd[nt] : cs[nt]);
          fsc[(mt*16 + quad*4 + r)*17 + l16] = p;
        }
      // wave-private: compiler inserts lgkm waits, no barrier needed
      float s = 0.f;
      #pragma unroll
      for (int j=0; j<16; ++j) s += fsc[lane*17 + j];
      if (grow < M) al[grow*8 + pass*4 + head_w] = s;
    }
  }

  // ---- epilogue 2: Cb bf16 via per-wave LDS tile + coalesced dwordx4 ----
  unsigned short* tile = lbuf;
  #pragma unroll
  for (int mt=0; mt<4; ++mt)
    #pragma unroll
    for (int r=0; r<4; ++r){
      int rl = mt*16 + quad*4 + r;
      #pragma unroll
      for (int nt=0; nt<4; ++nt)
        tile[rl*64 + nt*16 + l16] = f2bf(acc[mt][nt][r]);
    }
  int orow = lane >> 3, ocol = (lane & 7) * 8;
  #pragma unroll
  for (int it=0; it<8; ++it){
    int rl = it*8 + orow;
    int row = bm0 + wm*64 + rl;
    if (row < M){
      uint4 v = *(uint4*)&tile[rl*64 + ocol];
      *(uint4*)(Cb + (size_t)row*FD + bn0 + wn*64 + ocol) = v;
    }
  }
}

// ---------------- gather chunk: 8 edges/iter, 4 loads in flight, no clamps ----
// sb holds BYTE offsets (src*512), zero-padded to 64; eb zero-padded alphas.
// Pad edges gather row 0 with alpha 0 (harmless, L1-hot).
static __device__ __forceinline__ void gather_chunk(int cnt, const float* eb, const int* sb,
                                                    const char* hp, int half, int head8,
                                                    float acc[8]){
  for (int tt = 0; tt < cnt; tt += 8){
    int e0 = tt + half, e1 = e0 + 2, e2 = e0 + 4, e3 = e0 + 6;   // max 63
    int o0 = sb[e0], o1 = sb[e1], o2 = sb[e2], o3 = sb[e3];
    float v0 = eb[e0*4 + head8], v1 = eb[e1*4 + head8];
    float v2 = eb[e2*4 + head8], v3 = eb[e3*4 + head8];
    uint4 a = *(const uint4*)(hp + o0);
    uint4 b = *(const uint4*)(hp + o1);
    uint4 c = *(const uint4*)(hp + o2);
    uint4 d = *(const uint4*)(hp + o3);
    acc[0]+=v0*bflo(a.x); acc[1]+=v0*bfhi(a.x); acc[2]+=v0*bflo(a.y); acc[3]+=v0*bfhi(a.y);
    acc[4]+=v0*bflo(a.z); acc[5]+=v0*bfhi(a.z); acc[6]+=v0*bflo(a.w); acc[7]+=v0*bfhi(a.w);
    acc[0]+=v1*bflo(b.x); acc[1]+=v1*bfhi(b.x); acc[2]+=v1*bflo(b.y); acc[3]+=v1*bfhi(b.y);
    acc[4]+=v1*bflo(b.z); acc[5]+=v1*bfhi(b.z); acc[6]+=v1*bflo(b.w); acc[7]+=v1*bfhi(b.w);
    acc[0]+=v2*bflo(c.x); acc[1]+=v2*bfhi(c.x); acc[2]+=v2*bflo(c.y); acc[3]+=v2*bfhi(c.y);
    acc[4]+=v2*bflo(c.z); acc[5]+=v2*bfhi(c.z); acc[6]+=v2*bflo(c.w); acc[7]+=v2*bfhi(c.w);
    acc[0]+=v3*bflo(d.x); acc[1]+=v3*bfhi(d.x); acc[2]+=v3*bflo(d.y); acc[3]+=v3*bfhi(d.y);
    acc[4]+=v3*bflo(d.z); acc[5]+=v3*bfhi(d.z); acc[6]+=v3*bflo(d.w); acc[7]+=v3*bfhi(d.w);
  }
}

// ---------------- GAT aggregation: wave/node; FUSE_W3 computes h3 instead of oh/ol
template<bool FUSE_W3>
__global__ __launch_bounds__(256) void gat_agg(const unsigned short* __restrict__ hb,
                                               const float* __restrict__ al,
                                               const int* __restrict__ indptr, const int* __restrict__ csr,
                                               const float* __restrict__ bias,
                                               unsigned short* __restrict__ outh,
                                               unsigned short* __restrict__ outl,
                                               const float* __restrict__ W3,
                                               float* __restrict__ h3){
  __shared__ float ebuf[4][256];
  __shared__ int   sbuf[4][64];
  int wv = threadIdx.x >> 6, lane = threadIdx.x & 63;
  int n = blockIdx.x*4 + wv;
  if (n >= NN) return;
  int half = lane >> 5, l32 = lane & 31, head8 = l32 >> 3;
  int base = indptr[n], deg = indptr[n+1] - base;
  float4 ald = *(const float4*)(al + n*8 + 4);
  float* eb = &ebuf[wv][0];
  int*   sb = &sbuf[wv][0];
  const char* hp = (const char*)hb + l32*16;

  float acc[8] = {0.f,0.f,0.f,0.f,0.f,0.f,0.f,0.f};
  float4 esum = make_float4(0.f,0.f,0.f,0.f);

  if (deg <= 64){
    int sj = 0;
    float4 lg = make_float4(-1e30f,-1e30f,-1e30f,-1e30f);
    if (lane < deg){
      sj = csr[base + lane];
      float4 als = *(const float4*)(al + sj*8);
      lg.x = lrelu(als.x + ald.x);
      lg.y = lrelu(als.y + ald.y);
      lg.z = lrelu(als.z + ald.z);
      lg.w = lrelu(als.w + ald.w);
    }
    float4 mx = lg;
    for (int off=32; off; off>>=1){
      mx.x = fmaxf(mx.x, __shfl_xor(mx.x, off));
      mx.y = fmaxf(mx.y, __shfl_xor(mx.y, off));
      mx.z = fmaxf(mx.z, __shfl_xor(mx.z, off));
      mx.w = fmaxf(mx.w, __shfl_xor(mx.w, off));
    }
    float4 e4 = make_float4(0.f,0.f,0.f,0.f);
    if (lane < deg){
      e4.x = expf(lg.x - mx.x); e4.y = expf(lg.y - mx.y);
      e4.z = expf(lg.z - mx.z); e4.w = expf(lg.w - mx.w);
    }
    esum = e4;
    *(float4*)&eb[lane*4] = e4;
    sb[lane] = sj << 9;                 // byte offset (FD*2 = 512)
    gather_chunk(deg, eb, sb, hp, half, head8, acc);
  } else {
    float4 mx = make_float4(-1e30f,-1e30f,-1e30f,-1e30f);
    for (int j = lane; j < deg; j += 64){
      int s = csr[base+j];
      float4 als = *(const float4*)(al + s*8);
      mx.x = fmaxf(mx.x, lrelu(als.x + ald.x));
      mx.y = fmaxf(mx.y, lrelu(als.y + ald.y));
      mx.z = fmaxf(mx.z, lrelu(als.z + ald.z));
      mx.w = fmaxf(mx.w, lrelu(als.w + ald.w));
    }
    for (int off=32; off; off>>=1){
      mx.x = fmaxf(mx.x, __shfl_xor(mx.x, off));
      mx.y = fmaxf(mx.y, __shfl_xor(mx.y, off));
      mx.z = fmaxf(mx.z, __shfl_xor(mx.z, off));
      mx.w = fmaxf(mx.w, __shfl_xor(mx.w, off));
    }
    for (int j0 = 0; j0 < deg; j0 += 64){
      int j = j0 + lane;
      float4 e4 = make_float4(0.f,0.f,0.f,0.f);
      int sj = 0;
      if (j < deg){
        sj = csr[base+j];
        float4 als = *(const float4*)(al + sj*8);
        e4.x = expf(lrelu(als.x + ald.x) - mx.x);
        e4.y = expf(lrelu(als.y + ald.y) - mx.y);
        e4.z = expf(lrelu(als.z + ald.z) - mx.z);
        e4.w = expf(lrelu(als.w + ald.w) - mx.w);
        esum.x += e4.x; esum.y += e4.y; esum.z += e4.z; esum.w += e4.w;
      }
      *(float4*)&eb[lane*4] = e4;
      sb[lane] = sj << 9;
      gather_chunk(min(64, deg - j0), eb, sb, hp, half, head8, acc);
    }
  }

  for (int off=32; off; off>>=1){
    esum.x += __shfl_xor(esum.x, off);
    esum.y += __shfl_xor(esum.y, off);
    esum.z += __shfl_xor(esum.z, off);
    esum.w += __shfl_xor(esum.w, off);
  }
  #pragma unroll
  for (int i=0;i<8;i++) acc[i] += __shfl_xor(acc[i], 32);

  float sH = (head8==0)?esum.x:(head8==1)?esum.y:(head8==2)?esum.z:esum.w;
  float inv = 1.f/(sH + 1e-16f);
  int ch0 = l32*8;
  float4 b0 = *(const float4*)(bias + ch0);
  float4 b1 = *(const float4*)(bias + ch0 + 4);
  float o[8];
  o[0]=acc[0]*inv+b0.x; o[1]=acc[1]*inv+b0.y; o[2]=acc[2]*inv+b0.z; o[3]=acc[3]*inv+b0.w;
  o[4]=acc[4]*inv+b1.x; o[5]=acc[5]*inv+b1.y; o[6]=acc[6]*inv+b1.z; o[7]=acc[7]*inv+b1.w;
  #pragma unroll
  for (int i=0;i<8;i++) o[i] = o[i] > 0.f ? o[i] : expm1f(o[i]);   // elu

  if (FUSE_W3){
    // h3[n] = elu(out) . W3  (both halves hold identical o; reduce within half)
    float4 w0 = *(const float4*)(W3 + ch0);
    float4 w1 = *(const float4*)(W3 + ch0 + 4);
    float p = o[0]*w0.x + o[1]*w0.y + o[2]*w0.z + o[3]*w0.w
            + o[4]*w1.x + o[5]*w1.y + o[6]*w1.z + o[7]*w1.w;
    #pragma unroll
    for (int off=16; off; off>>=1) p += __shfl_xor(p, off);
    if (lane == 0) h3[n] = p;
  } else if (half == 0){
    unsigned hi[4], lo[4];
    #pragma unroll
    for (int i=0;i<4;i++){
      unsigned short h0 = f2bf(o[2*i]),   h1 = f2bf(o[2*i+1]);
      unsigned short g0 = f2bf(o[2*i]   - bf2f(h0));
      unsigned short g1 = f2bf(o[2*i+1] - bf2f(h1));
      hi[i] = (unsigned)h0 | ((unsigned)h1 << 16);
      lo[i] = (unsigned)g0 | ((unsigned)g1 << 16);
    }
    *(uint4*)(outh + (size_t)n*FD + ch0) = make_uint4(hi[0],hi[1],hi[2],hi[3]);
    *(uint4*)(outl + (size_t)n*FD + ch0) = make_uint4(lo[0],lo[1],lo[2],lo[3]);
  }
}

// ---------------- layer 3: scalar GAT on h3 ----------------
__global__ __launch_bounds__(256) void gat_agg3(const float* __restrict__ h3, const int* __restrict__ indptr,
                                                const int* __restrict__ csr, const float* __restrict__ asrc,
                                                const float* __restrict__ adst, const float* __restrict__ b3,
                                                float* __restrict__ out){
  int n = blockIdx.x*blockDim.x + threadIdx.x;
  if (n >= NN) return;
  float as = asrc[0], ad = adst[0];
  float hd = h3[n]*ad;
  int base = indptr[n], end = indptr[n+1];
  float m = -1e30f;
  for (int e=base; e<end; ++e){
    float l = lrelu(as*h3[csr[e]] + hd);
    m = fmaxf(m, l);
  }
  float s = 0.f, w = 0.f;
  for (int e=base; e<end; ++e){
    float hv = h3[csr[e]];
    float l = lrelu(as*hv + hd);
    float ee = expf(l - m);
    s += ee; w += ee*hv;
  }
  out[n] = w/(s + 1e-16f) + b3[0];
}

extern "C" void kernel_launch(void* const* d_in, const int* in_sizes, int n_in,
                              void* d_out, int out_size, void* d_ws, size_t ws_size,
                              hipStream_t stream){
  const float* x   = (const float*)d_in[0];
  const int*   ei  = (const int*)d_in[1];
  const float* W1  = (const float*)d_in[2];
  const float* as1 = (const float*)d_in[3];
  const float* ad1 = (const float*)d_in[4];
  const float* b1  = (const float*)d_in[5];
  const float* W2  = (const float*)d_in[6];
  const float* as2 = (const float*)d_in[7];
  const float* ad2 = (const float*)d_in[8];
  const float* b2  = (const float*)d_in[9];
  const float* W3  = (const float*)d_in[10];
  const float* as3 = (const float*)d_in[11];
  const float* ad3 = (const float*)d_in[12];
  const float* b3  = (const float*)d_in[13];
  float* outp = (float*)d_out;

  char* w = (char*)d_ws;
  size_t off = 0;
  auto alloc = [&](size_t bytes)->void*{
    void* p = w + off; off += (bytes + 255) & ~(size_t)255; return p;
  };
  unsigned short* hb  = (unsigned short*)alloc((size_t)NN*FD*2);  // 25.6 MB (Cb)
  unsigned short* oh  = (unsigned short*)alloc((size_t)NN*FD*2);  // 25.6 MB
  unsigned short* ol  = (unsigned short*)alloc((size_t)NN*FD*2);  // 25.6 MB
  unsigned short* xh  = (unsigned short*)alloc((size_t)NN*128*2); // 12.8 MB
  unsigned short* xl  = (unsigned short*)alloc((size_t)NN*128*2); // 12.8 MB
  float* al    = (float*)alloc((size_t)NN*8*4);                   // 1.6 MB
  int*   indptr= (int*)alloc((size_t)(NN+1)*4);
  int*   cursor= (int*)alloc((size_t)NN*4);
  int*   csr   = (int*)alloc((size_t)NET*4);                      // 2.8 MB
  int*   bsums = (int*)alloc(64*4);
  float* h3    = (float*)alloc((size_t)NN*4);
  unsigned short* bt1h = (unsigned short*)alloc((size_t)256*128*2);
  unsigned short* bt1l = (unsigned short*)alloc((size_t)256*128*2);
  unsigned short* bt2h = (unsigned short*)alloc((size_t)256*256*2);
  unsigned short* bt2l = (unsigned short*)alloc((size_t)256*256*2);

  // ---- CSR build (once; same graph for all layers) ----
  hipMemsetAsync(cursor, 0, (size_t)NN*4, stream);
  count_deg<<<(NET+255)/256, 256, 0, stream>>>(ei, cursor);
  int nb = (NN+1023)/1024;
  scan_block<<<nb, 256, 0, stream>>>(cursor, indptr, bsums);
  scan_tops<<<1, 64, 0, stream>>>(bsums, nb);
  scan_add<<<(NN+255)/256, 256, 0, stream>>>(indptr, bsums, cursor);
  scatter_csr<<<(NET+255)/256, 256, 0, stream>>>(ei, cursor, csr);

  // ---- input/weight split (tiny) ----
  castBt<<<128, 256, 0, stream>>>(W1, bt1h, bt1l, 128);
  castBt<<<256, 256, 0, stream>>>(W2, bt2h, bt2l, 256);
  castA<<<(NN*128/4+255)/256, 256, 0, stream>>>(x, xh, xl, NN*128);

  dim3 gemm_grid(FD/128, (NN+127)/128);
  int agg_blocks = (NN+3)/4;

  // ---- layer 1 ----
  gemm_mfma<<<gemm_grid, 256, 0, stream>>>(xh, xl, bt1h, bt1l, hb, as1, ad1, al, NN, 128);
  gat_agg<false><<<agg_blocks, 256, 0, stream>>>(hb, al, indptr, csr, b1, oh, ol, nullptr, nullptr);
  // ---- layer 2 (fused W3 gemv; no oh/ol write) ----
  gemm_mfma<<<gemm_grid, 256, 0, stream>>>(oh, ol, bt2h, bt2l, hb, as2, ad2, al, NN, 256);
  gat_agg<true><<<agg_blocks, 256, 0, stream>>>(hb, al, indptr, csr, b2, nullptr, nullptr, W3, h3);
  // ---- layer 3 ----
  gat_agg3<<<(NN+255)/256, 256, 0, stream>>>(h3, indptr, csr, as3, ad3, b3, outp);
}

// Round 7
// 367.226 us; speedup vs baseline: 1.5994x; 1.0323x over previous
//
#include <hip/hip_runtime.h>
#include <math.h>

#define NN 50000     // nodes
#define NE 650000    // edges (without self loops)
#define NET 700000   // NE + NN self loops
#define FD 256       // H*C = 4*64
#define NEG 0.2f

static __device__ __forceinline__ float lrelu(float v){ return v > 0.f ? v : NEG*v; }

// bf16 helpers
static __device__ __forceinline__ unsigned short f2bf(float f){
  union { float f; unsigned u; } v; v.f = f;
  unsigned r = v.u + 0x7fff + ((v.u >> 16) & 1);
  return (unsigned short)(r >> 16);
}
static __device__ __forceinline__ float bf2f(unsigned short h){
  union { unsigned u; float f; } v; v.u = ((unsigned)h) << 16;
  return v.f;
}
static __device__ __forceinline__ float bflo(unsigned u){ return __uint_as_float(u << 16); }
static __device__ __forceinline__ float bfhi(unsigned u){ return __uint_as_float(u & 0xffff0000u); }

// async global->LDS DMA, 16 B per lane, LDS dest = uniform base + lane*16 (m97/m104)
static __device__ __forceinline__ void gload_lds16(const unsigned short* g, unsigned short* l){
  __builtin_amdgcn_global_load_lds(
      (const __attribute__((address_space(1))) unsigned int*)(g),
      (__attribute__((address_space(3))) unsigned int*)(l), 16, 0, 0);
}

typedef __attribute__((ext_vector_type(8))) short short8_t;  // 8 bf16 = 4 VGPR
typedef __attribute__((ext_vector_type(4))) float f32x4;

// ---------------- CSR build (graph identical for all 3 layers) ----------------
__global__ void count_deg(const int* __restrict__ ei, int* __restrict__ deg){
  int e = blockIdx.x*blockDim.x + threadIdx.x;
  if (e >= NET) return;
  int d = (e < NE) ? ei[NE + e] : (e - NE);
  atomicAdd(&deg[d], 1);
}

__global__ void scan_block(const int* __restrict__ deg, int* __restrict__ excl, int* __restrict__ bsums){
  __shared__ int sh[256];
  int t = threadIdx.x;
  int i0 = blockIdx.x*1024 + t*4;
  int v0 = (i0+0 < NN) ? deg[i0+0] : 0;
  int v1 = (i0+1 < NN) ? deg[i0+1] : 0;
  int v2 = (i0+2 < NN) ? deg[i0+2] : 0;
  int v3 = (i0+3 < NN) ? deg[i0+3] : 0;
  int tot = v0+v1+v2+v3;
  sh[t] = tot;
  __syncthreads();
  for (int off=1; off<256; off<<=1){
    int x = (t>=off) ? sh[t-off] : 0;
    __syncthreads();
    sh[t] += x;
    __syncthreads();
  }
  int base = sh[t] - tot;
  if (i0+0 < NN) excl[i0+0] = base;
  if (i0+1 < NN) excl[i0+1] = base + v0;
  if (i0+2 < NN) excl[i0+2] = base + v0+v1;
  if (i0+3 < NN) excl[i0+3] = base + v0+v1+v2;
  if (t == 255) bsums[blockIdx.x] = sh[255];
}

__global__ void scan_tops(int* bsums, int nb){
  if (threadIdx.x==0 && blockIdx.x==0){
    int run=0;
    for (int i=0;i<nb;i++){ int x=bsums[i]; bsums[i]=run; run+=x; }
  }
}

__global__ void scan_add(int* __restrict__ indptr, const int* __restrict__ bsums, int* __restrict__ cursor){
  int i = blockIdx.x*blockDim.x + threadIdx.x;
  if (i < NN){
    int v = indptr[i] + bsums[i>>10];
    indptr[i] = v;
    cursor[i] = v;
  }
  if (i == 0) indptr[NN] = NET;
}

__global__ void scatter_csr(const int* __restrict__ ei, int* __restrict__ cursor, int* __restrict__ csr){
  int e = blockIdx.x*blockDim.x + threadIdx.x;
  if (e >= NET) return;
  int s, d;
  if (e < NE){ s = ei[e]; d = ei[NE+e]; } else { s = e-NE; d = e-NE; }
  int pos = atomicAdd(&cursor[d], 1);
  csr[pos] = s;
}

// ---------------- B[K][256] fp32 -> Bt_hi/Bt_lo [256][K] bf16 (split) ----------------
__global__ void castBt(const float* __restrict__ B, unsigned short* __restrict__ bth,
                       unsigned short* __restrict__ btl, int K){
  int idx = blockIdx.x*blockDim.x + threadIdx.x;
  if (idx >= K*256) return;
  int k = idx >> 8, n = idx & 255;
  float f = B[idx];
  unsigned short h = f2bf(f);
  float lo = f - bf2f(h);
  bth[n*K + k] = h;
  btl[n*K + k] = f2bf(lo);
}

// ---------------- x fp32 -> hi/lo bf16 (row-major, once) ----------------
__global__ void castA(const float* __restrict__ x, unsigned short* __restrict__ xh,
                      unsigned short* __restrict__ xl, int n){
  int i = (blockIdx.x*blockDim.x + threadIdx.x)*4;
  if (i >= n) return;
  float4 f = *(const float4*)(x + i);
  ushort4 h, l;
  h.x = f2bf(f.x); l.x = f2bf(f.x - bf2f(h.x));
  h.y = f2bf(f.y); l.y = f2bf(f.y - bf2f(h.y));
  h.z = f2bf(f.z); l.z = f2bf(f.z - bf2f(h.z));
  h.w = f2bf(f.w); l.w = f2bf(f.w - bf2f(h.w));
  *(ushort4*)(xh + i) = h;
  *(ushort4*)(xl + i) = l;
}

// ---------------- split-bf16 MFMA GEMM, global_load_lds staging, fused al ----------------
// acc = Ah*Bh + Ah*Bl + Al*Bh (~fp32 precision). Tile 128x128, BK=32,
// contiguous k-major LDS (64 B/row) per global_load_lds constraint (m104).
__global__ __launch_bounds__(256, 2) void gemm_mfma(const unsigned short* __restrict__ Ahg,
                                                    const unsigned short* __restrict__ Alg,
                                                    const unsigned short* __restrict__ Bth,
                                                    const unsigned short* __restrict__ Btl,
                                                    unsigned short* __restrict__ Cb,
                                                    const float* __restrict__ a_src,
                                                    const float* __restrict__ a_dst,
                                                    float* __restrict__ al,
                                                    int M, int K){
  __shared__ unsigned short Ah[128*32], Al[128*32], Bh[128*32], Bl[128*32]; // 8 KB each
  int t = threadIdx.x;
  int wave = t >> 6, lane = t & 63;
  int wm = wave >> 1, wn = wave & 1;
  int quad = lane >> 4, l16 = lane & 15;
  int bm0 = blockIdx.y*128, bn0 = blockIdx.x*128;

  const unsigned short* gsrc = (wave==0)?Ahg:(wave==1)?Alg:(wave==2)?Bth:Btl;
  unsigned short* lbuf       = (wave==0)?Ah :(wave==1)?Al :(wave==2)?Bh :Bl;
  int sbase = (wave < 2) ? bm0 : bn0;
  int srow = lane >> 2;
  int skg  = (lane & 3) * 8;

  f32x4 acc[4][4];
  #pragma unroll
  for (int i=0;i<4;i++)
    #pragma unroll
    for (int j=0;j<4;j++) acc[i][j] = (f32x4){0.f,0.f,0.f,0.f};

  for (int k0 = 0; k0 < K; k0 += 32){
    __syncthreads();
    #pragma unroll
    for (int i=0;i<8;i++){
      int r = sbase + i*16 + srow;
      if (wave < 2) r = min(r, M-1);   // clamp: dup rows, never OOB
      gload_lds16(gsrc + (size_t)r*K + k0 + skg, lbuf + i*512);
    }
    __syncthreads();

    short8_t afh[4], afl[4], bfh[4], bfl[4];
    #pragma unroll
    for (int mt=0; mt<4; ++mt){
      int row = wm*64 + mt*16 + l16;
      afh[mt] = *(short8_t*)&Ah[row*32 + quad*8];
      afl[mt] = *(short8_t*)&Al[row*32 + quad*8];
    }
    #pragma unroll
    for (int nt=0; nt<4; ++nt){
      int col = wn*64 + nt*16 + l16;
      bfh[nt] = *(short8_t*)&Bh[col*32 + quad*8];
      bfl[nt] = *(short8_t*)&Bl[col*32 + quad*8];
    }
    #pragma unroll
    for (int mt=0; mt<4; ++mt)
      #pragma unroll
      for (int nt=0; nt<4; ++nt){
        acc[mt][nt] = __builtin_amdgcn_mfma_f32_16x16x32_bf16(afh[mt], bfh[nt], acc[mt][nt], 0,0,0);
        acc[mt][nt] = __builtin_amdgcn_mfma_f32_16x16x32_bf16(afh[mt], bfl[nt], acc[mt][nt], 0,0,0);
        acc[mt][nt] = __builtin_amdgcn_mfma_f32_16x16x32_bf16(afl[mt], bfh[nt], acc[mt][nt], 0,0,0);
      }
  }

  __syncthreads();   // all waves done reading LDS; lbuf becomes wave-private scratch

  // ---- epilogue 1: fused al via LDS transpose (stride 17 floats) ----
  int head_w = (bn0 >> 6) + wn;
  float cs[4], cd[4];
  #pragma unroll
  for (int nt=0; nt<4; ++nt){
    cs[nt] = a_src[head_w*64 + nt*16 + l16];
    cd[nt] = a_dst[head_w*64 + nt*16 + l16];
  }
  {
    float* fsc = (float*)lbuf;
    int grow = bm0 + wm*64 + lane;
    #pragma unroll
    for (int pass=0; pass<2; ++pass){
      #pragma unroll
      for (int mt=0; mt<4; ++mt)
        #pragma unroll
        for (int r=0; r<4; ++r){
          float p = 0.f;
          #pragma unroll
          for (int nt=0; nt<4; ++nt)
            p += acc[mt][nt][r] * (pass ? cd[nt] : cs[nt]);
          fsc[(mt*16 + quad*4 + r)*17 + l16] = p;
        }
      float s = 0.f;
      #pragma unroll
      for (int j=0; j<16; ++j) s += fsc[lane*17 + j];
      if (grow < M) al[grow*8 + pass*4 + head_w] = s;
    }
  }

  // ---- epilogue 2: Cb bf16 via per-wave LDS tile + coalesced dwordx4 ----
  unsigned short* tile = lbuf;
  #pragma unroll
  for (int mt=0; mt<4; ++mt)
    #pragma unroll
    for (int r=0; r<4; ++r){
      int rl = mt*16 + quad*4 + r;
      #pragma unroll
      for (int nt=0; nt<4; ++nt)
        tile[rl*64 + nt*16 + l16] = f2bf(acc[mt][nt][r]);
    }
  int orow = lane >> 3, ocol = (lane & 7) * 8;
  #pragma unroll
  for (int it=0; it<8; ++it){
    int rl = it*8 + orow;
    int row = bm0 + wm*64 + rl;
    if (row < M){
      uint4 v = *(uint4*)&tile[rl*64 + ocol];
      *(uint4*)(Cb + (size_t)row*FD + bn0 + wn*64 + ocol) = v;
    }
  }
}

// ---------------- GAT aggregation v3: one node per 32-lane HALF ----------------
// 2 nodes/wave, 8 nodes/block. Within a half: 32 lanes x 16 B = one full 512 B
// row per load; each lane owns 8 unique bf16 channels (no duplication, no
// acc-combine). No segment-max pass: logits bounded (|l| <~ 12), exp is safe
// in fp32 and normalization cancels the shift exactly.
template<bool FUSE_W3>
__global__ __launch_bounds__(256) void gat_agg(const unsigned short* __restrict__ hb,
                                               const float* __restrict__ al,
                                               const int* __restrict__ indptr, const int* __restrict__ csr,
                                               const float* __restrict__ bias,
                                               unsigned short* __restrict__ outh,
                                               unsigned short* __restrict__ outl,
                                               const float* __restrict__ W3,
                                               float* __restrict__ h3){
  __shared__ float ebuf[8][128];   // per node: 32 slots x 4 heads
  __shared__ int   sbuf[8][32];    // per node: 32 byte-offsets
  int wave = threadIdx.x >> 6, lane = threadIdx.x & 63;
  int half = lane >> 5, l32 = lane & 31;
  int slot = wave*2 + half;
  int n = blockIdx.x*8 + slot;
  if (n >= NN) return;
  int head8 = l32 >> 3;
  int base = indptr[n], deg = indptr[n+1] - base;
  float4 ald = *(const float4*)(al + n*8 + 4);   // same addr across half: broadcast
  float* eb = &ebuf[slot][0];
  int*   sb = &sbuf[slot][0];
  const char* hp = (const char*)hb + l32*16;

  float acc[8] = {0.f,0.f,0.f,0.f,0.f,0.f,0.f,0.f};
  float4 esum = make_float4(0.f,0.f,0.f,0.f);

  for (int j0 = 0; j0 < deg; j0 += 32){
    int j = j0 + l32;
    float4 e4 = make_float4(0.f,0.f,0.f,0.f);
    int sj = 0;
    if (j < deg){
      sj = csr[base + j];
      float4 als = *(const float4*)(al + sj*8);
      e4.x = __expf(lrelu(als.x + ald.x));
      e4.y = __expf(lrelu(als.y + ald.y));
      e4.z = __expf(lrelu(als.z + ald.z));
      e4.w = __expf(lrelu(als.w + ald.w));
      esum.x += e4.x; esum.y += e4.y; esum.z += e4.z; esum.w += e4.w;
    }
    *(float4*)&eb[l32*4] = e4;
    sb[l32] = sj << 9;                       // byte offset (FD*2 = 512)
    // wave-internal LDS write->read: compiler inserts lgkm wait; no barrier.
    int cnt  = min(32, deg - j0);
    int cpad = (cnt + 3) & ~3;               // pads read row 0 with alpha 0
    for (int tt = 0; tt < cpad; tt += 4){
      int o0 = sb[tt], o1 = sb[tt+1], o2 = sb[tt+2], o3 = sb[tt+3];
      float v0 = eb[tt*4 + head8],     v1 = eb[(tt+1)*4 + head8];
      float v2 = eb[(tt+2)*4 + head8], v3 = eb[(tt+3)*4 + head8];
      uint4 a = *(const uint4*)(hp + o0);
      uint4 b = *(const uint4*)(hp + o1);
      uint4 c = *(const uint4*)(hp + o2);
      uint4 d = *(const uint4*)(hp + o3);
      acc[0]+=v0*bflo(a.x); acc[1]+=v0*bfhi(a.x); acc[2]+=v0*bflo(a.y); acc[3]+=v0*bfhi(a.y);
      acc[4]+=v0*bflo(a.z); acc[5]+=v0*bfhi(a.z); acc[6]+=v0*bflo(a.w); acc[7]+=v0*bfhi(a.w);
      acc[0]+=v1*bflo(b.x); acc[1]+=v1*bfhi(b.x); acc[2]+=v1*bflo(b.y); acc[3]+=v1*bfhi(b.y);
      acc[4]+=v1*bflo(b.z); acc[5]+=v1*bfhi(b.z); acc[6]+=v1*bflo(b.w); acc[7]+=v1*bfhi(b.w);
      acc[0]+=v2*bflo(c.x); acc[1]+=v2*bfhi(c.x); acc[2]+=v2*bflo(c.y); acc[3]+=v2*bfhi(c.y);
      acc[4]+=v2*bflo(c.z); acc[5]+=v2*bfhi(c.z); acc[6]+=v2*bflo(c.w); acc[7]+=v2*bfhi(c.w);
      acc[0]+=v3*bflo(d.x); acc[1]+=v3*bfhi(d.x); acc[2]+=v3*bflo(d.y); acc[3]+=v3*bfhi(d.y);
      acc[4]+=v3*bflo(d.z); acc[5]+=v3*bfhi(d.z); acc[6]+=v3*bflo(d.w); acc[7]+=v3*bfhi(d.w);
    }
  }

  // esum reduction within the half (offsets <=16 stay inside the half)
  for (int off=16; off; off>>=1){
    esum.x += __shfl_xor(esum.x, off);
    esum.y += __shfl_xor(esum.y, off);
    esum.z += __shfl_xor(esum.z, off);
    esum.w += __shfl_xor(esum.w, off);
  }
  float sH = (head8==0)?esum.x:(head8==1)?esum.y:(head8==2)?esum.z:esum.w;
  float inv = 1.f/(sH + 1e-16f);
  int ch0 = l32*8;
  float4 b0 = *(const float4*)(bias + ch0);
  float4 b1 = *(const float4*)(bias + ch0 + 4);
  float o[8];
  o[0]=acc[0]*inv+b0.x; o[1]=acc[1]*inv+b0.y; o[2]=acc[2]*inv+b0.z; o[3]=acc[3]*inv+b0.w;
  o[4]=acc[4]*inv+b1.x; o[5]=acc[5]*inv+b1.y; o[6]=acc[6]*inv+b1.z; o[7]=acc[7]*inv+b1.w;
  #pragma unroll
  for (int i=0;i<8;i++) o[i] = o[i] > 0.f ? o[i] : expm1f(o[i]);   // elu

  if (FUSE_W3){
    float4 w0 = *(const float4*)(W3 + ch0);
    float4 w1 = *(const float4*)(W3 + ch0 + 4);
    float p = o[0]*w0.x + o[1]*w0.y + o[2]*w0.z + o[3]*w0.w
            + o[4]*w1.x + o[5]*w1.y + o[6]*w1.z + o[7]*w1.w;
    #pragma unroll
    for (int off=16; off; off>>=1) p += __shfl_xor(p, off);
    if (l32 == 0) h3[n] = p;
  } else {
    unsigned hi[4], lo[4];
    #pragma unroll
    for (int i=0;i<4;i++){
      unsigned short h0 = f2bf(o[2*i]),   h1 = f2bf(o[2*i+1]);
      unsigned short g0 = f2bf(o[2*i]   - bf2f(h0));
      unsigned short g1 = f2bf(o[2*i+1] - bf2f(h1));
      hi[i] = (unsigned)h0 | ((unsigned)h1 << 16);
      lo[i] = (unsigned)g0 | ((unsigned)g1 << 16);
    }
    *(uint4*)(outh + (size_t)n*FD + ch0) = make_uint4(hi[0],hi[1],hi[2],hi[3]);
    *(uint4*)(outl + (size_t)n*FD + ch0) = make_uint4(lo[0],lo[1],lo[2],lo[3]);
  }
}

// ---------------- layer 3: scalar GAT on h3 ----------------
__global__ __launch_bounds__(256) void gat_agg3(const float* __restrict__ h3, const int* __restrict__ indptr,
                                                const int* __restrict__ csr, const float* __restrict__ asrc,
                                                const float* __restrict__ adst, const float* __restrict__ b3,
                                                float* __restrict__ out){
  int n = blockIdx.x*blockDim.x + threadIdx.x;
  if (n >= NN) return;
  float as = asrc[0], ad = adst[0];
  float hd = h3[n]*ad;
  int base = indptr[n], end = indptr[n+1];
  float m = -1e30f;
  for (int e=base; e<end; ++e){
    float l = lrelu(as*h3[csr[e]] + hd);
    m = fmaxf(m, l);
  }
  float s = 0.f, w = 0.f;
  for (int e=base; e<end; ++e){
    float hv = h3[csr[e]];
    float l = lrelu(as*hv + hd);
    float ee = expf(l - m);
    s += ee; w += ee*hv;
  }
  out[n] = w/(s + 1e-16f) + b3[0];
}

extern "C" void kernel_launch(void* const* d_in, const int* in_sizes, int n_in,
                              void* d_out, int out_size, void* d_ws, size_t ws_size,
                              hipStream_t stream){
  const float* x   = (const float*)d_in[0];
  const int*   ei  = (const int*)d_in[1];
  const float* W1  = (const float*)d_in[2];
  const float* as1 = (const float*)d_in[3];
  const float* ad1 = (const float*)d_in[4];
  const float* b1  = (const float*)d_in[5];
  const float* W2  = (const float*)d_in[6];
  const float* as2 = (const float*)d_in[7];
  const float* ad2 = (const float*)d_in[8];
  const float* b2  = (const float*)d_in[9];
  const float* W3  = (const float*)d_in[10];
  const float* as3 = (const float*)d_in[11];
  const float* ad3 = (const float*)d_in[12];
  const float* b3  = (const float*)d_in[13];
  float* outp = (float*)d_out;

  char* w = (char*)d_ws;
  size_t off = 0;
  auto alloc = [&](size_t bytes)->void*{
    void* p = w + off; off += (bytes + 255) & ~(size_t)255; return p;
  };
  unsigned short* hb  = (unsigned short*)alloc((size_t)NN*FD*2);  // 25.6 MB (Cb)
  unsigned short* oh  = (unsigned short*)alloc((size_t)NN*FD*2);  // 25.6 MB
  unsigned short* ol  = (unsigned short*)alloc((size_t)NN*FD*2);  // 25.6 MB
  unsigned short* xh  = (unsigned short*)alloc((size_t)NN*128*2); // 12.8 MB
  unsigned short* xl  = (unsigned short*)alloc((size_t)NN*128*2); // 12.8 MB
  float* al    = (float*)alloc((size_t)NN*8*4);                   // 1.6 MB
  int*   indptr= (int*)alloc((size_t)(NN+1)*4);
  int*   cursor= (int*)alloc((size_t)NN*4);
  int*   csr   = (int*)alloc((size_t)NET*4);                      // 2.8 MB
  int*   bsums = (int*)alloc(64*4);
  float* h3    = (float*)alloc((size_t)NN*4);
  unsigned short* bt1h = (unsigned short*)alloc((size_t)256*128*2);
  unsigned short* bt1l = (unsigned short*)alloc((size_t)256*128*2);
  unsigned short* bt2h = (unsigned short*)alloc((size_t)256*256*2);
  unsigned short* bt2l = (unsigned short*)alloc((size_t)256*256*2);

  // ---- CSR build (once; same graph for all layers) ----
  hipMemsetAsync(cursor, 0, (size_t)NN*4, stream);
  count_deg<<<(NET+255)/256, 256, 0, stream>>>(ei, cursor);
  int nb = (NN+1023)/1024;
  scan_block<<<nb, 256, 0, stream>>>(cursor, indptr, bsums);
  scan_tops<<<1, 64, 0, stream>>>(bsums, nb);
  scan_add<<<(NN+255)/256, 256, 0, stream>>>(indptr, bsums, cursor);
  scatter_csr<<<(NET+255)/256, 256, 0, stream>>>(ei, cursor, csr);

  // ---- input/weight split (tiny) ----
  castBt<<<128, 256, 0, stream>>>(W1, bt1h, bt1l, 128);
  castBt<<<256, 256, 0, stream>>>(W2, bt2h, bt2l, 256);
  castA<<<(NN*128/4+255)/256, 256, 0, stream>>>(x, xh, xl, NN*128);

  dim3 gemm_grid(FD/128, (NN+127)/128);
  int agg_blocks = (NN+7)/8;

  // ---- layer 1 ----
  gemm_mfma<<<gemm_grid, 256, 0, stream>>>(xh, xl, bt1h, bt1l, hb, as1, ad1, al, NN, 128);
  gat_agg<false><<<agg_blocks, 256, 0, stream>>>(hb, al, indptr, csr, b1, oh, ol, nullptr, nullptr);
  // ---- layer 2 (fused W3 gemv; no oh/ol write) ----
  gemm_mfma<<<gemm_grid, 256, 0, stream>>>(oh, ol, bt2h, bt2l, hb, as2, ad2, al, NN, 256);
  gat_agg<true><<<agg_blocks, 256, 0, stream>>>(hb, al, indptr, csr, b2, nullptr, nullptr, W3, h3);
  // ---- layer 3 ----
  gat_agg3<<<(NN+255)/256, 256, 0, stream>>>(h3, indptr, csr, as3, ad3, b3, outp);
}

// Round 8
// 366.256 us; speedup vs baseline: 1.6037x; 1.0026x over previous
//
#include <hip/hip_runtime.h>
#include <math.h>

#define NN 50000     // nodes
#define NE 650000    // edges (without self loops)
#define NET 700000   // NE + NN self loops
#define FD 256       // H*C = 4*64
#define NEG 0.2f

static __device__ __forceinline__ float lrelu(float v){ return v > 0.f ? v : NEG*v; }

// bf16 helpers
static __device__ __forceinline__ unsigned short f2bf(float f){
  union { float f; unsigned u; } v; v.f = f;
  unsigned r = v.u + 0x7fff + ((v.u >> 16) & 1);
  return (unsigned short)(r >> 16);
}
static __device__ __forceinline__ float bf2f(unsigned short h){
  union { unsigned u; float f; } v; v.u = ((unsigned)h) << 16;
  return v.f;
}
static __device__ __forceinline__ float bflo(unsigned u){ return __uint_as_float(u << 16); }
static __device__ __forceinline__ float bfhi(unsigned u){ return __uint_as_float(u & 0xffff0000u); }

// async global->LDS DMA, 16 B per lane, LDS dest = uniform base + lane*16 (m97/m104)
static __device__ __forceinline__ void gload_lds16(const unsigned short* g, unsigned short* l){
  __builtin_amdgcn_global_load_lds(
      (const __attribute__((address_space(1))) unsigned int*)(g),
      (__attribute__((address_space(3))) unsigned int*)(l), 16, 0, 0);
}

typedef __attribute__((ext_vector_type(8))) short short8_t;  // 8 bf16 = 4 VGPR
typedef __attribute__((ext_vector_type(4))) float f32x4;

// ---------------- CSR build (graph identical for all 3 layers) ----------------
__global__ void count_deg(const int* __restrict__ ei, int* __restrict__ deg){
  int e = blockIdx.x*blockDim.x + threadIdx.x;
  if (e >= NET) return;
  int d = (e < NE) ? ei[NE + e] : (e - NE);
  atomicAdd(&deg[d], 1);
}

__global__ void scan_block(const int* __restrict__ deg, int* __restrict__ excl, int* __restrict__ bsums){
  __shared__ int sh[256];
  int t = threadIdx.x;
  int i0 = blockIdx.x*1024 + t*4;
  int v0 = (i0+0 < NN) ? deg[i0+0] : 0;
  int v1 = (i0+1 < NN) ? deg[i0+1] : 0;
  int v2 = (i0+2 < NN) ? deg[i0+2] : 0;
  int v3 = (i0+3 < NN) ? deg[i0+3] : 0;
  int tot = v0+v1+v2+v3;
  sh[t] = tot;
  __syncthreads();
  for (int off=1; off<256; off<<=1){
    int x = (t>=off) ? sh[t-off] : 0;
    __syncthreads();
    sh[t] += x;
    __syncthreads();
  }
  int base = sh[t] - tot;
  if (i0+0 < NN) excl[i0+0] = base;
  if (i0+1 < NN) excl[i0+1] = base + v0;
  if (i0+2 < NN) excl[i0+2] = base + v0+v1;
  if (i0+3 < NN) excl[i0+3] = base + v0+v1+v2;
  if (t == 255) bsums[blockIdx.x] = sh[255];
}

__global__ void scan_tops(int* bsums, int nb){
  if (threadIdx.x==0 && blockIdx.x==0){
    int run=0;
    for (int i=0;i<nb;i++){ int x=bsums[i]; bsums[i]=run; run+=x; }
  }
}

__global__ void scan_add(int* __restrict__ indptr, const int* __restrict__ bsums, int* __restrict__ cursor){
  int i = blockIdx.x*blockDim.x + threadIdx.x;
  if (i < NN){
    int v = indptr[i] + bsums[i>>10];
    indptr[i] = v;
    cursor[i] = v;
  }
  if (i == 0) indptr[NN] = NET;
}

__global__ void scatter_csr(const int* __restrict__ ei, int* __restrict__ cursor, int* __restrict__ csr){
  int e = blockIdx.x*blockDim.x + threadIdx.x;
  if (e >= NET) return;
  int s, d;
  if (e < NE){ s = ei[e]; d = ei[NE+e]; } else { s = e-NE; d = e-NE; }
  int pos = atomicAdd(&cursor[d], 1);
  csr[pos] = s;
}

// ---------------- B[K][256] fp32 -> Bt_hi/Bt_lo [256][K] bf16 (split) ----------------
__global__ void castBt(const float* __restrict__ B, unsigned short* __restrict__ bth,
                       unsigned short* __restrict__ btl, int K){
  int idx = blockIdx.x*blockDim.x + threadIdx.x;
  if (idx >= K*256) return;
  int k = idx >> 8, n = idx & 255;
  float f = B[idx];
  unsigned short h = f2bf(f);
  float lo = f - bf2f(h);
  bth[n*K + k] = h;
  btl[n*K + k] = f2bf(lo);
}

// ---------------- x fp32 -> hi/lo bf16 (row-major, once) ----------------
__global__ void castA(const float* __restrict__ x, unsigned short* __restrict__ xh,
                      unsigned short* __restrict__ xl, int n){
  int i = (blockIdx.x*blockDim.x + threadIdx.x)*4;
  if (i >= n) return;
  float4 f = *(const float4*)(x + i);
  ushort4 h, l;
  h.x = f2bf(f.x); l.x = f2bf(f.x - bf2f(h.x));
  h.y = f2bf(f.y); l.y = f2bf(f.y - bf2f(h.y));
  h.z = f2bf(f.z); l.z = f2bf(f.z - bf2f(h.z));
  h.w = f2bf(f.w); l.w = f2bf(f.w - bf2f(h.w));
  *(ushort4*)(xh + i) = h;
  *(ushort4*)(xl + i) = l;
}

// ---------------- split-bf16 MFMA GEMM, global_load_lds staging, fused al ----------------
// acc = Ah*Bh + Ah*Bl + Al*Bh (~fp32 precision). Tile 128x128, BK=32,
// contiguous k-major LDS (64 B/row) per global_load_lds constraint (m104).
__global__ __launch_bounds__(256, 2) void gemm_mfma(const unsigned short* __restrict__ Ahg,
                                                    const unsigned short* __restrict__ Alg,
                                                    const unsigned short* __restrict__ Bth,
                                                    const unsigned short* __restrict__ Btl,
                                                    unsigned short* __restrict__ Cb,
                                                    const float* __restrict__ a_src,
                                                    const float* __restrict__ a_dst,
                                                    float* __restrict__ al,
                                                    int M, int K){
  __shared__ unsigned short Ah[128*32], Al[128*32], Bh[128*32], Bl[128*32]; // 8 KB each
  int t = threadIdx.x;
  int wave = t >> 6, lane = t & 63;
  int wm = wave >> 1, wn = wave & 1;
  int quad = lane >> 4, l16 = lane & 15;
  int bm0 = blockIdx.y*128, bn0 = blockIdx.x*128;

  const unsigned short* gsrc = (wave==0)?Ahg:(wave==1)?Alg:(wave==2)?Bth:Btl;
  unsigned short* lbuf       = (wave==0)?Ah :(wave==1)?Al :(wave==2)?Bh :Bl;
  int sbase = (wave < 2) ? bm0 : bn0;
  int srow = lane >> 2;
  int skg  = (lane & 3) * 8;

  f32x4 acc[4][4];
  #pragma unroll
  for (int i=0;i<4;i++)
    #pragma unroll
    for (int j=0;j<4;j++) acc[i][j] = (f32x4){0.f,0.f,0.f,0.f};

  for (int k0 = 0; k0 < K; k0 += 32){
    __syncthreads();
    #pragma unroll
    for (int i=0;i<8;i++){
      int r = sbase + i*16 + srow;
      if (wave < 2) r = min(r, M-1);   // clamp: dup rows, never OOB
      gload_lds16(gsrc + (size_t)r*K + k0 + skg, lbuf + i*512);
    }
    __syncthreads();

    short8_t afh[4], afl[4], bfh[4], bfl[4];
    #pragma unroll
    for (int mt=0; mt<4; ++mt){
      int row = wm*64 + mt*16 + l16;
      afh[mt] = *(short8_t*)&Ah[row*32 + quad*8];
      afl[mt] = *(short8_t*)&Al[row*32 + quad*8];
    }
    #pragma unroll
    for (int nt=0; nt<4; ++nt){
      int col = wn*64 + nt*16 + l16;
      bfh[nt] = *(short8_t*)&Bh[col*32 + quad*8];
      bfl[nt] = *(short8_t*)&Bl[col*32 + quad*8];
    }
    #pragma unroll
    for (int mt=0; mt<4; ++mt)
      #pragma unroll
      for (int nt=0; nt<4; ++nt){
        acc[mt][nt] = __builtin_amdgcn_mfma_f32_16x16x32_bf16(afh[mt], bfh[nt], acc[mt][nt], 0,0,0);
        acc[mt][nt] = __builtin_amdgcn_mfma_f32_16x16x32_bf16(afh[mt], bfl[nt], acc[mt][nt], 0,0,0);
        acc[mt][nt] = __builtin_amdgcn_mfma_f32_16x16x32_bf16(afl[mt], bfh[nt], acc[mt][nt], 0,0,0);
      }
  }

  __syncthreads();   // all waves done reading LDS; lbuf becomes wave-private scratch

  // ---- epilogue 1: fused al via LDS transpose (stride 17 floats) ----
  int head_w = (bn0 >> 6) + wn;
  float cs[4], cd[4];
  #pragma unroll
  for (int nt=0; nt<4; ++nt){
    cs[nt] = a_src[head_w*64 + nt*16 + l16];
    cd[nt] = a_dst[head_w*64 + nt*16 + l16];
  }
  {
    float* fsc = (float*)lbuf;
    int grow = bm0 + wm*64 + lane;
    #pragma unroll
    for (int pass=0; pass<2; ++pass){
      #pragma unroll
      for (int mt=0; mt<4; ++mt)
        #pragma unroll
        for (int r=0; r<4; ++r){
          float p = 0.f;
          #pragma unroll
          for (int nt=0; nt<4; ++nt)
            p += acc[mt][nt][r] * (pass ? cd[nt] : cs[nt]);
          fsc[(mt*16 + quad*4 + r)*17 + l16] = p;
        }
      float s = 0.f;
      #pragma unroll
      for (int j=0; j<16; ++j) s += fsc[lane*17 + j];
      if (grow < M) al[grow*8 + pass*4 + head_w] = s;
    }
  }

  // ---- epilogue 2: Cb bf16 via per-wave LDS tile + coalesced dwordx4 ----
  unsigned short* tile = lbuf;
  #pragma unroll
  for (int mt=0; mt<4; ++mt)
    #pragma unroll
    for (int r=0; r<4; ++r){
      int rl = mt*16 + quad*4 + r;
      #pragma unroll
      for (int nt=0; nt<4; ++nt)
        tile[rl*64 + nt*16 + l16] = f2bf(acc[mt][nt][r]);
    }
  int orow = lane >> 3, ocol = (lane & 7) * 8;
  #pragma unroll
  for (int it=0; it<8; ++it){
    int rl = it*8 + orow;
    int row = bm0 + wm*64 + rl;
    if (row < M){
      uint4 v = *(uint4*)&tile[rl*64 + ocol];
      *(uint4*)(Cb + (size_t)row*FD + bn0 + wn*64 + ocol) = v;
    }
  }
}

// ---------------- GAT aggregation: one node per 32-lane half, 8-deep gather MLP ----
// 2 nodes/wave, 8 nodes/block. 32 lanes x 16 B = one 512 B row per load; each
// lane owns 8 unique bf16 channels. No segment-max (logits bounded; exp safe in
// fp32; normalization cancels the shift). 8 x 1KB loads in flight per wave.
template<bool FUSE_W3>
__global__ __launch_bounds__(256) void gat_agg(const unsigned short* __restrict__ hb,
                                               const float* __restrict__ al,
                                               const int* __restrict__ indptr, const int* __restrict__ csr,
                                               const float* __restrict__ bias,
                                               unsigned short* __restrict__ outh,
                                               unsigned short* __restrict__ outl,
                                               const float* __restrict__ W3,
                                               float* __restrict__ h3){
  __shared__ float ebuf[8][128];   // per node: 32 slots x 4 heads
  __shared__ int   sbuf[8][32];    // per node: 32 byte-offsets
  int wave = threadIdx.x >> 6, lane = threadIdx.x & 63;
  int half = lane >> 5, l32 = lane & 31;
  int slot = wave*2 + half;
  int n = blockIdx.x*8 + slot;
  if (n >= NN) return;
  int head8 = l32 >> 3;
  int2 ip = *(const int2*)(indptr + n);
  int base = ip.x, deg = ip.y - ip.x;
  float4 ald = *(const float4*)(al + n*8 + 4);   // uniform across half: broadcast
  float* eb = &ebuf[slot][0];
  int*   sb = &sbuf[slot][0];
  const char* hp = (const char*)hb + l32*16;

  float acc[8] = {0.f,0.f,0.f,0.f,0.f,0.f,0.f,0.f};
  float4 esum = make_float4(0.f,0.f,0.f,0.f);

  for (int j0 = 0; j0 < deg; j0 += 32){
    int j = j0 + l32;
    float4 e4 = make_float4(0.f,0.f,0.f,0.f);
    int sj = 0;
    if (j < deg){
      sj = csr[base + j];
      float4 als = *(const float4*)(al + sj*8);
      e4.x = __expf(lrelu(als.x + ald.x));
      e4.y = __expf(lrelu(als.y + ald.y));
      e4.z = __expf(lrelu(als.z + ald.z));
      e4.w = __expf(lrelu(als.w + ald.w));
      esum.x += e4.x; esum.y += e4.y; esum.z += e4.z; esum.w += e4.w;
    }
    *(float4*)&eb[l32*4] = e4;
    sb[l32] = sj << 9;                       // byte offset (FD*2 = 512)
    // wave-internal LDS write->read: compiler inserts lgkm wait; no barrier.
    int cnt  = min(32, deg - j0);
    int cpad = (cnt + 7) & ~7;               // pad reads row 0 with alpha 0
    for (int tt = 0; tt < cpad; tt += 8){
      uint4 r[8];
      float v[8];
      #pragma unroll
      for (int q=0; q<8; ++q){
        int o = sb[tt+q];
        v[q] = eb[(tt+q)*4 + head8];
        r[q] = *(const uint4*)(hp + o);
      }
      #pragma unroll
      for (int q=0; q<8; ++q){
        acc[0]+=v[q]*bflo(r[q].x); acc[1]+=v[q]*bfhi(r[q].x);
        acc[2]+=v[q]*bflo(r[q].y); acc[3]+=v[q]*bfhi(r[q].y);
        acc[4]+=v[q]*bflo(r[q].z); acc[5]+=v[q]*bfhi(r[q].z);
        acc[6]+=v[q]*bflo(r[q].w); acc[7]+=v[q]*bfhi(r[q].w);
      }
    }
  }

  // esum reduction within the half (offsets <=16 stay inside the half)
  for (int off=16; off; off>>=1){
    esum.x += __shfl_xor(esum.x, off);
    esum.y += __shfl_xor(esum.y, off);
    esum.z += __shfl_xor(esum.z, off);
    esum.w += __shfl_xor(esum.w, off);
  }
  float sH = (head8==0)?esum.x:(head8==1)?esum.y:(head8==2)?esum.z:esum.w;
  float inv = 1.f/(sH + 1e-16f);
  int ch0 = l32*8;
  float4 b0 = *(const float4*)(bias + ch0);
  float4 b1 = *(const float4*)(bias + ch0 + 4);
  float o[8];
  o[0]=acc[0]*inv+b0.x; o[1]=acc[1]*inv+b0.y; o[2]=acc[2]*inv+b0.z; o[3]=acc[3]*inv+b0.w;
  o[4]=acc[4]*inv+b1.x; o[5]=acc[5]*inv+b1.y; o[6]=acc[6]*inv+b1.z; o[7]=acc[7]*inv+b1.w;
  #pragma unroll
  for (int i=0;i<8;i++) o[i] = o[i] > 0.f ? o[i] : expm1f(o[i]);   // elu

  if (FUSE_W3){
    float4 w0 = *(const float4*)(W3 + ch0);
    float4 w1 = *(const float4*)(W3 + ch0 + 4);
    float p = o[0]*w0.x + o[1]*w0.y + o[2]*w0.z + o[3]*w0.w
            + o[4]*w1.x + o[5]*w1.y + o[6]*w1.z + o[7]*w1.w;
    #pragma unroll
    for (int off=16; off; off>>=1) p += __shfl_xor(p, off);
    if (l32 == 0) h3[n] = p;
  } else {
    unsigned hi[4], lo[4];
    #pragma unroll
    for (int i=0;i<4;i++){
      unsigned short h0 = f2bf(o[2*i]),   h1 = f2bf(o[2*i+1]);
      unsigned short g0 = f2bf(o[2*i]   - bf2f(h0));
      unsigned short g1 = f2bf(o[2*i+1] - bf2f(h1));
      hi[i] = (unsigned)h0 | ((unsigned)h1 << 16);
      lo[i] = (unsigned)g0 | ((unsigned)g1 << 16);
    }
    *(uint4*)(outh + (size_t)n*FD + ch0) = make_uint4(hi[0],hi[1],hi[2],hi[3]);
    *(uint4*)(outl + (size_t)n*FD + ch0) = make_uint4(lo[0],lo[1],lo[2],lo[3]);
  }
}

// ---------------- layer 3: scalar GAT on h3 ----------------
__global__ __launch_bounds__(256) void gat_agg3(const float* __restrict__ h3, const int* __restrict__ indptr,
                                                const int* __restrict__ csr, const float* __restrict__ asrc,
                                                const float* __restrict__ adst, const float* __restrict__ b3,
                                                float* __restrict__ out){
  int n = blockIdx.x*blockDim.x + threadIdx.x;
  if (n >= NN) return;
  float as = asrc[0], ad = adst[0];
  float hd = h3[n]*ad;
  int base = indptr[n], end = indptr[n+1];
  float m = -1e30f;
  for (int e=base; e<end; ++e){
    float l = lrelu(as*h3[csr[e]] + hd);
    m = fmaxf(m, l);
  }
  float s = 0.f, w = 0.f;
  for (int e=base; e<end; ++e){
    float hv = h3[csr[e]];
    float l = lrelu(as*hv + hd);
    float ee = expf(l - m);
    s += ee; w += ee*hv;
  }
  out[n] = w/(s + 1e-16f) + b3[0];
}

extern "C" void kernel_launch(void* const* d_in, const int* in_sizes, int n_in,
                              void* d_out, int out_size, void* d_ws, size_t ws_size,
                              hipStream_t stream){
  const float* x   = (const float*)d_in[0];
  const int*   ei  = (const int*)d_in[1];
  const float* W1  = (const float*)d_in[2];
  const float* as1 = (const float*)d_in[3];
  const float* ad1 = (const float*)d_in[4];
  const float* b1  = (const float*)d_in[5];
  const float* W2  = (const float*)d_in[6];
  const float* as2 = (const float*)d_in[7];
  const float* ad2 = (const float*)d_in[8];
  const float* b2  = (const float*)d_in[9];
  const float* W3  = (const float*)d_in[10];
  const float* as3 = (const float*)d_in[11];
  const float* ad3 = (const float*)d_in[12];
  const float* b3  = (const float*)d_in[13];
  float* outp = (float*)d_out;

  char* w = (char*)d_ws;
  size_t off = 0;
  auto alloc = [&](size_t bytes)->void*{
    void* p = w + off; off += (bytes + 255) & ~(size_t)255; return p;
  };
  unsigned short* hb  = (unsigned short*)alloc((size_t)NN*FD*2);  // 25.6 MB (Cb)
  unsigned short* oh  = (unsigned short*)alloc((size_t)NN*FD*2);  // 25.6 MB
  unsigned short* ol  = (unsigned short*)alloc((size_t)NN*FD*2);  // 25.6 MB
  unsigned short* xh  = (unsigned short*)alloc((size_t)NN*128*2); // 12.8 MB
  unsigned short* xl  = (unsigned short*)alloc((size_t)NN*128*2); // 12.8 MB
  float* al    = (float*)alloc((size_t)NN*8*4);                   // 1.6 MB
  int*   indptr= (int*)alloc((size_t)(NN+1)*4);
  int*   cursor= (int*)alloc((size_t)NN*4);
  int*   csr   = (int*)alloc((size_t)NET*4);                      // 2.8 MB
  int*   bsums = (int*)alloc(64*4);
  float* h3    = (float*)alloc((size_t)NN*4);
  unsigned short* bt1h = (unsigned short*)alloc((size_t)256*128*2);
  unsigned short* bt1l = (unsigned short*)alloc((size_t)256*128*2);
  unsigned short* bt2h = (unsigned short*)alloc((size_t)256*256*2);
  unsigned short* bt2l = (unsigned short*)alloc((size_t)256*256*2);

  // ---- CSR build (once; same graph for all layers) ----
  hipMemsetAsync(cursor, 0, (size_t)NN*4, stream);
  count_deg<<<(NET+255)/256, 256, 0, stream>>>(ei, cursor);
  int nb = (NN+1023)/1024;
  scan_block<<<nb, 256, 0, stream>>>(cursor, indptr, bsums);
  scan_tops<<<1, 64, 0, stream>>>(bsums, nb);
  scan_add<<<(NN+255)/256, 256, 0, stream>>>(indptr, bsums, cursor);
  scatter_csr<<<(NET+255)/256, 256, 0, stream>>>(ei, cursor, csr);

  // ---- input/weight split (tiny) ----
  castBt<<<128, 256, 0, stream>>>(W1, bt1h, bt1l, 128);
  castBt<<<256, 256, 0, stream>>>(W2, bt2h, bt2l, 256);
  castA<<<(NN*128/4+255)/256, 256, 0, stream>>>(x, xh, xl, NN*128);

  dim3 gemm_grid(FD/128, (NN+127)/128);
  int agg_blocks = (NN+7)/8;

  // ---- layer 1 ----
  gemm_mfma<<<gemm_grid, 256, 0, stream>>>(xh, xl, bt1h, bt1l, hb, as1, ad1, al, NN, 128);
  gat_agg<false><<<agg_blocks, 256, 0, stream>>>(hb, al, indptr, csr, b1, oh, ol, nullptr, nullptr);
  // ---- layer 2 (fused W3 gemv; no oh/ol write) ----
  gemm_mfma<<<gemm_grid, 256, 0, stream>>>(oh, ol, bt2h, bt2l, hb, as2, ad2, al, NN, 256);
  gat_agg<true><<<agg_blocks, 256, 0, stream>>>(hb, al, indptr, csr, b2, nullptr, nullptr, W3, h3);
  // ---- layer 3 ----
  gat_agg3<<<(NN+255)/256, 256, 0, stream>>>(h3, indptr, csr, as3, ad3, b3, outp);
}

// Round 9
// 352.199 us; speedup vs baseline: 1.6677x; 1.0399x over previous
//
#include <hip/hip_runtime.h>
#include <math.h>

#define NN 50000     // nodes
#define NE 650000    // edges (without self loops)
#define NET 700000   // NE + NN self loops
#define FD 256       // H*C = 4*64
#define NEG 0.2f

static __device__ __forceinline__ float lrelu(float v){ return v > 0.f ? v : NEG*v; }

// bf16 helpers
static __device__ __forceinline__ unsigned short f2bf(float f){
  union { float f; unsigned u; } v; v.f = f;
  unsigned r = v.u + 0x7fff + ((v.u >> 16) & 1);
  return (unsigned short)(r >> 16);
}
static __device__ __forceinline__ float bf2f(unsigned short h){
  union { unsigned u; float f; } v; v.u = ((unsigned)h) << 16;
  return v.f;
}
static __device__ __forceinline__ float bflo(unsigned u){ return __uint_as_float(u << 16); }
static __device__ __forceinline__ float bfhi(unsigned u){ return __uint_as_float(u & 0xffff0000u); }

// async global->LDS DMA, 16 B per lane, LDS dest = uniform base + lane*16 (m97/m104)
static __device__ __forceinline__ void gload_lds16(const unsigned short* g, unsigned short* l){
  __builtin_amdgcn_global_load_lds(
      (const __attribute__((address_space(1))) unsigned int*)(g),
      (__attribute__((address_space(3))) unsigned int*)(l), 16, 0, 0);
}

typedef __attribute__((ext_vector_type(8))) short short8_t;  // 8 bf16 = 4 VGPR
typedef __attribute__((ext_vector_type(4))) float f32x4;

// ---------------- CSR build (graph identical for all 3 layers) ----------------
__global__ void count_deg(const int* __restrict__ ei, int* __restrict__ deg){
  int e = blockIdx.x*blockDim.x + threadIdx.x;
  if (e >= NET) return;
  int d = (e < NE) ? ei[NE + e] : (e - NE);
  atomicAdd(&deg[d], 1);
}

__global__ void scan_block(const int* __restrict__ deg, int* __restrict__ excl, int* __restrict__ bsums){
  __shared__ int sh[256];
  int t = threadIdx.x;
  int i0 = blockIdx.x*1024 + t*4;
  int v0 = (i0+0 < NN) ? deg[i0+0] : 0;
  int v1 = (i0+1 < NN) ? deg[i0+1] : 0;
  int v2 = (i0+2 < NN) ? deg[i0+2] : 0;
  int v3 = (i0+3 < NN) ? deg[i0+3] : 0;
  int tot = v0+v1+v2+v3;
  sh[t] = tot;
  __syncthreads();
  for (int off=1; off<256; off<<=1){
    int x = (t>=off) ? sh[t-off] : 0;
    __syncthreads();
    sh[t] += x;
    __syncthreads();
  }
  int base = sh[t] - tot;
  if (i0+0 < NN) excl[i0+0] = base;
  if (i0+1 < NN) excl[i0+1] = base + v0;
  if (i0+2 < NN) excl[i0+2] = base + v0+v1;
  if (i0+3 < NN) excl[i0+3] = base + v0+v1+v2;
  if (t == 255) bsums[blockIdx.x] = sh[255];
}

// wave-parallel exclusive prefix over <=64 block sums (was: serial 1-thread loop
// = 49 dependent global round-trips ~15us of latency)
__global__ void scan_tops(int* bsums, int nb){
  int lane = threadIdx.x & 63;
  int v = (lane < nb) ? bsums[lane] : 0;
  int orig = v;
  for (int off=1; off<64; off<<=1){
    int u = __shfl_up(v, off);
    if (lane >= off) v += u;
  }
  v -= orig;   // exclusive
  if (lane < nb) bsums[lane] = v;
}

__global__ void scan_add(int* __restrict__ indptr, const int* __restrict__ bsums, int* __restrict__ cursor){
  int i = blockIdx.x*blockDim.x + threadIdx.x;
  if (i < NN){
    int v = indptr[i] + bsums[i>>10];
    indptr[i] = v;
    cursor[i] = v;
  }
  if (i == 0) indptr[NN] = NET;
}

__global__ void scatter_csr(const int* __restrict__ ei, int* __restrict__ cursor, int* __restrict__ csr){
  int e = blockIdx.x*blockDim.x + threadIdx.x;
  if (e >= NET) return;
  int s, d;
  if (e < NE){ s = ei[e]; d = ei[NE+e]; } else { s = e-NE; d = e-NE; }
  int pos = atomicAdd(&cursor[d], 1);
  csr[pos] = s;
}

// ---------------- merged cast kernel: x -> xh/xl, W1/W2 -> split+transpose ----
// region 0: [0, NX)                      x fp32 -> xh/xl bf16 (row-major)
// region 1: [NX, NX+128*256)             W1 [128][256] -> bt1 [256][128]
// region 2: [NX+128*256, NX+128*256+256*256)  W2 [256][256] -> bt2 [256][256]
#define NX (NN*128)
__global__ void cast_all(const float* __restrict__ x, const float* __restrict__ W1,
                         const float* __restrict__ W2,
                         unsigned short* __restrict__ xh, unsigned short* __restrict__ xl,
                         unsigned short* __restrict__ bt1h, unsigned short* __restrict__ bt1l,
                         unsigned short* __restrict__ bt2h, unsigned short* __restrict__ bt2l){
  int i = (blockIdx.x*blockDim.x + threadIdx.x)*4;
  if (i < NX){
    float4 f = *(const float4*)(x + i);
    ushort4 h, l;
    h.x = f2bf(f.x); l.x = f2bf(f.x - bf2f(h.x));
    h.y = f2bf(f.y); l.y = f2bf(f.y - bf2f(h.y));
    h.z = f2bf(f.z); l.z = f2bf(f.z - bf2f(h.z));
    h.w = f2bf(f.w); l.w = f2bf(f.w - bf2f(h.w));
    *(ushort4*)(xh + i) = h;
    *(ushort4*)(xl + i) = l;
    return;
  }
  int e, K;
  const float* B;
  unsigned short *bh, *bl;
  if (i < NX + 128*256){ e = i - NX; K = 128; B = W1; bh = bt1h; bl = bt1l; }
  else if (i < NX + 128*256 + 256*256){ e = i - NX - 128*256; K = 256; B = W2; bh = bt2h; bl = bt2l; }
  else return;
  int k = e >> 8, n = e & 255;
  float4 f = *(const float4*)(B + e);
  #pragma unroll
  for (int j=0;j<4;j++){
    float fv = (j==0)?f.x:(j==1)?f.y:(j==2)?f.z:f.w;
    unsigned short h = f2bf(fv);
    bh[(n+j)*K + k] = h;
    bl[(n+j)*K + k] = f2bf(fv - bf2f(h));
  }
}

// ---------------- split-bf16 MFMA GEMM, pipelined global_load_lds, fused al ----
// acc = Ah*Bh + Ah*Bl + Al*Bh (~fp32 precision). Tile 128x128, BK=32,
// contiguous k-major LDS (64 B/row) per global_load_lds constraint (m104).
// K-loop pipelined: frag ds_reads -> barrier -> DMA(next) -> MFMA(cur), so the
// 48 MFMAs cover the DMA flight time (was: sync; DMA; drain-sync; compute).
template<int K>
__global__ __launch_bounds__(256, 2) void gemm_mfma(const unsigned short* __restrict__ Ahg,
                                                    const unsigned short* __restrict__ Alg,
                                                    const unsigned short* __restrict__ Bth,
                                                    const unsigned short* __restrict__ Btl,
                                                    unsigned short* __restrict__ Cb,
                                                    const float* __restrict__ a_src,
                                                    const float* __restrict__ a_dst,
                                                    float* __restrict__ al,
                                                    int M){
  constexpr int ITERS = K/32;
  __shared__ unsigned short Ah[128*32], Al[128*32], Bh[128*32], Bl[128*32]; // 8 KB each
  int t = threadIdx.x;
  int wave = t >> 6, lane = t & 63;
  int wm = wave >> 1, wn = wave & 1;
  int quad = lane >> 4, l16 = lane & 15;
  int bm0 = blockIdx.y*128, bn0 = blockIdx.x*128;

  const unsigned short* gsrc = (wave==0)?Ahg:(wave==1)?Alg:(wave==2)?Bth:Btl;
  unsigned short* lbuf       = (wave==0)?Ah :(wave==1)?Al :(wave==2)?Bh :Bl;
  int sbase = (wave < 2) ? bm0 : bn0;
  int srow = lane >> 2;
  int skg  = (lane & 3) * 8;

  // per-row global base pointers (row index constant across k-iters)
  const unsigned short* gp[8];
  #pragma unroll
  for (int i=0;i<8;i++){
    int r = sbase + i*16 + srow;
    if (wave < 2) r = min(r, M-1);   // clamp: dup rows, never OOB
    gp[i] = gsrc + (size_t)r*K + skg;
  }

  f32x4 acc[4][4];
  #pragma unroll
  for (int i=0;i<4;i++)
    #pragma unroll
    for (int j=0;j<4;j++) acc[i][j] = (f32x4){0.f,0.f,0.f,0.f};

  // prologue: DMA iter 0
  #pragma unroll
  for (int i=0;i<8;i++) gload_lds16(gp[i], lbuf + i*512);

  #pragma unroll
  for (int it=0; it<ITERS; ++it){
    __syncthreads();                       // drain DMA(it) (vmcnt(0) at barrier)

    short8_t afh[4], afl[4], bfh[4], bfl[4];
    #pragma unroll
    for (int mt=0; mt<4; ++mt){
      int row = wm*64 + mt*16 + l16;
      afh[mt] = *(short8_t*)&Ah[row*32 + quad*8];
      afl[mt] = *(short8_t*)&Al[row*32 + quad*8];
    }
    #pragma unroll
    for (int nt=0; nt<4; ++nt){
      int col = wn*64 + nt*16 + l16;
      bfh[nt] = *(short8_t*)&Bh[col*32 + quad*8];
      bfl[nt] = *(short8_t*)&Bl[col*32 + quad*8];
    }
    __syncthreads();                       // all frag reads done; LDS writable

    if (it+1 < ITERS){
      int k0 = (it+1)*32;
      #pragma unroll
      for (int i=0;i<8;i++) gload_lds16(gp[i] + k0, lbuf + i*512);
    }

    #pragma unroll
    for (int mt=0; mt<4; ++mt)
      #pragma unroll
      for (int nt=0; nt<4; ++nt){
        acc[mt][nt] = __builtin_amdgcn_mfma_f32_16x16x32_bf16(afh[mt], bfh[nt], acc[mt][nt], 0,0,0);
        acc[mt][nt] = __builtin_amdgcn_mfma_f32_16x16x32_bf16(afh[mt], bfl[nt], acc[mt][nt], 0,0,0);
        acc[mt][nt] = __builtin_amdgcn_mfma_f32_16x16x32_bf16(afl[mt], bfh[nt], acc[mt][nt], 0,0,0);
      }
  }
  // frag reads all completed before the last in-loop barrier; LDS now
  // wave-private scratch (each wave only touches its own lbuf below).

  // ---- epilogue 1: fused al via LDS transpose (stride 17 floats) ----
  int head_w = (bn0 >> 6) + wn;
  float cs[4], cd[4];
  #pragma unroll
  for (int nt=0; nt<4; ++nt){
    cs[nt] = a_src[head_w*64 + nt*16 + l16];
    cd[nt] = a_dst[head_w*64 + nt*16 + l16];
  }
  {
    float* fsc = (float*)lbuf;
    int grow = bm0 + wm*64 + lane;
    #pragma unroll
    for (int pass=0; pass<2; ++pass){
      #pragma unroll
      for (int mt=0; mt<4; ++mt)
        #pragma unroll
        for (int r=0; r<4; ++r){
          float p = 0.f;
          #pragma unroll
          for (int nt=0; nt<4; ++nt)
            p += acc[mt][nt][r] * (pass ? cd[nt] : cs[nt]);
          fsc[(mt*16 + quad*4 + r)*17 + l16] = p;
        }
      float s = 0.f;
      #pragma unroll
      for (int j=0; j<16; ++j) s += fsc[lane*17 + j];
      if (grow < M) al[grow*8 + pass*4 + head_w] = s;
    }
  }

  // ---- epilogue 2: Cb bf16 via per-wave LDS tile + coalesced dwordx4 ----
  unsigned short* tile = lbuf;
  #pragma unroll
  for (int mt=0; mt<4; ++mt)
    #pragma unroll
    for (int r=0; r<4; ++r){
      int rl = mt*16 + quad*4 + r;
      #pragma unroll
      for (int nt=0; nt<4; ++nt)
        tile[rl*64 + nt*16 + l16] = f2bf(acc[mt][nt][r]);
    }
  int orow = lane >> 3, ocol = (lane & 7) * 8;
  #pragma unroll
  for (int it=0; it<8; ++it){
    int rl = it*8 + orow;
    int row = bm0 + wm*64 + rl;
    if (row < M){
      uint4 v = *(uint4*)&tile[rl*64 + ocol];
      *(uint4*)(Cb + (size_t)row*FD + bn0 + wn*64 + ocol) = v;
    }
  }
}

// ---------------- GAT aggregation: one node per 32-lane half, 8-deep gather MLP ----
template<bool FUSE_W3>
__global__ __launch_bounds__(256) void gat_agg(const unsigned short* __restrict__ hb,
                                               const float* __restrict__ al,
                                               const int* __restrict__ indptr, const int* __restrict__ csr,
                                               const float* __restrict__ bias,
                                               unsigned short* __restrict__ outh,
                                               unsigned short* __restrict__ outl,
                                               const float* __restrict__ W3,
                                               float* __restrict__ h3){
  __shared__ float ebuf[8][128];   // per node: 32 slots x 4 heads
  __shared__ int   sbuf[8][32];    // per node: 32 byte-offsets
  int wave = threadIdx.x >> 6, lane = threadIdx.x & 63;
  int half = lane >> 5, l32 = lane & 31;
  int slot = wave*2 + half;
  int n = blockIdx.x*8 + slot;
  if (n >= NN) return;
  int head8 = l32 >> 3;
  int2 ip = *(const int2*)(indptr + n);
  int base = ip.x, deg = ip.y - ip.x;
  float4 ald = *(const float4*)(al + n*8 + 4);   // uniform across half: broadcast
  float* eb = &ebuf[slot][0];
  int*   sb = &sbuf[slot][0];
  const char* hp = (const char*)hb + l32*16;

  float acc[8] = {0.f,0.f,0.f,0.f,0.f,0.f,0.f,0.f};
  float4 esum = make_float4(0.f,0.f,0.f,0.f);

  for (int j0 = 0; j0 < deg; j0 += 32){
    int j = j0 + l32;
    float4 e4 = make_float4(0.f,0.f,0.f,0.f);
    int sj = 0;
    if (j < deg){
      sj = csr[base + j];
      float4 als = *(const float4*)(al + sj*8);
      e4.x = __expf(lrelu(als.x + ald.x));
      e4.y = __expf(lrelu(als.y + ald.y));
      e4.z = __expf(lrelu(als.z + ald.z));
      e4.w = __expf(lrelu(als.w + ald.w));
      esum.x += e4.x; esum.y += e4.y; esum.z += e4.z; esum.w += e4.w;
    }
    *(float4*)&eb[l32*4] = e4;
    sb[l32] = sj << 9;                       // byte offset (FD*2 = 512)
    // wave-internal LDS write->read: compiler inserts lgkm wait; no barrier.
    int cnt  = min(32, deg - j0);
    int cpad = (cnt + 7) & ~7;               // pad reads row 0 with alpha 0
    for (int tt = 0; tt < cpad; tt += 8){
      uint4 r[8];
      float v[8];
      #pragma unroll
      for (int q=0; q<8; ++q){
        int o = sb[tt+q];
        v[q] = eb[(tt+q)*4 + head8];
        r[q] = *(const uint4*)(hp + o);
      }
      #pragma unroll
      for (int q=0; q<8; ++q){
        acc[0]+=v[q]*bflo(r[q].x); acc[1]+=v[q]*bfhi(r[q].x);
        acc[2]+=v[q]*bflo(r[q].y); acc[3]+=v[q]*bfhi(r[q].y);
        acc[4]+=v[q]*bflo(r[q].z); acc[5]+=v[q]*bfhi(r[q].z);
        acc[6]+=v[q]*bflo(r[q].w); acc[7]+=v[q]*bfhi(r[q].w);
      }
    }
  }

  // esum reduction within the half (offsets <=16 stay inside the half)
  for (int off=16; off; off>>=1){
    esum.x += __shfl_xor(esum.x, off);
    esum.y += __shfl_xor(esum.y, off);
    esum.z += __shfl_xor(esum.z, off);
    esum.w += __shfl_xor(esum.w, off);
  }
  float sH = (head8==0)?esum.x:(head8==1)?esum.y:(head8==2)?esum.z:esum.w;
  float inv = 1.f/(sH + 1e-16f);
  int ch0 = l32*8;
  float4 b0 = *(const float4*)(bias + ch0);
  float4 b1 = *(const float4*)(bias + ch0 + 4);
  float o[8];
  o[0]=acc[0]*inv+b0.x; o[1]=acc[1]*inv+b0.y; o[2]=acc[2]*inv+b0.z; o[3]=acc[3]*inv+b0.w;
  o[4]=acc[4]*inv+b1.x; o[5]=acc[5]*inv+b1.y; o[6]=acc[6]*inv+b1.z; o[7]=acc[7]*inv+b1.w;
  #pragma unroll
  for (int i=0;i<8;i++) o[i] = o[i] > 0.f ? o[i] : expm1f(o[i]);   // elu

  if (FUSE_W3){
    float4 w0 = *(const float4*)(W3 + ch0);
    float4 w1 = *(const float4*)(W3 + ch0 + 4);
    float p = o[0]*w0.x + o[1]*w0.y + o[2]*w0.z + o[3]*w0.w
            + o[4]*w1.x + o[5]*w1.y + o[6]*w1.z + o[7]*w1.w;
    #pragma unroll
    for (int off=16; off; off>>=1) p += __shfl_xor(p, off);
    if (l32 == 0) h3[n] = p;
  } else {
    unsigned hi[4], lo[4];
    #pragma unroll
    for (int i=0;i<4;i++){
      unsigned short h0 = f2bf(o[2*i]),   h1 = f2bf(o[2*i+1]);
      unsigned short g0 = f2bf(o[2*i]   - bf2f(h0));
      unsigned short g1 = f2bf(o[2*i+1] - bf2f(h1));
      hi[i] = (unsigned)h0 | ((unsigned)h1 << 16);
      lo[i] = (unsigned)g0 | ((unsigned)g1 << 16);
    }
    *(uint4*)(outh + (size_t)n*FD + ch0) = make_uint4(hi[0],hi[1],hi[2],hi[3]);
    *(uint4*)(outl + (size_t)n*FD + ch0) = make_uint4(lo[0],lo[1],lo[2],lo[3]);
  }
}

// ---------------- layer 3: scalar GAT on h3, 4 lanes/node, single pass ----------
// No segment-max: |h3| <~ 10, |a| <~ 0.3 -> logits bounded, exp safe in fp32;
// normalization cancels the shift exactly.
__global__ __launch_bounds__(256) void gat_agg3(const float* __restrict__ h3, const int* __restrict__ indptr,
                                                const int* __restrict__ csr, const float* __restrict__ asrc,
                                                const float* __restrict__ adst, const float* __restrict__ b3,
                                                float* __restrict__ out){
  int tid = blockIdx.x*blockDim.x + threadIdx.x;
  int n = tid >> 2, sub = tid & 3;
  if (n >= NN) return;
  float as = asrc[0], ad = adst[0];
  float hd = h3[n]*ad;
  int2 ip = *(const int2*)(indptr + n);
  float s = 0.f, w = 0.f;
  for (int e = ip.x + sub; e < ip.y; e += 4){
    float hv = h3[csr[e]];
    float ee = __expf(lrelu(as*hv + hd));
    s += ee; w += ee*hv;
  }
  s += __shfl_xor(s, 1); w += __shfl_xor(w, 1);
  s += __shfl_xor(s, 2); w += __shfl_xor(w, 2);
  if (sub == 0) out[n] = w/(s + 1e-16f) + b3[0];
}

extern "C" void kernel_launch(void* const* d_in, const int* in_sizes, int n_in,
                              void* d_out, int out_size, void* d_ws, size_t ws_size,
                              hipStream_t stream){
  const float* x   = (const float*)d_in[0];
  const int*   ei  = (const int*)d_in[1];
  const float* W1  = (const float*)d_in[2];
  const float* as1 = (const float*)d_in[3];
  const float* ad1 = (const float*)d_in[4];
  const float* b1  = (const float*)d_in[5];
  const float* W2  = (const float*)d_in[6];
  const float* as2 = (const float*)d_in[7];
  const float* ad2 = (const float*)d_in[8];
  const float* b2  = (const float*)d_in[9];
  const float* W3  = (const float*)d_in[10];
  const float* as3 = (const float*)d_in[11];
  const float* ad3 = (const float*)d_in[12];
  const float* b3  = (const float*)d_in[13];
  float* outp = (float*)d_out;

  char* w = (char*)d_ws;
  size_t off = 0;
  auto alloc = [&](size_t bytes)->void*{
    void* p = w + off; off += (bytes + 255) & ~(size_t)255; return p;
  };
  unsigned short* hb  = (unsigned short*)alloc((size_t)NN*FD*2);  // 25.6 MB (Cb)
  unsigned short* oh  = (unsigned short*)alloc((size_t)NN*FD*2);  // 25.6 MB
  unsigned short* ol  = (unsigned short*)alloc((size_t)NN*FD*2);  // 25.6 MB
  unsigned short* xh  = (unsigned short*)alloc((size_t)NN*128*2); // 12.8 MB
  unsigned short* xl  = (unsigned short*)alloc((size_t)NN*128*2); // 12.8 MB
  float* al    = (float*)alloc((size_t)NN*8*4);                   // 1.6 MB
  int*   indptr= (int*)alloc((size_t)(NN+1)*4);
  int*   cursor= (int*)alloc((size_t)NN*4);
  int*   csr   = (int*)alloc((size_t)NET*4);                      // 2.8 MB
  int*   bsums = (int*)alloc(64*4);
  float* h3    = (float*)alloc((size_t)NN*4);
  unsigned short* bt1h = (unsigned short*)alloc((size_t)256*128*2);
  unsigned short* bt1l = (unsigned short*)alloc((size_t)256*128*2);
  unsigned short* bt2h = (unsigned short*)alloc((size_t)256*256*2);
  unsigned short* bt2l = (unsigned short*)alloc((size_t)256*256*2);

  // ---- CSR build (once; same graph for all layers) ----
  hipMemsetAsync(cursor, 0, (size_t)NN*4, stream);
  count_deg<<<(NET+255)/256, 256, 0, stream>>>(ei, cursor);
  int nb = (NN+1023)/1024;
  scan_block<<<nb, 256, 0, stream>>>(cursor, indptr, bsums);
  scan_tops<<<1, 64, 0, stream>>>(bsums, nb);
  scan_add<<<(NN+255)/256, 256, 0, stream>>>(indptr, bsums, cursor);
  scatter_csr<<<(NET+255)/256, 256, 0, stream>>>(ei, cursor, csr);

  // ---- merged input/weight split ----
  int cast_elems = NX + 128*256 + 256*256;
  cast_all<<<(cast_elems/4+255)/256, 256, 0, stream>>>(x, W1, W2, xh, xl,
                                                       bt1h, bt1l, bt2h, bt2l);

  dim3 gemm_grid(FD/128, (NN+127)/128);
  int agg_blocks = (NN+7)/8;

  // ---- layer 1 ----
  gemm_mfma<128><<<gemm_grid, 256, 0, stream>>>(xh, xl, bt1h, bt1l, hb, as1, ad1, al, NN);
  gat_agg<false><<<agg_blocks, 256, 0, stream>>>(hb, al, indptr, csr, b1, oh, ol, nullptr, nullptr);
  // ---- layer 2 (fused W3 gemv; no oh/ol write) ----
  gemm_mfma<256><<<gemm_grid, 256, 0, stream>>>(oh, ol, bt2h, bt2l, hb, as2, ad2, al, NN);
  gat_agg<true><<<agg_blocks, 256, 0, stream>>>(hb, al, indptr, csr, b2, nullptr, nullptr, W3, h3);
  // ---- layer 3 ----
  gat_agg3<<<(NN*4+255)/256, 256, 0, stream>>>(h3, indptr, csr, as3, ad3, b3, outp);
}

// Round 10
// 343.853 us; speedup vs baseline: 1.7082x; 1.0243x over previous
//
#include <hip/hip_runtime.h>
#include <math.h>

#define NN 50000     // nodes
#define NE 650000    // edges (without self loops)
#define NET 700000   // NE + NN self loops
#define FD 256       // H*C = 4*64
#define NEG 0.2f
#define NB 49        // scan blocks = ceil(NN/1024)

static __device__ __forceinline__ float lrelu(float v){ return v > 0.f ? v : NEG*v; }

// bf16 helpers
static __device__ __forceinline__ unsigned short f2bf(float f){
  union { float f; unsigned u; } v; v.f = f;
  unsigned r = v.u + 0x7fff + ((v.u >> 16) & 1);
  return (unsigned short)(r >> 16);
}
static __device__ __forceinline__ float bf2f(unsigned short h){
  union { unsigned u; float f; } v; v.u = ((unsigned)h) << 16;
  return v.f;
}
static __device__ __forceinline__ float bflo(unsigned u){ return __uint_as_float(u << 16); }
static __device__ __forceinline__ float bfhi(unsigned u){ return __uint_as_float(u & 0xffff0000u); }

// async global->LDS DMA, 16 B per lane, LDS dest = uniform base + lane*16 (m97/m104)
static __device__ __forceinline__ void gload_lds16(const unsigned short* g, unsigned short* l){
  __builtin_amdgcn_global_load_lds(
      (const __attribute__((address_space(1))) unsigned int*)(g),
      (__attribute__((address_space(3))) unsigned int*)(l), 16, 0, 0);
}

typedef __attribute__((ext_vector_type(8))) short short8_t;  // 8 bf16 = 4 VGPR
typedef __attribute__((ext_vector_type(4))) float f32x4;

// ---------------- fused init: cast x/W1/W2 + degree count (disjoint block ranges) ----
#define NX (NN*128)
#define CAST_ELEMS (NX + 128*256 + 256*256)
#define CAST_BLOCKS ((CAST_ELEMS/4 + 255)/256)
#define CNT_BLOCKS ((NET + 255)/256)
__global__ void init_fused(const float* __restrict__ x, const float* __restrict__ W1,
                           const float* __restrict__ W2,
                           unsigned short* __restrict__ xh, unsigned short* __restrict__ xl,
                           unsigned short* __restrict__ bt1h, unsigned short* __restrict__ bt1l,
                           unsigned short* __restrict__ bt2h, unsigned short* __restrict__ bt2l,
                           const int* __restrict__ ei, int* __restrict__ deg){
  int b = blockIdx.x;
  if (b >= CAST_BLOCKS){
    int e = (b - CAST_BLOCKS)*256 + threadIdx.x;
    if (e < NET){
      int d = (e < NE) ? ei[NE + e] : (e - NE);
      atomicAdd(&deg[d], 1);
    }
    return;
  }
  int i = (b*256 + threadIdx.x)*4;
  if (i < NX){
    float4 f = *(const float4*)(x + i);
    ushort4 h, l;
    h.x = f2bf(f.x); l.x = f2bf(f.x - bf2f(h.x));
    h.y = f2bf(f.y); l.y = f2bf(f.y - bf2f(h.y));
    h.z = f2bf(f.z); l.z = f2bf(f.z - bf2f(h.z));
    h.w = f2bf(f.w); l.w = f2bf(f.w - bf2f(h.w));
    *(ushort4*)(xh + i) = h;
    *(ushort4*)(xl + i) = l;
    return;
  }
  int e, K;
  const float* B;
  unsigned short *bh, *bl;
  if (i < NX + 128*256){ e = i - NX; K = 128; B = W1; bh = bt1h; bl = bt1l; }
  else if (i < CAST_ELEMS){ e = i - NX - 128*256; K = 256; B = W2; bh = bt2h; bl = bt2l; }
  else return;
  int k = e >> 8, n = e & 255;
  float4 f = *(const float4*)(B + e);
  #pragma unroll
  for (int j=0;j<4;j++){
    float fv = (j==0)?f.x:(j==1)?f.y:(j==2)?f.z:f.w;
    unsigned short h = f2bf(fv);
    bh[(n+j)*K + k] = h;
    bl[(n+j)*K + k] = f2bf(fv - bf2f(h));
  }
}

// ---------------- CSR scan ----------------
__global__ void scan_block(const int* __restrict__ deg, int* __restrict__ excl, int* __restrict__ bsums){
  __shared__ int sh[256];
  int t = threadIdx.x;
  int i0 = blockIdx.x*1024 + t*4;
  int v0 = (i0+0 < NN) ? deg[i0+0] : 0;
  int v1 = (i0+1 < NN) ? deg[i0+1] : 0;
  int v2 = (i0+2 < NN) ? deg[i0+2] : 0;
  int v3 = (i0+3 < NN) ? deg[i0+3] : 0;
  int tot = v0+v1+v2+v3;
  sh[t] = tot;
  __syncthreads();
  for (int off=1; off<256; off<<=1){
    int x = (t>=off) ? sh[t-off] : 0;
    __syncthreads();
    sh[t] += x;
    __syncthreads();
  }
  int base = sh[t] - tot;
  if (i0+0 < NN) excl[i0+0] = base;
  if (i0+1 < NN) excl[i0+1] = base + v0;
  if (i0+2 < NN) excl[i0+2] = base + v0+v1;
  if (i0+3 < NN) excl[i0+3] = base + v0+v1+v2;
  if (t == 255) bsums[blockIdx.x] = sh[255];
}

// scan_add with inlined block-sum scan (wave 0 redundantly scans the NB sums)
__global__ void scan_add(int* __restrict__ indptr, const int* __restrict__ bsums, int* __restrict__ cursor){
  __shared__ int boff[64];
  if (threadIdx.x < 64){
    int lane = threadIdx.x;
    int v = (lane < NB) ? bsums[lane] : 0;
    int orig = v;
    for (int off=1; off<64; off<<=1){
      int u = __shfl_up(v, off);
      if (lane >= off) v += u;
    }
    boff[lane] = v - orig;   // exclusive
  }
  __syncthreads();
  int i = blockIdx.x*blockDim.x + threadIdx.x;
  if (i < NN){
    int v = indptr[i] + boff[i>>10];
    indptr[i] = v;
    cursor[i] = v;
  }
  if (i == 0) indptr[NN] = NET;
}

__global__ void scatter_csr(const int* __restrict__ ei, int* __restrict__ cursor, int* __restrict__ csr){
  int e = blockIdx.x*blockDim.x + threadIdx.x;
  if (e >= NET) return;
  int s, d;
  if (e < NE){ s = ei[e]; d = ei[NE+e]; } else { s = e-NE; d = e-NE; }
  int pos = atomicAdd(&cursor[d], 1);
  csr[pos] = s;
}

// ---------------- split-bf16 MFMA GEMM, pipelined global_load_lds, fused al ----
// acc = Ah*Bh + Ah*Bl + Al*Bh (~fp32 precision). Tile 128x128, BK=32,
// contiguous k-major LDS (64 B/row) per global_load_lds constraint (m104).
// K-loop pipelined: frag ds_reads -> barrier -> DMA(next) -> MFMA(cur).
template<int K>
__global__ __launch_bounds__(256, 3) void gemm_mfma(const unsigned short* __restrict__ Ahg,
                                                    const unsigned short* __restrict__ Alg,
                                                    const unsigned short* __restrict__ Bth,
                                                    const unsigned short* __restrict__ Btl,
                                                    unsigned short* __restrict__ Cb,
                                                    const float* __restrict__ a_src,
                                                    const float* __restrict__ a_dst,
                                                    float* __restrict__ al,
                                                    int M){
  constexpr int ITERS = K/32;
  __shared__ unsigned short Ah[128*32], Al[128*32], Bh[128*32], Bl[128*32]; // 8 KB each
  int t = threadIdx.x;
  int wave = t >> 6, lane = t & 63;
  int wm = wave >> 1, wn = wave & 1;
  int quad = lane >> 4, l16 = lane & 15;
  int bm0 = blockIdx.y*128, bn0 = blockIdx.x*128;

  const unsigned short* gsrc = (wave==0)?Ahg:(wave==1)?Alg:(wave==2)?Bth:Btl;
  unsigned short* lbuf       = (wave==0)?Ah :(wave==1)?Al :(wave==2)?Bh :Bl;
  int sbase = (wave < 2) ? bm0 : bn0;
  int srow = lane >> 2;
  int skg  = (lane & 3) * 8;

  // per-row global base pointers (row index constant across k-iters)
  const unsigned short* gp[8];
  #pragma unroll
  for (int i=0;i<8;i++){
    int r = sbase + i*16 + srow;
    if (wave < 2) r = min(r, M-1);   // clamp: dup rows, never OOB
    gp[i] = gsrc + (size_t)r*K + skg;
  }

  f32x4 acc[4][4];
  #pragma unroll
  for (int i=0;i<4;i++)
    #pragma unroll
    for (int j=0;j<4;j++) acc[i][j] = (f32x4){0.f,0.f,0.f,0.f};

  // prologue: DMA iter 0
  #pragma unroll
  for (int i=0;i<8;i++) gload_lds16(gp[i], lbuf + i*512);

  #pragma unroll
  for (int it=0; it<ITERS; ++it){
    __syncthreads();                       // drain DMA(it)

    short8_t afh[4], afl[4], bfh[4], bfl[4];
    #pragma unroll
    for (int mt=0; mt<4; ++mt){
      int row = wm*64 + mt*16 + l16;
      afh[mt] = *(short8_t*)&Ah[row*32 + quad*8];
      afl[mt] = *(short8_t*)&Al[row*32 + quad*8];
    }
    #pragma unroll
    for (int nt=0; nt<4; ++nt){
      int col = wn*64 + nt*16 + l16;
      bfh[nt] = *(short8_t*)&Bh[col*32 + quad*8];
      bfl[nt] = *(short8_t*)&Bl[col*32 + quad*8];
    }
    __syncthreads();                       // all frag reads done; LDS writable

    if (it+1 < ITERS){
      int k0 = (it+1)*32;
      #pragma unroll
      for (int i=0;i<8;i++) gload_lds16(gp[i] + k0, lbuf + i*512);
    }

    #pragma unroll
    for (int mt=0; mt<4; ++mt)
      #pragma unroll
      for (int nt=0; nt<4; ++nt){
        acc[mt][nt] = __builtin_amdgcn_mfma_f32_16x16x32_bf16(afh[mt], bfh[nt], acc[mt][nt], 0,0,0);
        acc[mt][nt] = __builtin_amdgcn_mfma_f32_16x16x32_bf16(afh[mt], bfl[nt], acc[mt][nt], 0,0,0);
        acc[mt][nt] = __builtin_amdgcn_mfma_f32_16x16x32_bf16(afl[mt], bfh[nt], acc[mt][nt], 0,0,0);
      }
  }
  // frag reads all completed before the last in-loop barrier; LDS now
  // wave-private scratch (each wave only touches its own lbuf below).

  // ---- epilogue 1: fused al via LDS transpose (stride 17 floats) ----
  int head_w = (bn0 >> 6) + wn;
  float cs[4], cd[4];
  #pragma unroll
  for (int nt=0; nt<4; ++nt){
    cs[nt] = a_src[head_w*64 + nt*16 + l16];
    cd[nt] = a_dst[head_w*64 + nt*16 + l16];
  }
  {
    float* fsc = (float*)lbuf;
    int grow = bm0 + wm*64 + lane;
    #pragma unroll
    for (int pass=0; pass<2; ++pass){
      #pragma unroll
      for (int mt=0; mt<4; ++mt)
        #pragma unroll
        for (int r=0; r<4; ++r){
          float p = 0.f;
          #pragma unroll
          for (int nt=0; nt<4; ++nt)
            p += acc[mt][nt][r] * (pass ? cd[nt] : cs[nt]);
          fsc[(mt*16 + quad*4 + r)*17 + l16] = p;
        }
      float s = 0.f;
      #pragma unroll
      for (int j=0; j<16; ++j) s += fsc[lane*17 + j];
      if (grow < M) al[grow*8 + pass*4 + head_w] = s;
    }
  }

  // ---- epilogue 2: Cb bf16 via per-wave LDS tile + coalesced dwordx4 ----
  unsigned short* tile = lbuf;
  #pragma unroll
  for (int mt=0; mt<4; ++mt)
    #pragma unroll
    for (int r=0; r<4; ++r){
      int rl = mt*16 + quad*4 + r;
      #pragma unroll
      for (int nt=0; nt<4; ++nt)
        tile[rl*64 + nt*16 + l16] = f2bf(acc[mt][nt][r]);
    }
  int orow = lane >> 3, ocol = (lane & 7) * 8;
  #pragma unroll
  for (int it=0; it<8; ++it){
    int rl = it*8 + orow;
    int row = bm0 + wm*64 + rl;
    if (row < M){
      uint4 v = *(uint4*)&tile[rl*64 + ocol];
      *(uint4*)(Cb + (size_t)row*FD + bn0 + wn*64 + ocol) = v;
    }
  }
}

// ---------------- GAT aggregation: one node per 32-lane half, 8-deep gather MLP ----
template<bool FUSE_W3>
__global__ __launch_bounds__(256) void gat_agg(const unsigned short* __restrict__ hb,
                                               const float* __restrict__ al,
                                               const int* __restrict__ indptr, const int* __restrict__ csr,
                                               const float* __restrict__ bias,
                                               unsigned short* __restrict__ outh,
                                               unsigned short* __restrict__ outl,
                                               const float* __restrict__ W3,
                                               float* __restrict__ h3){
  __shared__ float ebuf[8][128];   // per node: 32 slots x 4 heads
  __shared__ int   sbuf[8][32];    // per node: 32 byte-offsets
  int wave = threadIdx.x >> 6, lane = threadIdx.x & 63;
  int half = lane >> 5, l32 = lane & 31;
  int slot = wave*2 + half;
  int n = blockIdx.x*8 + slot;
  if (n >= NN) return;
  int head8 = l32 >> 3;
  int2 ip = *(const int2*)(indptr + n);
  int base = ip.x, deg = ip.y - ip.x;
  float4 ald = *(const float4*)(al + n*8 + 4);   // uniform across half: broadcast
  float* eb = &ebuf[slot][0];
  int*   sb = &sbuf[slot][0];
  const char* hp = (const char*)hb + l32*16;

  float acc[8] = {0.f,0.f,0.f,0.f,0.f,0.f,0.f,0.f};
  float4 esum = make_float4(0.f,0.f,0.f,0.f);

  for (int j0 = 0; j0 < deg; j0 += 32){
    int j = j0 + l32;
    float4 e4 = make_float4(0.f,0.f,0.f,0.f);
    int sj = 0;
    if (j < deg){
      sj = csr[base + j];
      float4 als = *(const float4*)(al + sj*8);
      e4.x = __expf(lrelu(als.x + ald.x));
      e4.y = __expf(lrelu(als.y + ald.y));
      e4.z = __expf(lrelu(als.z + ald.z));
      e4.w = __expf(lrelu(als.w + ald.w));
      esum.x += e4.x; esum.y += e4.y; esum.z += e4.z; esum.w += e4.w;
    }
    *(float4*)&eb[l32*4] = e4;
    sb[l32] = sj << 9;                       // byte offset (FD*2 = 512)
    // wave-internal LDS write->read: compiler inserts lgkm wait; no barrier.
    int cnt  = min(32, deg - j0);
    int cpad = (cnt + 7) & ~7;               // pad reads row 0 with alpha 0
    for (int tt = 0; tt < cpad; tt += 8){
      uint4 r[8];
      float v[8];
      #pragma unroll
      for (int q=0; q<8; ++q){
        int o = sb[tt+q];
        v[q] = eb[(tt+q)*4 + head8];
        r[q] = *(const uint4*)(hp + o);
      }
      #pragma unroll
      for (int q=0; q<8; ++q){
        acc[0]+=v[q]*bflo(r[q].x); acc[1]+=v[q]*bfhi(r[q].x);
        acc[2]+=v[q]*bflo(r[q].y); acc[3]+=v[q]*bfhi(r[q].y);
        acc[4]+=v[q]*bflo(r[q].z); acc[5]+=v[q]*bfhi(r[q].z);
        acc[6]+=v[q]*bflo(r[q].w); acc[7]+=v[q]*bfhi(r[q].w);
      }
    }
  }

  // esum reduction within the half
  for (int off=16; off; off>>=1){
    esum.x += __shfl_xor(esum.x, off);
    esum.y += __shfl_xor(esum.y, off);
    esum.z += __shfl_xor(esum.z, off);
    esum.w += __shfl_xor(esum.w, off);
  }
  float sH = (head8==0)?esum.x:(head8==1)?esum.y:(head8==2)?esum.z:esum.w;
  float inv = 1.f/(sH + 1e-16f);
  int ch0 = l32*8;
  float4 b0 = *(const float4*)(bias + ch0);
  float4 b1 = *(const float4*)(bias + ch0 + 4);
  float o[8];
  o[0]=acc[0]*inv+b0.x; o[1]=acc[1]*inv+b0.y; o[2]=acc[2]*inv+b0.z; o[3]=acc[3]*inv+b0.w;
  o[4]=acc[4]*inv+b1.x; o[5]=acc[5]*inv+b1.y; o[6]=acc[6]*inv+b1.z; o[7]=acc[7]*inv+b1.w;
  #pragma unroll
  for (int i=0;i<8;i++) o[i] = o[i] > 0.f ? o[i] : expm1f(o[i]);   // elu

  if (FUSE_W3){
    float4 w0 = *(const float4*)(W3 + ch0);
    float4 w1 = *(const float4*)(W3 + ch0 + 4);
    float p = o[0]*w0.x + o[1]*w0.y + o[2]*w0.z + o[3]*w0.w
            + o[4]*w1.x + o[5]*w1.y + o[6]*w1.z + o[7]*w1.w;
    #pragma unroll
    for (int off=16; off; off>>=1) p += __shfl_xor(p, off);
    if (l32 == 0) h3[n] = p;
  } else {
    unsigned hi[4], lo[4];
    #pragma unroll
    for (int i=0;i<4;i++){
      unsigned short h0 = f2bf(o[2*i]),   h1 = f2bf(o[2*i+1]);
      unsigned short g0 = f2bf(o[2*i]   - bf2f(h0));
      unsigned short g1 = f2bf(o[2*i+1] - bf2f(h1));
      hi[i] = (unsigned)h0 | ((unsigned)h1 << 16);
      lo[i] = (unsigned)g0 | ((unsigned)g1 << 16);
    }
    *(uint4*)(outh + (size_t)n*FD + ch0) = make_uint4(hi[0],hi[1],hi[2],hi[3]);
    *(uint4*)(outl + (size_t)n*FD + ch0) = make_uint4(lo[0],lo[1],lo[2],lo[3]);
  }
}

// ---------------- layer 3: scalar GAT on h3, 4 lanes/node, single pass ----------
__global__ __launch_bounds__(256) void gat_agg3(const float* __restrict__ h3, const int* __restrict__ indptr,
                                                const int* __restrict__ csr, const float* __restrict__ asrc,
                                                const float* __restrict__ adst, const float* __restrict__ b3,
                                                float* __restrict__ out){
  int tid = blockIdx.x*blockDim.x + threadIdx.x;
  int n = tid >> 2, sub = tid & 3;
  if (n >= NN) return;
  float as = asrc[0], ad = adst[0];
  float hd = h3[n]*ad;
  int2 ip = *(const int2*)(indptr + n);
  float s = 0.f, w = 0.f;
  for (int e = ip.x + sub; e < ip.y; e += 4){
    float hv = h3[csr[e]];
    float ee = __expf(lrelu(as*hv + hd));
    s += ee; w += ee*hv;
  }
  s += __shfl_xor(s, 1); w += __shfl_xor(w, 1);
  s += __shfl_xor(s, 2); w += __shfl_xor(w, 2);
  if (sub == 0) out[n] = w/(s + 1e-16f) + b3[0];
}

extern "C" void kernel_launch(void* const* d_in, const int* in_sizes, int n_in,
                              void* d_out, int out_size, void* d_ws, size_t ws_size,
                              hipStream_t stream){
  const float* x   = (const float*)d_in[0];
  const int*   ei  = (const int*)d_in[1];
  const float* W1  = (const float*)d_in[2];
  const float* as1 = (const float*)d_in[3];
  const float* ad1 = (const float*)d_in[4];
  const float* b1  = (const float*)d_in[5];
  const float* W2  = (const float*)d_in[6];
  const float* as2 = (const float*)d_in[7];
  const float* ad2 = (const float*)d_in[8];
  const float* b2  = (const float*)d_in[9];
  const float* W3  = (const float*)d_in[10];
  const float* as3 = (const float*)d_in[11];
  const float* ad3 = (const float*)d_in[12];
  const float* b3  = (const float*)d_in[13];
  float* outp = (float*)d_out;

  char* w = (char*)d_ws;
  size_t off = 0;
  auto alloc = [&](size_t bytes)->void*{
    void* p = w + off; off += (bytes + 255) & ~(size_t)255; return p;
  };
  unsigned short* hb  = (unsigned short*)alloc((size_t)NN*FD*2);  // 25.6 MB (Cb)
  unsigned short* oh  = (unsigned short*)alloc((size_t)NN*FD*2);  // 25.6 MB
  unsigned short* ol  = (unsigned short*)alloc((size_t)NN*FD*2);  // 25.6 MB
  unsigned short* xh  = (unsigned short*)alloc((size_t)NN*128*2); // 12.8 MB
  unsigned short* xl  = (unsigned short*)alloc((size_t)NN*128*2); // 12.8 MB
  float* al    = (float*)alloc((size_t)NN*8*4);                   // 1.6 MB
  int*   indptr= (int*)alloc((size_t)(NN+1)*4);
  int*   cursor= (int*)alloc((size_t)NN*4);
  int*   csr   = (int*)alloc((size_t)NET*4);                      // 2.8 MB
  int*   bsums = (int*)alloc(64*4);
  float* h3    = (float*)alloc((size_t)NN*4);
  unsigned short* bt1h = (unsigned short*)alloc((size_t)256*128*2);
  unsigned short* bt1l = (unsigned short*)alloc((size_t)256*128*2);
  unsigned short* bt2h = (unsigned short*)alloc((size_t)256*256*2);
  unsigned short* bt2l = (unsigned short*)alloc((size_t)256*256*2);

  // ---- CSR build + casts (fused; graph identical for all layers) ----
  hipMemsetAsync(cursor, 0, (size_t)NN*4, stream);
  init_fused<<<CAST_BLOCKS + CNT_BLOCKS, 256, 0, stream>>>(x, W1, W2, xh, xl,
                                                           bt1h, bt1l, bt2h, bt2l,
                                                           ei, cursor);
  scan_block<<<NB, 256, 0, stream>>>(cursor, indptr, bsums);
  scan_add<<<(NN+255)/256, 256, 0, stream>>>(indptr, bsums, cursor);
  scatter_csr<<<(NET+255)/256, 256, 0, stream>>>(ei, cursor, csr);

  dim3 gemm_grid(FD/128, (NN+127)/128);
  int agg_blocks = (NN+7)/8;

  // ---- layer 1 ----
  gemm_mfma<128><<<gemm_grid, 256, 0, stream>>>(xh, xl, bt1h, bt1l, hb, as1, ad1, al, NN);
  gat_agg<false><<<agg_blocks, 256, 0, stream>>>(hb, al, indptr, csr, b1, oh, ol, nullptr, nullptr);
  // ---- layer 2 (fused W3 gemv; no oh/ol write) ----
  gemm_mfma<256><<<gemm_grid, 256, 0, stream>>>(oh, ol, bt2h, bt2l, hb, as2, ad2, al, NN);
  gat_agg<true><<<agg_blocks, 256, 0, stream>>>(hb, al, indptr, csr, b2, nullptr, nullptr, W3, h3);
  // ---- layer 3 ----
  gat_agg3<<<(NN*4+255)/256, 256, 0, stream>>>(h3, indptr, csr, as3, ad3, b3, outp);
}